// Round 7
// baseline (130.530 us; speedup 1.0000x reference)
//
#include <hip/hip_runtime.h>
#include <math.h>

#define Bb 4
#define Nn 384
#define CSs 384
#define Hh 12
#define Cc 16
#define PQq 4
#define PVv 8
#define FPROJ 1152
#define FCAT 576
#define INFV 100000.0f
#define EPSV 1e-8f

// ws layout (floats)
#define WS_PROJ 0
#define WS_KP   (1536*1152)             // 1,769,472
#define WS_VP   (WS_KP + 48*384*16)     // 2,064,384
#define WS_KPP  (WS_VP + 48*384*16)     // 2,359,296
#define WS_VPP  (WS_KPP + 48*384*12)    // 2,580,480
#define WS_CAT  (WS_VPP + 48*384*24)    // 3,022,848

__device__ __forceinline__ float get_bias(int f,
    const float* __restrict__ b_q, const float* __restrict__ b_kv,
    const float* __restrict__ b_qp, const float* __restrict__ b_kvp)
{
    if (f < 192) return b_q[f];
    if (f < 576) return b_kv[f - 192];
    if (f < 720) return b_qp[f - 576];
    return b_kvp[f - 720];
}

// ---------------- Kernel 1: projection GEMM, LDS-tiled (r6, unchanged) ----------------
__global__ __launch_bounds__(256) void proj_kernel(
    const float* __restrict__ s,
    const float* __restrict__ w_q, const float* __restrict__ b_q,
    const float* __restrict__ w_kv, const float* __restrict__ b_kv,
    const float* __restrict__ w_qp, const float* __restrict__ b_qp,
    const float* __restrict__ w_kvp, const float* __restrict__ b_kvp,
    float* __restrict__ proj)
{
    __shared__ float sT[16 * 68];
    __shared__ float wT[16 * 64];

    const int bm = blockIdx.x % 24;
    const int bn = blockIdx.x / 24;
    const int m0 = bm * 64;
    const int f0 = bn * 64;
    const int t = threadIdx.x;

    const int smm = t >> 2;
    const int skq = t & 3;
    const int wkk = t >> 4;
    const int wfq = t & 15;

    const float* wb; int ldw; int colof;
    {
        int f = f0 + wfq * 4;
        if (f < 192)      { wb = w_q;   ldw = 192; colof = f; }
        else if (f < 576) { wb = w_kv;  ldw = 384; colof = f - 192; }
        else if (f < 720) { wb = w_qp;  ldw = 144; colof = f - 576; }
        else              { wb = w_kvp; ldw = 432; colof = f - 720; }
    }
    const float* wptr = wb + (size_t)wkk * ldw + colof;
    const float* sptr = s + (size_t)(m0 + smm) * CSs + skq * 4;

    const int tm = t >> 4;
    const int tn = t & 15;

    float acc[16];
#pragma unroll
    for (int e = 0; e < 16; ++e) acc[e] = 0.0f;

    float4 sreg = *(const float4*)sptr;
    float4 wreg = *(const float4*)wptr;

    for (int ks = 0; ks < 24; ++ks) {
        sT[(skq * 4 + 0) * 68 + smm] = sreg.x;
        sT[(skq * 4 + 1) * 68 + smm] = sreg.y;
        sT[(skq * 4 + 2) * 68 + smm] = sreg.z;
        sT[(skq * 4 + 3) * 68 + smm] = sreg.w;
        *(float4*)&wT[wkk * 64 + wfq * 4] = wreg;
        __syncthreads();

        if (ks + 1 < 24) {
            sreg = *(const float4*)(sptr + (ks + 1) * 16);
            wreg = *(const float4*)(wptr + (size_t)(ks + 1) * 16 * ldw);
        }

#pragma unroll
        for (int kk = 0; kk < 16; ++kk) {
            float4 a = *(const float4*)&sT[kk * 68 + tm * 4];
            float4 b = *(const float4*)&wT[kk * 64 + tn * 4];
            acc[0]  += a.x * b.x; acc[1]  += a.x * b.y; acc[2]  += a.x * b.z; acc[3]  += a.x * b.w;
            acc[4]  += a.y * b.x; acc[5]  += a.y * b.y; acc[6]  += a.y * b.z; acc[7]  += a.y * b.w;
            acc[8]  += a.z * b.x; acc[9]  += a.z * b.y; acc[10] += a.z * b.z; acc[11] += a.z * b.w;
            acc[12] += a.w * b.x; acc[13] += a.w * b.y; acc[14] += a.w * b.z; acc[15] += a.w * b.w;
        }
        __syncthreads();
    }

    float bias[4];
#pragma unroll
    for (int cc = 0; cc < 4; ++cc)
        bias[cc] = get_bias(f0 + tn * 4 + cc, b_q, b_kv, b_qp, b_kvp);
#pragma unroll
    for (int rr = 0; rr < 4; ++rr) {
        float4 o;
        o.x = acc[rr * 4 + 0] + bias[0];
        o.y = acc[rr * 4 + 1] + bias[1];
        o.z = acc[rr * 4 + 2] + bias[2];
        o.w = acc[rr * 4 + 3] + bias[3];
        *(float4*)&proj[(size_t)(m0 + tm * 4 + rr) * FPROJ + f0 + tn * 4] = o;
    }
}

// ---------------- Kernel 2: rigid-apply + pack (r6, unchanged) ----------------
__global__ __launch_bounds__(192) void pack_kernel(
    const float* __restrict__ proj,
    const float* __restrict__ rot, const float* __restrict__ trans,
    float* __restrict__ Kp, float* __restrict__ Vp,
    float* __restrict__ KPp, float* __restrict__ VPp)
{
    const int bn = blockIdx.x;
    const int b = bn / Nn;
    const int n = bn % Nn;
    const int t = threadIdx.x;
    const float* R = rot + (size_t)bn * 9;
    const float* T = trans + (size_t)bn * 3;
    const float* pr = proj + (size_t)bn * FPROJ;

    if (t < 144) {
        float x = pr[720 + t];
        float y = pr[720 + 144 + t];
        float z = pr[720 + 288 + t];
        float ox = R[0]*x + R[1]*y + R[2]*z + T[0];
        float oy = R[3]*x + R[4]*y + R[5]*z + T[1];
        float oz = R[6]*x + R[7]*y + R[8]*z + T[2];
        int h = t / 12, pp = t % 12;
        int bh = b * Hh + h;
        if (pp < PQq) {
            float* o = KPp + ((size_t)(bh * Nn + n)) * 12 + pp * 3;
            o[0] = ox; o[1] = oy; o[2] = oz;
        } else {
            float* o = VPp + ((size_t)(bh * Nn + n)) * 24 + (pp - PQq) * 3;
            o[0] = ox; o[1] = oy; o[2] = oz;
        }
    }
#pragma unroll
    for (int rep = 0; rep < 2; ++rep) {
        int idx = t + rep * 192;
        int h = idx / 32, c2 = idx % 32;
        int bh = b * Hh + h;
        float v = pr[192 + h * 32 + c2];
        if (c2 < 16) Kp[((size_t)(bh * Nn + n)) * 16 + c2] = v;
        else         Vp[((size_t)(bh * Nn + n)) * 16 + (c2 - 16)] = v;
    }
}

// ---------------- Kernel 3: attention v6 — two-GEMM formulation ----------------
// grid = B*H*12 = 576 blocks (32 rows each), 128 threads (2 waves).
// Per j-chunk (64): logits GEMM L[32][64] = A'[30-dim] x K'[30-dim] (4x4 reg tiles),
// in-register online softmax (16-lane shuffle groups), P^T -> LDS,
// PV GEMM O[32][40] += P^T x V' (4x4 reg tiles, 80 threads), online rescale.
// Row-constant logit terms (wc|qp_i|^2, -INFV, INFV*m_i) dropped: softmax-invariant.
__global__ __launch_bounds__(128) void attn_kernel(
    const float* __restrict__ proj,
    const float* __restrict__ Kp, const float* __restrict__ Vp,
    const float* __restrict__ KPp, const float* __restrict__ VPp,
    const float* __restrict__ rot, const float* __restrict__ trans,
    const float* __restrict__ mask, const float* __restrict__ head_weights,
    float* __restrict__ cat)
{
    __shared__ float Ash[30 * 34];     // A'[k][i], 32 rows pad 34
    __shared__ float Ksh[30 * 66];     // K'[k][j], 64 cols pad 66   (aliased as o_buf at end)
    __shared__ float Vsh[64 * 44];     // V'[j][c], 40 cols pad 44
    __shared__ float Psh[64 * 34];     // P^T[j][i], pad 34
    __shared__ float rowscale[32];
    __shared__ float rowsum[32];

    const int bid = blockIdx.x;
    const int ib = bid % 12;
    const int h  = (bid / 12) % Hh;
    const int b  = bid / (12 * Hh);
    const int t  = threadIdx.x;
    const int i0 = ib * 32;
    const int bh = b * Hh + h;

    const float hw = log1pf(expf(head_weights[h]));
    const float wc = -0.5f * hw * 0.13608276348795434f;   // * sqrt(1/54)
    const float scale2 = 2.0f * 0.14433756729740643f;     // 2 * sqrt(1/48)

    const float* KpB  = Kp  + (size_t)(bh * Nn) * 16;
    const float* VpB  = Vp  + (size_t)(bh * Nn) * 16;
    const float* KPpB = KPp + (size_t)(bh * Nn) * 12;
    const float* VPpB = VPp + (size_t)(bh * Nn) * 24;
    const float* mb   = mask + b * Nn;

    // ---- A' staging (once per block) ----
    {
        // q rows 0..15 (scaled by scale2)
        int r = t >> 5;           // 0..3
        int i = t & 31;
        const float4 qv = *(const float4*)(proj + (size_t)(b * Nn + i0 + i) * FPROJ + h * Cc + 4 * r);
        Ash[(4 * r + 0) * 34 + i] = scale2 * qv.x;
        Ash[(4 * r + 1) * 34 + i] = scale2 * qv.y;
        Ash[(4 * r + 2) * 34 + i] = scale2 * qv.z;
        Ash[(4 * r + 3) * 34 + i] = scale2 * qv.w;
    }
    if (t < 32) {
        const int bnI = b * Nn + i0 + t;
        const float* R = rot + (size_t)bnI * 9;
        const float* T = trans + (size_t)bnI * 3;
        const float* pq = proj + (size_t)bnI * FPROJ + 576;
        const float n2wc = -2.0f * wc;
#pragma unroll
        for (int p = 0; p < PQq; ++p) {
            float x = pq[h * PQq + p];
            float y = pq[48 + h * PQq + p];
            float z = pq[96 + h * PQq + p];
            Ash[(16 + p * 3 + 0) * 34 + t] = n2wc * (R[0]*x + R[1]*y + R[2]*z + T[0]);
            Ash[(16 + p * 3 + 1) * 34 + t] = n2wc * (R[3]*x + R[4]*y + R[5]*z + T[1]);
            Ash[(16 + p * 3 + 2) * 34 + t] = n2wc * (R[6]*x + R[7]*y + R[8]*z + T[2]);
        }
        Ash[28 * 34 + t] = 1.0f;
        Ash[29 * 34 + t] = mask[bnI];
    }

    // ---- chunk staging (T14 split: load-to-regs early, write-late) ----
    const int jj2 = t >> 1;     // 0..63 (j within chunk)
    const int q   = t & 1;
    float4 kA, kB, vA, vB, kpA, kpB, vpA, vpB, vpC;
    float mj;

#define STAGE_LOAD(TILE) do { \
    int j = (TILE) * 64 + jj2; \
    kA  = *(const float4*)(KpB  + (size_t)j * 16 + 8 * q); \
    kB  = *(const float4*)(KpB  + (size_t)j * 16 + 8 * q + 4); \
    vA  = *(const float4*)(VpB  + (size_t)j * 16 + 8 * q); \
    vB  = *(const float4*)(VpB  + (size_t)j * 16 + 8 * q + 4); \
    kpA = *(const float4*)(KPpB + (size_t)j * 12 + 8 * q); \
    kpB = *(const float4*)(KPpB + (size_t)j * 12 + 4); \
    vpA = *(const float4*)(VPpB + (size_t)j * 24 + 12 * q); \
    vpB = *(const float4*)(VPpB + (size_t)j * 24 + 12 * q + 4); \
    vpC = *(const float4*)(VPpB + (size_t)j * 24 + 12 * q + 8); \
    mj  = mb[j]; \
} while (0)

#define STAGE_WRITE() do { \
    int c0 = 8 * q; \
    Ksh[(c0+0)*66 + jj2] = kA.x; Ksh[(c0+1)*66 + jj2] = kA.y; \
    Ksh[(c0+2)*66 + jj2] = kA.z; Ksh[(c0+3)*66 + jj2] = kA.w; \
    Ksh[(c0+4)*66 + jj2] = kB.x; Ksh[(c0+5)*66 + jj2] = kB.y; \
    Ksh[(c0+6)*66 + jj2] = kB.z; Ksh[(c0+7)*66 + jj2] = kB.w; \
    float s_; \
    if (q == 0) { \
        Ksh[(16)*66 + jj2] = kpA.x; Ksh[(17)*66 + jj2] = kpA.y; \
        Ksh[(18)*66 + jj2] = kpA.z; Ksh[(19)*66 + jj2] = kpA.w; \
        Ksh[(20)*66 + jj2] = kpB.x; Ksh[(21)*66 + jj2] = kpB.y; \
        Ksh[(22)*66 + jj2] = kpB.z; Ksh[(23)*66 + jj2] = kpB.w; \
        s_ = kpA.x*kpA.x + kpA.y*kpA.y + kpA.z*kpA.z + kpA.w*kpA.w \
           + kpB.x*kpB.x + kpB.y*kpB.y + kpB.z*kpB.z + kpB.w*kpB.w; \
    } else { \
        Ksh[(24)*66 + jj2] = kpA.x; Ksh[(25)*66 + jj2] = kpA.y; \
        Ksh[(26)*66 + jj2] = kpA.z; Ksh[(27)*66 + jj2] = kpA.w; \
        s_ = kpA.x*kpA.x + kpA.y*kpA.y + kpA.z*kpA.z + kpA.w*kpA.w; \
    } \
    float full_ = s_ + __shfl_xor(s_, 1); \
    if (q == 1) { \
        Ksh[28*66 + jj2] = wc * full_; \
        Ksh[29*66 + jj2] = INFV * (mj - 1.0f); \
    } \
    *(float4*)&Vsh[jj2 * 44 + 8 * q]      = vA; \
    *(float4*)&Vsh[jj2 * 44 + 8 * q + 4]  = vB; \
    *(float4*)&Vsh[jj2 * 44 + 16 + 12*q]     = vpA; \
    *(float4*)&Vsh[jj2 * 44 + 16 + 12*q + 4] = vpB; \
    *(float4*)&Vsh[jj2 * 44 + 16 + 12*q + 8] = vpC; \
} while (0)

    STAGE_LOAD(0);
    STAGE_WRITE();
    __syncthreads();

    // compute-role indices
    const int ig = t >> 4;      // 0..7 : logits row-quad (rows 4ig..4ig+3)
    const int jg = t & 15;      // 0..15: logits col-quad
    const int ig2 = t & 7;      // PV row-quad (t<80)
    const int cg  = t >> 3;     // PV col-quad 0..9 (t<80)

    float mrun[4], srun[4];
    float acc[4][4];
#pragma unroll
    for (int ii = 0; ii < 4; ++ii) {
        mrun[ii] = -3.0e38f; srun[ii] = 0.0f;
#pragma unroll
        for (int cc = 0; cc < 4; ++cc) acc[ii][cc] = 0.0f;
    }

    for (int tile = 0; tile < 6; ++tile) {
        const bool pf = (tile + 1 < 6);
        if (pf) STAGE_LOAD(tile + 1);

        // ---- logits GEMM: L[4i][4j] over 30-dim K ----
        float L[4][4];
#pragma unroll
        for (int ii = 0; ii < 4; ++ii)
#pragma unroll
            for (int jj = 0; jj < 4; ++jj) L[ii][jj] = 0.0f;

#pragma unroll
        for (int k = 0; k < 30; ++k) {
            float4 a = *(const float4*)&Ash[k * 34 + 4 * ig];
            float4 bb = *(const float4*)&Ksh[k * 66 + 4 * jg];
            L[0][0] += a.x*bb.x; L[0][1] += a.x*bb.y; L[0][2] += a.x*bb.z; L[0][3] += a.x*bb.w;
            L[1][0] += a.y*bb.x; L[1][1] += a.y*bb.y; L[1][2] += a.y*bb.z; L[1][3] += a.y*bb.w;
            L[2][0] += a.z*bb.x; L[2][1] += a.z*bb.y; L[2][2] += a.z*bb.z; L[2][3] += a.z*bb.w;
            L[3][0] += a.w*bb.x; L[3][1] += a.w*bb.y; L[3][2] += a.w*bb.z; L[3][3] += a.w*bb.w;
        }

        // ---- online softmax (16-lane groups share a row-quad) ----
        float p[4][4];
#pragma unroll
        for (int ii = 0; ii < 4; ++ii) {
            float tmax = fmaxf(fmaxf(L[ii][0], L[ii][1]), fmaxf(L[ii][2], L[ii][3]));
#pragma unroll
            for (int off = 8; off >= 1; off >>= 1) tmax = fmaxf(tmax, __shfl_xor(tmax, off));
            float mnew = fmaxf(mrun[ii], tmax);
            float f = __expf(mrun[ii] - mnew);
            mrun[ii] = mnew;
            float cs = 0.0f;
#pragma unroll
            for (int jj = 0; jj < 4; ++jj) {
                p[ii][jj] = __expf(L[ii][jj] - mnew);
                cs += p[ii][jj];
            }
#pragma unroll
            for (int off = 8; off >= 1; off >>= 1) cs += __shfl_xor(cs, off);
            srun[ii] = srun[ii] * f + cs;
            if (jg == 0) rowscale[4 * ig + ii] = f;
        }
#pragma unroll
        for (int jj = 0; jj < 4; ++jj) {
            float4 pc; pc.x = p[0][jj]; pc.y = p[1][jj]; pc.z = p[2][jj]; pc.w = p[3][jj];
            *(float4*)&Psh[(4 * jg + jj) * 34 + 4 * ig] = pc;
        }
        __syncthreads();   // bar B: Psh/rowscale ready

        // ---- PV GEMM (80 threads): O[4i][4c] += P^T x V' ----
        if (t < 80) {
            float fr[4];
#pragma unroll
            for (int ii = 0; ii < 4; ++ii) fr[ii] = rowscale[4 * ig2 + ii];
#pragma unroll
            for (int ii = 0; ii < 4; ++ii)
#pragma unroll
                for (int cc = 0; cc < 4; ++cc) acc[ii][cc] *= fr[ii];
#pragma unroll 4
            for (int j = 0; j < 64; ++j) {
                float4 pc = *(const float4*)&Psh[j * 34 + 4 * ig2];
                float4 vr = *(const float4*)&Vsh[j * 44 + 4 * cg];
                acc[0][0] += pc.x*vr.x; acc[0][1] += pc.x*vr.y; acc[0][2] += pc.x*vr.z; acc[0][3] += pc.x*vr.w;
                acc[1][0] += pc.y*vr.x; acc[1][1] += pc.y*vr.y; acc[1][2] += pc.y*vr.z; acc[1][3] += pc.y*vr.w;
                acc[2][0] += pc.z*vr.x; acc[2][1] += pc.z*vr.y; acc[2][2] += pc.z*vr.z; acc[2][3] += pc.z*vr.w;
                acc[3][0] += pc.w*vr.x; acc[3][1] += pc.w*vr.y; acc[3][2] += pc.w*vr.z; acc[3][3] += pc.w*vr.w;
            }
        }
        __syncthreads();   // bar C: PV done reading Psh/Vsh

        if (pf) {
            STAGE_WRITE();
            __syncthreads();   // bar A: next chunk staged
        }
    }

    // ---- epilogue ----
    if (jg == 0) {
#pragma unroll
        for (int ii = 0; ii < 4; ++ii) rowsum[4 * ig + ii] = srun[ii];
    }
    float* ob = Ksh;   // alias: o_buf[32][44]
    if (t < 80) {
#pragma unroll
        for (int ii = 0; ii < 4; ++ii) {
            float4 o; o.x = acc[ii][0]; o.y = acc[ii][1]; o.z = acc[ii][2]; o.w = acc[ii][3];
            *(float4*)&ob[(4 * ig2 + ii) * 44 + 4 * cg] = o;
        }
    }
    __syncthreads();

    {
        const int i = t >> 2;        // 0..31
        const int qq = t & 3;
        const int bnI = b * Nn + i0 + i;
        const float inv = 1.0f / rowsum[i];
        float* crow = cat + (size_t)bnI * FCAT;

        // o part (cols 0..15 -> cat[h*16 + c])
        float4 o = *(const float4*)&ob[i * 44 + 4 * qq];
        float4 os; os.x = o.x * inv; os.y = o.y * inv; os.z = o.z * inv; os.w = o.w * inv;
        *(float4*)&crow[h * 16 + 4 * qq] = os;

        // o_pt part: two points per thread
        const float* R = rot + (size_t)bnI * 9;
        const float* T = trans + (size_t)bnI * 3;
#pragma unroll
        for (int e = 0; e < 2; ++e) {
            int pe = qq + 4 * e;
            float g0 = ob[i * 44 + 16 + 3 * pe + 0] * inv - T[0];
            float g1 = ob[i * 44 + 16 + 3 * pe + 1] * inv - T[1];
            float g2 = ob[i * 44 + 16 + 3 * pe + 2] * inv - T[2];
            float lx = R[0]*g0 + R[3]*g1 + R[6]*g2;
            float ly = R[1]*g0 + R[4]*g1 + R[7]*g2;
            float lz = R[2]*g0 + R[5]*g1 + R[8]*g2;
            crow[192 + h * 8 + pe] = lx;
            crow[288 + h * 8 + pe] = ly;
            crow[384 + h * 8 + pe] = lz;
            crow[480 + h * 8 + pe] = sqrtf(lx*lx + ly*ly + lz*lz + EPSV);
        }
    }
#undef STAGE_LOAD
#undef STAGE_WRITE
}

// ---------------- Kernel 4: output GEMM, LDS-tiled (r6, unchanged) ----------------
__global__ __launch_bounds__(256) void out_kernel(
    const float* __restrict__ cat,
    const float* __restrict__ w_out, const float* __restrict__ b_out,
    float* __restrict__ out)
{
    __shared__ float cT[16 * 68];
    __shared__ float wT[16 * 64];

    const int bm = blockIdx.x % 24;
    const int bn = blockIdx.x / 24;
    const int m0 = bm * 64;
    const int n0 = bn * 64;
    const int t = threadIdx.x;

    const int smm = t >> 2;
    const int skq = t & 3;
    const int wkk = t >> 4;
    const int wfq = t & 15;

    const float* cptr = cat + (size_t)(m0 + smm) * FCAT + skq * 4;
    const float* wptr = w_out + (size_t)wkk * 384 + n0 + wfq * 4;

    const int tm = t >> 4;
    const int tn = t & 15;

    float acc[16];
#pragma unroll
    for (int e = 0; e < 16; ++e) acc[e] = 0.0f;

    float4 creg = *(const float4*)cptr;
    float4 wreg = *(const float4*)wptr;

    for (int ks = 0; ks < 36; ++ks) {
        cT[(skq * 4 + 0) * 68 + smm] = creg.x;
        cT[(skq * 4 + 1) * 68 + smm] = creg.y;
        cT[(skq * 4 + 2) * 68 + smm] = creg.z;
        cT[(skq * 4 + 3) * 68 + smm] = creg.w;
        *(float4*)&wT[wkk * 64 + wfq * 4] = wreg;
        __syncthreads();

        if (ks + 1 < 36) {
            creg = *(const float4*)(cptr + (ks + 1) * 16);
            wreg = *(const float4*)(wptr + (size_t)(ks + 1) * 16 * 384);
        }

#pragma unroll
        for (int kk = 0; kk < 16; ++kk) {
            float4 a = *(const float4*)&cT[kk * 68 + tm * 4];
            float4 b = *(const float4*)&wT[kk * 64 + tn * 4];
            acc[0]  += a.x * b.x; acc[1]  += a.x * b.y; acc[2]  += a.x * b.z; acc[3]  += a.x * b.w;
            acc[4]  += a.y * b.x; acc[5]  += a.y * b.y; acc[6]  += a.y * b.z; acc[7]  += a.y * b.w;
            acc[8]  += a.z * b.x; acc[9]  += a.z * b.y; acc[10] += a.z * b.z; acc[11] += a.z * b.w;
            acc[12] += a.w * b.x; acc[13] += a.w * b.y; acc[14] += a.w * b.z; acc[15] += a.w * b.w;
        }
        __syncthreads();
    }

    float4 bias = *(const float4*)&b_out[n0 + tn * 4];
#pragma unroll
    for (int rr = 0; rr < 4; ++rr) {
        float4 o;
        o.x = acc[rr * 4 + 0] + bias.x;
        o.y = acc[rr * 4 + 1] + bias.y;
        o.z = acc[rr * 4 + 2] + bias.z;
        o.w = acc[rr * 4 + 3] + bias.w;
        *(float4*)&out[(size_t)(m0 + tm * 4 + rr) * 384 + n0 + tn * 4] = o;
    }
}

extern "C" void kernel_launch(void* const* d_in, const int* in_sizes, int n_in,
                              void* d_out, int out_size, void* d_ws, size_t ws_size,
                              hipStream_t stream) {
    const float* s     = (const float*)d_in[0];
    const float* rot   = (const float*)d_in[2];
    const float* trans = (const float*)d_in[3];
    const float* mask  = (const float*)d_in[4];
    const float* w_q   = (const float*)d_in[5];
    const float* b_q   = (const float*)d_in[6];
    const float* w_kv  = (const float*)d_in[7];
    const float* b_kv  = (const float*)d_in[8];
    const float* w_qp  = (const float*)d_in[13];
    const float* b_qp  = (const float*)d_in[14];
    const float* w_kvp = (const float*)d_in[15];
    const float* b_kvp = (const float*)d_in[16];
    const float* hwts  = (const float*)d_in[17];
    const float* w_out = (const float*)d_in[18];
    const float* b_out = (const float*)d_in[19];

    float* ws    = (float*)d_ws;
    float* proj  = ws + WS_PROJ;
    float* Kp    = ws + WS_KP;
    float* Vp    = ws + WS_VP;
    float* KPp   = ws + WS_KPP;
    float* VPp   = ws + WS_VPP;
    float* catb  = ws + WS_CAT;
    float* out   = (float*)d_out;

    hipLaunchKernelGGL(proj_kernel, dim3(432), dim3(256), 0, stream,
                       s, w_q, b_q, w_kv, b_kv, w_qp, b_qp, w_kvp, b_kvp, proj);
    hipLaunchKernelGGL(pack_kernel, dim3(1536), dim3(192), 0, stream,
                       proj, rot, trans, Kp, Vp, KPp, VPp);
    hipLaunchKernelGGL(attn_kernel, dim3(576), dim3(128), 0, stream,
                       proj, Kp, Vp, KPp, VPp, rot, trans, mask, hwts, catb);
    hipLaunchKernelGGL(out_kernel, dim3(144), dim3(256), 0, stream,
                       catb, w_out, b_out, out);
}

// Round 9
// 92.209 us; speedup vs baseline: 1.4156x; 1.4156x over previous
//
#include <hip/hip_runtime.h>
#include <math.h>

#define Bb 4
#define Nn 384
#define CSs 384
#define Hh 12
#define Cc 16
#define PQq 4
#define PVv 8
#define FPROJ 1152
#define FCAT 576
#define INFV 100000.0f
#define EPSV 1e-8f

// ws layout (floats)
#define WS_PROJ 0
#define WS_KP   1769472
#define WS_VP   2064384
#define WS_KPP  2359296
#define WS_VPP  2580480
#define WS_CAT  3022848
#define WS_QP   3907584
#define WS_QPP  4202496
#define WS_PART 4423680
// part: 48 bh x 6 ic x 6 jc blocks, stride 2688 (O[64][40] | m[64]@2560 | s[64]@2624)
#define PSTRIDE 2688

__device__ __forceinline__ float get_bias(int f,
    const float* __restrict__ b_q, const float* __restrict__ b_kv,
    const float* __restrict__ b_qp, const float* __restrict__ b_kvp)
{
    if (f < 192) return b_q[f];
    if (f < 576) return b_kv[f - 192];
    if (f < 720) return b_qp[f - 576];
    return b_kvp[f - 720];
}

// ---------------- Kernel 1: projection GEMM, LDS-tiled ----------------
__global__ __launch_bounds__(256) void proj_kernel(
    const float* __restrict__ s,
    const float* __restrict__ w_q, const float* __restrict__ b_q,
    const float* __restrict__ w_kv, const float* __restrict__ b_kv,
    const float* __restrict__ w_qp, const float* __restrict__ b_qp,
    const float* __restrict__ w_kvp, const float* __restrict__ b_kvp,
    float* __restrict__ proj)
{
    __shared__ float sT[16 * 68];
    __shared__ float wT[16 * 64];

    const int bm = blockIdx.x % 24;
    const int bn = blockIdx.x / 24;
    const int m0 = bm * 64;
    const int f0 = bn * 64;
    const int t = threadIdx.x;

    const int smm = t >> 2;
    const int skq = t & 3;
    const int wkk = t >> 4;
    const int wfq = t & 15;

    const float* wb; int ldw; int colof;
    {
        int f = f0 + wfq * 4;
        if (f < 192)      { wb = w_q;   ldw = 192; colof = f; }
        else if (f < 576) { wb = w_kv;  ldw = 384; colof = f - 192; }
        else if (f < 720) { wb = w_qp;  ldw = 144; colof = f - 576; }
        else              { wb = w_kvp; ldw = 432; colof = f - 720; }
    }
    const float* wptr = wb + (size_t)wkk * ldw + colof;
    const float* sptr = s + (size_t)(m0 + smm) * CSs + skq * 4;

    const int tm = t >> 4;
    const int tn = t & 15;

    float acc[16];
#pragma unroll
    for (int e = 0; e < 16; ++e) acc[e] = 0.0f;

    float4 sreg = *(const float4*)sptr;
    float4 wreg = *(const float4*)wptr;

    for (int ks = 0; ks < 24; ++ks) {
        sT[(skq * 4 + 0) * 68 + smm] = sreg.x;
        sT[(skq * 4 + 1) * 68 + smm] = sreg.y;
        sT[(skq * 4 + 2) * 68 + smm] = sreg.z;
        sT[(skq * 4 + 3) * 68 + smm] = sreg.w;
        *(float4*)&wT[wkk * 64 + wfq * 4] = wreg;
        __syncthreads();

        if (ks + 1 < 24) {
            sreg = *(const float4*)(sptr + (ks + 1) * 16);
            wreg = *(const float4*)(wptr + (size_t)(ks + 1) * 16 * ldw);
        }

#pragma unroll
        for (int kk = 0; kk < 16; ++kk) {
            float4 a = *(const float4*)&sT[kk * 68 + tm * 4];
            float4 b = *(const float4*)&wT[kk * 64 + tn * 4];
            acc[0]  += a.x * b.x; acc[1]  += a.x * b.y; acc[2]  += a.x * b.z; acc[3]  += a.x * b.w;
            acc[4]  += a.y * b.x; acc[5]  += a.y * b.y; acc[6]  += a.y * b.z; acc[7]  += a.y * b.w;
            acc[8]  += a.z * b.x; acc[9]  += a.z * b.y; acc[10] += a.z * b.z; acc[11] += a.z * b.w;
            acc[12] += a.w * b.x; acc[13] += a.w * b.y; acc[14] += a.w * b.z; acc[15] += a.w * b.w;
        }
        __syncthreads();
    }

    float bias[4];
#pragma unroll
    for (int cc = 0; cc < 4; ++cc)
        bias[cc] = get_bias(f0 + tn * 4 + cc, b_q, b_kv, b_qp, b_kvp);
#pragma unroll
    for (int rr = 0; rr < 4; ++rr) {
        float4 o;
        o.x = acc[rr * 4 + 0] + bias[0];
        o.y = acc[rr * 4 + 1] + bias[1];
        o.z = acc[rr * 4 + 2] + bias[2];
        o.w = acc[rr * 4 + 3] + bias[3];
        *(float4*)&proj[(size_t)(m0 + tm * 4 + rr) * FPROJ + f0 + tn * 4] = o;
    }
}

// ---------------- Kernel 2: rigid-apply + pack (Q-pack guard FIXED) ----------------
__global__ __launch_bounds__(192) void pack_kernel(
    const float* __restrict__ proj,
    const float* __restrict__ rot, const float* __restrict__ trans,
    const float* __restrict__ hwts,
    float* __restrict__ Kp, float* __restrict__ Vp,
    float* __restrict__ KPp, float* __restrict__ VPp,
    float* __restrict__ Qp, float* __restrict__ QPp)
{
    const int bn = blockIdx.x;
    const int b = bn / Nn;
    const int n = bn % Nn;
    const int t = threadIdx.x;
    const float* R = rot + (size_t)bn * 9;
    const float* T = trans + (size_t)bn * 3;
    const float* pr = proj + (size_t)bn * FPROJ;

    if (t < 144) {
        float x = pr[720 + t];
        float y = pr[720 + 144 + t];
        float z = pr[720 + 288 + t];
        float ox = R[0]*x + R[1]*y + R[2]*z + T[0];
        float oy = R[3]*x + R[4]*y + R[5]*z + T[1];
        float oz = R[6]*x + R[7]*y + R[8]*z + T[2];
        int h = t / 12, pp = t % 12;
        int bh = b * Hh + h;
        if (pp < PQq) {
            float* o = KPp + ((size_t)(bh * Nn + n)) * 12 + pp * 3;
            o[0] = ox; o[1] = oy; o[2] = oz;
        } else {
            float* o = VPp + ((size_t)(bh * Nn + n)) * 24 + (pp - PQq) * 3;
            o[0] = ox; o[1] = oy; o[2] = oz;
        }
    }
    if (t < 48) {
        // q_pts: rigid-apply + pre-scale by n2wc(h) = -2*wc = +hw*sqrt(1/54)
        float x = pr[576 + t];
        float y = pr[576 + 48 + t];
        float z = pr[576 + 96 + t];
        float ox = R[0]*x + R[1]*y + R[2]*z + T[0];
        float oy = R[3]*x + R[4]*y + R[5]*z + T[1];
        float oz = R[6]*x + R[7]*y + R[8]*z + T[2];
        int h = t / 4, p = t % 4;
        float hw2 = log1pf(expf(hwts[h]));
        float n2wc = hw2 * 0.13608276348795434f;
        float* o = QPp + ((size_t)((b * Hh + h) * Nn + n)) * 12 + p * 3;
        o[0] = n2wc * ox; o[1] = n2wc * oy; o[2] = n2wc * oz;
    }
#pragma unroll
    for (int rep = 0; rep < 2; ++rep) {
        int idx = t + rep * 192;
        {   // K/V pack (idx 0..383 covers the 384-col KV block)
            int h = idx / 32, c2 = idx % 32;
            int bh = b * Hh + h;
            float v = pr[192 + h * 32 + c2];
            if (c2 < 16) Kp[((size_t)(bh * Nn + n)) * 16 + c2] = v;
            else         Vp[((size_t)(bh * Nn + n)) * 16 + (c2 - 16)] = v;
        }
        if (idx < 192) {   // Q pack: q occupies pr[0..191] ONLY (was OOB for idx>=192)
            int h = idx >> 4, c = idx & 15;
            int bh = b * Hh + h;
            Qp[((size_t)(bh * Nn + n)) * 16 + c] = 0.28867513459481287f * pr[idx];
        }
    }
}

// ---------------- Kernel 3a: attention partial (split-j, two-GEMM) ----------------
// grid = B*H*6ic*6jc = 1728 blocks, 256 threads (4 waves). 64 rows x 64 j each.
__global__ __launch_bounds__(256) void attn_part_kernel(
    const float* __restrict__ Qp, const float* __restrict__ QPp,
    const float* __restrict__ Kp, const float* __restrict__ Vp,
    const float* __restrict__ KPp, const float* __restrict__ VPp,
    const float* __restrict__ mask, const float* __restrict__ hwts,
    float* __restrict__ part)
{
    __shared__ float Ash[30 * 68];   // A'[k][i], 64 rows pad 68
    __shared__ float Ksh[30 * 68];   // K'[k][j]
    __shared__ float Vsh[64 * 44];   // V'[j][c], 40 cols pad 44
    __shared__ float Psh[64 * 68];   // P^T[j][i], pad 68

    const int bid = blockIdx.x;
    const int jc = bid % 6;
    const int ic = (bid / 6) % 6;
    const int h  = (bid / 36) % Hh;
    const int b  = bid / (36 * Hh);
    const int t  = threadIdx.x;
    const int i0 = ic * 64;
    const int bh = b * Hh + h;

    const float hw = log1pf(expf(hwts[h]));
    const float wc = -0.5f * hw * 0.13608276348795434f;

    const float* QpB  = Qp  + ((size_t)(bh * Nn + i0)) * 16;
    const float* QPpB = QPp + ((size_t)(bh * Nn + i0)) * 12;
    const float* KpB  = Kp  + (size_t)(bh * Nn) * 16;
    const float* VpB  = Vp  + (size_t)(bh * Nn) * 16;
    const float* KPpB = KPp + (size_t)(bh * Nn) * 12;
    const float* VPpB = VPp + (size_t)(bh * Nn) * 24;
    const float* mb   = mask + b * Nn;

    // ---- A' staging (coalesced copies; scales pre-folded by pack) ----
    {
        int i = t >> 2, cq = t & 3;
        float4 v = *(const float4*)(QpB + (size_t)i * 16 + 4 * cq);
        Ash[(4*cq+0) * 68 + i] = v.x;
        Ash[(4*cq+1) * 68 + i] = v.y;
        Ash[(4*cq+2) * 68 + i] = v.z;
        Ash[(4*cq+3) * 68 + i] = v.w;
    }
    if (t < 192) {
        int i = t / 3, cp = t % 3;
        float4 v = *(const float4*)(QPpB + (size_t)i * 12 + 4 * cp);
        Ash[(16+4*cp+0) * 68 + i] = v.x;
        Ash[(16+4*cp+1) * 68 + i] = v.y;
        Ash[(16+4*cp+2) * 68 + i] = v.z;
        Ash[(16+4*cp+3) * 68 + i] = v.w;
    }
    if (t < 64) {
        Ash[28 * 68 + t] = 1.0f;
        Ash[29 * 68 + t] = mask[b * Nn + i0 + t];
    }

    // ---- K'/V' staging: lower half K-side, upper half V-side ----
    if (t < 128) {
        const int jj2 = t >> 1, q = t & 1;
        const int j = jc * 64 + jj2;
        float4 kA  = *(const float4*)(KpB  + (size_t)j * 16 + 8 * q);
        float4 kB  = *(const float4*)(KpB  + (size_t)j * 16 + 8 * q + 4);
        float4 kpA = *(const float4*)(KPpB + (size_t)j * 12 + 8 * q);
        float4 kpB = *(const float4*)(KPpB + (size_t)j * 12 + 4);
        float mj   = mb[j];
        int c0 = 8 * q;
        Ksh[(c0+0)*68 + jj2] = kA.x; Ksh[(c0+1)*68 + jj2] = kA.y;
        Ksh[(c0+2)*68 + jj2] = kA.z; Ksh[(c0+3)*68 + jj2] = kA.w;
        Ksh[(c0+4)*68 + jj2] = kB.x; Ksh[(c0+5)*68 + jj2] = kB.y;
        Ksh[(c0+6)*68 + jj2] = kB.z; Ksh[(c0+7)*68 + jj2] = kB.w;
        float s_;
        if (q == 0) {
            Ksh[16*68 + jj2] = kpA.x; Ksh[17*68 + jj2] = kpA.y;
            Ksh[18*68 + jj2] = kpA.z; Ksh[19*68 + jj2] = kpA.w;
            Ksh[20*68 + jj2] = kpB.x; Ksh[21*68 + jj2] = kpB.y;
            Ksh[22*68 + jj2] = kpB.z; Ksh[23*68 + jj2] = kpB.w;
            s_ = kpA.x*kpA.x + kpA.y*kpA.y + kpA.z*kpA.z + kpA.w*kpA.w
               + kpB.x*kpB.x + kpB.y*kpB.y + kpB.z*kpB.z + kpB.w*kpB.w;
        } else {
            Ksh[24*68 + jj2] = kpA.x; Ksh[25*68 + jj2] = kpA.y;
            Ksh[26*68 + jj2] = kpA.z; Ksh[27*68 + jj2] = kpA.w;
            s_ = kpA.x*kpA.x + kpA.y*kpA.y + kpA.z*kpA.z + kpA.w*kpA.w;
        }
        float full_ = s_ + __shfl_xor(s_, 1);
        if (q == 1) {
            Ksh[28*68 + jj2] = wc * full_;
            Ksh[29*68 + jj2] = INFV * (mj - 1.0f);
        }
    } else {
        const int tt = t - 128;
        const int jj2 = tt >> 1, q = tt & 1;
        const int j = jc * 64 + jj2;
        float4 vA  = *(const float4*)(VpB  + (size_t)j * 16 + 8 * q);
        float4 vB  = *(const float4*)(VpB  + (size_t)j * 16 + 8 * q + 4);
        float4 vpA = *(const float4*)(VPpB + (size_t)j * 24 + 12 * q);
        float4 vpB = *(const float4*)(VPpB + (size_t)j * 24 + 12 * q + 4);
        float4 vpC = *(const float4*)(VPpB + (size_t)j * 24 + 12 * q + 8);
        *(float4*)&Vsh[jj2 * 44 + 8 * q]          = vA;
        *(float4*)&Vsh[jj2 * 44 + 8 * q + 4]      = vB;
        *(float4*)&Vsh[jj2 * 44 + 16 + 12*q]      = vpA;
        *(float4*)&Vsh[jj2 * 44 + 16 + 12*q + 4]  = vpB;
        *(float4*)&Vsh[jj2 * 44 + 16 + 12*q + 8]  = vpC;
    }
    __syncthreads();

    // ---- logits GEMM: L[64][64], 256 threads 4x4 each ----
    const int ig = t >> 4;      // 0..15
    const int jg = t & 15;      // 0..15
    float L[4][4];
#pragma unroll
    for (int ii = 0; ii < 4; ++ii)
#pragma unroll
        for (int jj = 0; jj < 4; ++jj) L[ii][jj] = 0.0f;

#pragma unroll
    for (int k = 0; k < 30; ++k) {
        float4 a = *(const float4*)&Ash[k * 68 + 4 * ig];
        float4 bb = *(const float4*)&Ksh[k * 68 + 4 * jg];
        L[0][0] += a.x*bb.x; L[0][1] += a.x*bb.y; L[0][2] += a.x*bb.z; L[0][3] += a.x*bb.w;
        L[1][0] += a.y*bb.x; L[1][1] += a.y*bb.y; L[1][2] += a.y*bb.z; L[1][3] += a.y*bb.w;
        L[2][0] += a.z*bb.x; L[2][1] += a.z*bb.y; L[2][2] += a.z*bb.z; L[2][3] += a.z*bb.w;
        L[3][0] += a.w*bb.x; L[3][1] += a.w*bb.y; L[3][2] += a.w*bb.z; L[3][3] += a.w*bb.w;
    }

    // ---- local softmax (16-lane row groups) ----
    const size_t pidx = ((size_t)(bh * 6 + ic)) * 6 + jc;
    float* po = part + pidx * PSTRIDE;
    float mrow[4], srow[4];
#pragma unroll
    for (int ii = 0; ii < 4; ++ii) {
        float tmax = fmaxf(fmaxf(L[ii][0], L[ii][1]), fmaxf(L[ii][2], L[ii][3]));
#pragma unroll
        for (int off = 8; off >= 1; off >>= 1) tmax = fmaxf(tmax, __shfl_xor(tmax, off));
        float p0 = __expf(L[ii][0] - tmax);
        float p1 = __expf(L[ii][1] - tmax);
        float p2 = __expf(L[ii][2] - tmax);
        float p3 = __expf(L[ii][3] - tmax);
        float cs = p0 + p1 + p2 + p3;
        L[ii][0] = p0; L[ii][1] = p1; L[ii][2] = p2; L[ii][3] = p3;
#pragma unroll
        for (int off = 8; off >= 1; off >>= 1) cs += __shfl_xor(cs, off);
        mrow[ii] = tmax; srow[ii] = cs;
    }
#pragma unroll
    for (int jj = 0; jj < 4; ++jj) {
        float4 pc; pc.x = L[0][jj]; pc.y = L[1][jj]; pc.z = L[2][jj]; pc.w = L[3][jj];
        *(float4*)&Psh[(4 * jg + jj) * 68 + 4 * ig] = pc;
    }
    if (jg == 0) {
#pragma unroll
        for (int ii = 0; ii < 4; ++ii) {
            po[2560 + 4 * ig + ii] = mrow[ii];
            po[2624 + 4 * ig + ii] = srow[ii];
        }
    }
    __syncthreads();

    // ---- PV GEMM: O[64][40] = P^T x V', 160 threads 4x4 each ----
    if (t < 160) {
        const int ig2 = t & 15;
        const int cg  = t >> 4;
        float acc[4][4];
#pragma unroll
        for (int ii = 0; ii < 4; ++ii)
#pragma unroll
            for (int cc = 0; cc < 4; ++cc) acc[ii][cc] = 0.0f;
#pragma unroll 4
        for (int j = 0; j < 64; ++j) {
            float4 pc = *(const float4*)&Psh[j * 68 + 4 * ig2];
            float4 vr = *(const float4*)&Vsh[j * 44 + 4 * cg];
            acc[0][0] += pc.x*vr.x; acc[0][1] += pc.x*vr.y; acc[0][2] += pc.x*vr.z; acc[0][3] += pc.x*vr.w;
            acc[1][0] += pc.y*vr.x; acc[1][1] += pc.y*vr.y; acc[1][2] += pc.y*vr.z; acc[1][3] += pc.y*vr.w;
            acc[2][0] += pc.z*vr.x; acc[2][1] += pc.z*vr.y; acc[2][2] += pc.z*vr.z; acc[2][3] += pc.z*vr.w;
            acc[3][0] += pc.w*vr.x; acc[3][1] += pc.w*vr.y; acc[3][2] += pc.w*vr.z; acc[3][3] += pc.w*vr.w;
        }
#pragma unroll
        for (int ii = 0; ii < 4; ++ii) {
            float4 o; o.x = acc[ii][0]; o.y = acc[ii][1]; o.z = acc[ii][2]; o.w = acc[ii][3];
            *(float4*)&po[(4 * ig2 + ii) * 40 + 4 * cg] = o;
        }
    }
}

// ---------------- Kernel 3b: merge partials + epilogue ----------------
// grid = B*H*6 = 288 blocks, 256 threads; 64 rows each.
__global__ __launch_bounds__(256) void attn_merge_kernel(
    const float* __restrict__ part,
    const float* __restrict__ rot, const float* __restrict__ trans,
    float* __restrict__ cat)
{
    __shared__ float wsh[64 * 8];
    __shared__ float ob[64 * 44];

    const int bid = blockIdx.x;
    const int ic = bid % 6;
    const int h  = (bid / 6) % Hh;
    const int b  = bid / (6 * Hh);
    const int t  = threadIdx.x;
    const int i0 = ic * 64;
    const int bh = b * Hh + h;
    const size_t pbase = (((size_t)(bh * 6 + ic)) * 6) * PSTRIDE;

    if (t < 64) {
        float mk[6], sk[6];
        float M = -3.0e38f;
#pragma unroll
        for (int k = 0; k < 6; ++k) {
            mk[k] = part[pbase + (size_t)k * PSTRIDE + 2560 + t];
            sk[k] = part[pbase + (size_t)k * PSTRIDE + 2624 + t];
            M = fmaxf(M, mk[k]);
        }
        float wk[6]; float stot = 0.0f;
#pragma unroll
        for (int k = 0; k < 6; ++k) {
            wk[k] = __expf(mk[k] - M);
            stot += wk[k] * sk[k];
        }
        float inv = 1.0f / stot;
#pragma unroll
        for (int k = 0; k < 6; ++k) wsh[t * 8 + k] = wk[k] * inv;
    }
    __syncthreads();

#pragma unroll
    for (int it = 0; it < 10; ++it) {
        int idx = t + it * 256;     // < 2560
        int row = idx / 40, col = idx % 40;
        float v = 0.0f;
#pragma unroll
        for (int k = 0; k < 6; ++k)
            v += wsh[row * 8 + k] * part[pbase + (size_t)k * PSTRIDE + row * 40 + col];
        ob[row * 44 + col] = v;
    }
    __syncthreads();

    {
        const int i = t >> 2;       // 0..63
        const int qq = t & 3;
        const int bnI = b * Nn + i0 + i;
        float* crow = cat + (size_t)bnI * FCAT;

        float4 o = *(const float4*)&ob[i * 44 + 4 * qq];
        *(float4*)&crow[h * 16 + 4 * qq] = o;

        const float* R = rot + (size_t)bnI * 9;
        const float* T = trans + (size_t)bnI * 3;
#pragma unroll
        for (int e = 0; e < 2; ++e) {
            int pe = qq + 4 * e;
            float g0 = ob[i * 44 + 16 + 3 * pe + 0] - T[0];
            float g1 = ob[i * 44 + 16 + 3 * pe + 1] - T[1];
            float g2 = ob[i * 44 + 16 + 3 * pe + 2] - T[2];
            float lx = R[0]*g0 + R[3]*g1 + R[6]*g2;
            float ly = R[1]*g0 + R[4]*g1 + R[7]*g2;
            float lz = R[2]*g0 + R[5]*g1 + R[8]*g2;
            crow[192 + h * 8 + pe] = lx;
            crow[288 + h * 8 + pe] = ly;
            crow[384 + h * 8 + pe] = lz;
            crow[480 + h * 8 + pe] = sqrtf(lx*lx + ly*ly + lz*lz + EPSV);
        }
    }
}

// ---------------- Kernel 4: output GEMM, LDS-tiled ----------------
__global__ __launch_bounds__(256) void out_kernel(
    const float* __restrict__ cat,
    const float* __restrict__ w_out, const float* __restrict__ b_out,
    float* __restrict__ out)
{
    __shared__ float cT[16 * 68];
    __shared__ float wT[16 * 64];

    const int bm = blockIdx.x % 24;
    const int bn = blockIdx.x / 24;
    const int m0 = bm * 64;
    const int n0 = bn * 64;
    const int t = threadIdx.x;

    const int smm = t >> 2;
    const int skq = t & 3;
    const int wkk = t >> 4;
    const int wfq = t & 15;

    const float* cptr = cat + (size_t)(m0 + smm) * FCAT + skq * 4;
    const float* wptr = w_out + (size_t)wkk * 384 + n0 + wfq * 4;

    const int tm = t >> 4;
    const int tn = t & 15;

    float acc[16];
#pragma unroll
    for (int e = 0; e < 16; ++e) acc[e] = 0.0f;

    float4 creg = *(const float4*)cptr;
    float4 wreg = *(const float4*)wptr;

    for (int ks = 0; ks < 36; ++ks) {
        cT[(skq * 4 + 0) * 68 + smm] = creg.x;
        cT[(skq * 4 + 1) * 68 + smm] = creg.y;
        cT[(skq * 4 + 2) * 68 + smm] = creg.z;
        cT[(skq * 4 + 3) * 68 + smm] = creg.w;
        *(float4*)&wT[wkk * 64 + wfq * 4] = wreg;
        __syncthreads();

        if (ks + 1 < 36) {
            creg = *(const float4*)(cptr + (ks + 1) * 16);
            wreg = *(const float4*)(wptr + (size_t)(ks + 1) * 16 * 384);
        }

#pragma unroll
        for (int kk = 0; kk < 16; ++kk) {
            float4 a = *(const float4*)&cT[kk * 68 + tm * 4];
            float4 b = *(const float4*)&wT[kk * 64 + tn * 4];
            acc[0]  += a.x * b.x; acc[1]  += a.x * b.y; acc[2]  += a.x * b.z; acc[3]  += a.x * b.w;
            acc[4]  += a.y * b.x; acc[5]  += a.y * b.y; acc[6]  += a.y * b.z; acc[7]  += a.y * b.w;
            acc[8]  += a.z * b.x; acc[9]  += a.z * b.y; acc[10] += a.z * b.z; acc[11] += a.z * b.w;
            acc[12] += a.w * b.x; acc[13] += a.w * b.y; acc[14] += a.w * b.z; acc[15] += a.w * b.w;
        }
        __syncthreads();
    }

    float4 bias = *(const float4*)&b_out[n0 + tn * 4];
#pragma unroll
    for (int rr = 0; rr < 4; ++rr) {
        float4 o;
        o.x = acc[rr * 4 + 0] + bias.x;
        o.y = acc[rr * 4 + 1] + bias.y;
        o.z = acc[rr * 4 + 2] + bias.z;
        o.w = acc[rr * 4 + 3] + bias.w;
        *(float4*)&out[(size_t)(m0 + tm * 4 + rr) * 384 + n0 + tn * 4] = o;
    }
}

extern "C" void kernel_launch(void* const* d_in, const int* in_sizes, int n_in,
                              void* d_out, int out_size, void* d_ws, size_t ws_size,
                              hipStream_t stream) {
    const float* s     = (const float*)d_in[0];
    const float* rot   = (const float*)d_in[2];
    const float* trans = (const float*)d_in[3];
    const float* mask  = (const float*)d_in[4];
    const float* w_q   = (const float*)d_in[5];
    const float* b_q   = (const float*)d_in[6];
    const float* w_kv  = (const float*)d_in[7];
    const float* b_kv  = (const float*)d_in[8];
    const float* w_qp  = (const float*)d_in[13];
    const float* b_qp  = (const float*)d_in[14];
    const float* w_kvp = (const float*)d_in[15];
    const float* b_kvp = (const float*)d_in[16];
    const float* hwts  = (const float*)d_in[17];
    const float* w_out = (const float*)d_in[18];
    const float* b_out = (const float*)d_in[19];

    float* ws    = (float*)d_ws;
    float* proj  = ws + WS_PROJ;
    float* Kp    = ws + WS_KP;
    float* Vp    = ws + WS_VP;
    float* KPp   = ws + WS_KPP;
    float* VPp   = ws + WS_VPP;
    float* catb  = ws + WS_CAT;
    float* Qp    = ws + WS_QP;
    float* QPp   = ws + WS_QPP;
    float* partb = ws + WS_PART;
    float* out   = (float*)d_out;

    hipLaunchKernelGGL(proj_kernel, dim3(432), dim3(256), 0, stream,
                       s, w_q, b_q, w_kv, b_kv, w_qp, b_qp, w_kvp, b_kvp, proj);
    hipLaunchKernelGGL(pack_kernel, dim3(1536), dim3(192), 0, stream,
                       proj, rot, trans, hwts, Kp, Vp, KPp, VPp, Qp, QPp);
    hipLaunchKernelGGL(attn_part_kernel, dim3(1728), dim3(256), 0, stream,
                       Qp, QPp, Kp, Vp, KPp, VPp, mask, hwts, partb);
    hipLaunchKernelGGL(attn_merge_kernel, dim3(288), dim3(256), 0, stream,
                       partb, rot, trans, catb);
    hipLaunchKernelGGL(out_kernel, dim3(144), dim3(256), 0, stream,
                       catb, w_out, b_out, out);
}

// Round 10
// 90.668 us; speedup vs baseline: 1.4396x; 1.0170x over previous
//
#include <hip/hip_runtime.h>
#include <math.h>

#define Bb 4
#define Nn 384
#define CSs 384
#define Hh 12
#define Cc 16
#define PQq 4
#define PVv 8
#define FPROJ 1152
#define FCAT 576
#define INFV 100000.0f
#define EPSV 1e-8f

// ws layout (floats)
#define WS_PROJ 0
#define WS_KP   1769472
#define WS_VP   2064384
#define WS_KPP  2359296
#define WS_VPP  2580480
#define WS_CAT  3022848
#define WS_QP   3907584
#define WS_QPP  4202496
#define WS_PART 4423680
// part: 48 bh x 6 ic x 6 jc blocks, stride 2688 (O[64][40] | m[64]@2560 | s[64]@2624)
#define PSTRIDE 2688

__device__ __forceinline__ float get_bias(int f,
    const float* __restrict__ b_q, const float* __restrict__ b_kv,
    const float* __restrict__ b_qp, const float* __restrict__ b_kvp)
{
    if (f < 192) return b_q[f];
    if (f < 576) return b_kv[f - 192];
    if (f < 720) return b_qp[f - 576];
    return b_kvp[f - 720];
}

// ---------------- Kernel 1: projection GEMM, LDS-tiled (r9, unchanged) ----------------
__global__ __launch_bounds__(256) void proj_kernel(
    const float* __restrict__ s,
    const float* __restrict__ w_q, const float* __restrict__ b_q,
    const float* __restrict__ w_kv, const float* __restrict__ b_kv,
    const float* __restrict__ w_qp, const float* __restrict__ b_qp,
    const float* __restrict__ w_kvp, const float* __restrict__ b_kvp,
    float* __restrict__ proj)
{
    __shared__ float sT[16 * 68];
    __shared__ float wT[16 * 64];

    const int bm = blockIdx.x % 24;
    const int bn = blockIdx.x / 24;
    const int m0 = bm * 64;
    const int f0 = bn * 64;
    const int t = threadIdx.x;

    const int smm = t >> 2;
    const int skq = t & 3;
    const int wkk = t >> 4;
    const int wfq = t & 15;

    const float* wb; int ldw; int colof;
    {
        int f = f0 + wfq * 4;
        if (f < 192)      { wb = w_q;   ldw = 192; colof = f; }
        else if (f < 576) { wb = w_kv;  ldw = 384; colof = f - 192; }
        else if (f < 720) { wb = w_qp;  ldw = 144; colof = f - 576; }
        else              { wb = w_kvp; ldw = 432; colof = f - 720; }
    }
    const float* wptr = wb + (size_t)wkk * ldw + colof;
    const float* sptr = s + (size_t)(m0 + smm) * CSs + skq * 4;

    const int tm = t >> 4;
    const int tn = t & 15;

    float acc[16];
#pragma unroll
    for (int e = 0; e < 16; ++e) acc[e] = 0.0f;

    float4 sreg = *(const float4*)sptr;
    float4 wreg = *(const float4*)wptr;

    for (int ks = 0; ks < 24; ++ks) {
        sT[(skq * 4 + 0) * 68 + smm] = sreg.x;
        sT[(skq * 4 + 1) * 68 + smm] = sreg.y;
        sT[(skq * 4 + 2) * 68 + smm] = sreg.z;
        sT[(skq * 4 + 3) * 68 + smm] = sreg.w;
        *(float4*)&wT[wkk * 64 + wfq * 4] = wreg;
        __syncthreads();

        if (ks + 1 < 24) {
            sreg = *(const float4*)(sptr + (ks + 1) * 16);
            wreg = *(const float4*)(wptr + (size_t)(ks + 1) * 16 * ldw);
        }

#pragma unroll
        for (int kk = 0; kk < 16; ++kk) {
            float4 a = *(const float4*)&sT[kk * 68 + tm * 4];
            float4 b = *(const float4*)&wT[kk * 64 + tn * 4];
            acc[0]  += a.x * b.x; acc[1]  += a.x * b.y; acc[2]  += a.x * b.z; acc[3]  += a.x * b.w;
            acc[4]  += a.y * b.x; acc[5]  += a.y * b.y; acc[6]  += a.y * b.z; acc[7]  += a.y * b.w;
            acc[8]  += a.z * b.x; acc[9]  += a.z * b.y; acc[10] += a.z * b.z; acc[11] += a.z * b.w;
            acc[12] += a.w * b.x; acc[13] += a.w * b.y; acc[14] += a.w * b.z; acc[15] += a.w * b.w;
        }
        __syncthreads();
    }

    float bias[4];
#pragma unroll
    for (int cc = 0; cc < 4; ++cc)
        bias[cc] = get_bias(f0 + tn * 4 + cc, b_q, b_kv, b_qp, b_kvp);
#pragma unroll
    for (int rr = 0; rr < 4; ++rr) {
        float4 o;
        o.x = acc[rr * 4 + 0] + bias[0];
        o.y = acc[rr * 4 + 1] + bias[1];
        o.z = acc[rr * 4 + 2] + bias[2];
        o.w = acc[rr * 4 + 3] + bias[3];
        *(float4*)&proj[(size_t)(m0 + tm * 4 + rr) * FPROJ + f0 + tn * 4] = o;
    }
}

// ---------------- Kernel 2: rigid-apply + pack (r9, unchanged) ----------------
__global__ __launch_bounds__(192) void pack_kernel(
    const float* __restrict__ proj,
    const float* __restrict__ rot, const float* __restrict__ trans,
    const float* __restrict__ hwts,
    float* __restrict__ Kp, float* __restrict__ Vp,
    float* __restrict__ KPp, float* __restrict__ VPp,
    float* __restrict__ Qp, float* __restrict__ QPp)
{
    const int bn = blockIdx.x;
    const int b = bn / Nn;
    const int n = bn % Nn;
    const int t = threadIdx.x;
    const float* R = rot + (size_t)bn * 9;
    const float* T = trans + (size_t)bn * 3;
    const float* pr = proj + (size_t)bn * FPROJ;

    if (t < 144) {
        float x = pr[720 + t];
        float y = pr[720 + 144 + t];
        float z = pr[720 + 288 + t];
        float ox = R[0]*x + R[1]*y + R[2]*z + T[0];
        float oy = R[3]*x + R[4]*y + R[5]*z + T[1];
        float oz = R[6]*x + R[7]*y + R[8]*z + T[2];
        int h = t / 12, pp = t % 12;
        int bh = b * Hh + h;
        if (pp < PQq) {
            float* o = KPp + ((size_t)(bh * Nn + n)) * 12 + pp * 3;
            o[0] = ox; o[1] = oy; o[2] = oz;
        } else {
            float* o = VPp + ((size_t)(bh * Nn + n)) * 24 + (pp - PQq) * 3;
            o[0] = ox; o[1] = oy; o[2] = oz;
        }
    }
    if (t < 48) {
        float x = pr[576 + t];
        float y = pr[576 + 48 + t];
        float z = pr[576 + 96 + t];
        float ox = R[0]*x + R[1]*y + R[2]*z + T[0];
        float oy = R[3]*x + R[4]*y + R[5]*z + T[1];
        float oz = R[6]*x + R[7]*y + R[8]*z + T[2];
        int h = t / 4, p = t % 4;
        float hw2 = log1pf(expf(hwts[h]));
        float n2wc = hw2 * 0.13608276348795434f;
        float* o = QPp + ((size_t)((b * Hh + h) * Nn + n)) * 12 + p * 3;
        o[0] = n2wc * ox; o[1] = n2wc * oy; o[2] = n2wc * oz;
    }
#pragma unroll
    for (int rep = 0; rep < 2; ++rep) {
        int idx = t + rep * 192;
        {
            int h = idx / 32, c2 = idx % 32;
            int bh = b * Hh + h;
            float v = pr[192 + h * 32 + c2];
            if (c2 < 16) Kp[((size_t)(bh * Nn + n)) * 16 + c2] = v;
            else         Vp[((size_t)(bh * Nn + n)) * 16 + (c2 - 16)] = v;
        }
        if (idx < 192) {
            int h = idx >> 4, c = idx & 15;
            int bh = b * Hh + h;
            Qp[((size_t)(bh * Nn + n)) * 16 + c] = 0.28867513459481287f * pr[idx];
        }
    }
}

// ---------------- Kernel 3a: attention partial — LDS union (28.7 KB) ----------------
// grid = 1728 blocks, 256 threads. After the logits GEMM, Ash/Ksh are dead;
// Psh aliases their region (extra barrier guards the overwrite). 45->28.7 KB
// => 5 blocks/CU instead of 3.
__global__ __launch_bounds__(256) void attn_part_kernel(
    const float* __restrict__ Qp, const float* __restrict__ QPp,
    const float* __restrict__ Kp, const float* __restrict__ Vp,
    const float* __restrict__ KPp, const float* __restrict__ VPp,
    const float* __restrict__ mask, const float* __restrict__ hwts,
    float* __restrict__ part)
{
    __shared__ float smem[7168];        // 28672 B
    float* Ash = smem;                  // 30 x 68 (2040)
    float* Ksh = smem + 2176;           // 30 x 68 (2040; offset 2176 keeps bank pattern)
    float* Psh = smem;                  // 64 x 68 (4352) — aliases Ash+Ksh after logits
    float* Vsh = smem + 4352;           // 64 x 44 (2816)

    const int bid = blockIdx.x;
    const int jc = bid % 6;
    const int ic = (bid / 6) % 6;
    const int h  = (bid / 36) % Hh;
    const int b  = bid / (36 * Hh);
    const int t  = threadIdx.x;
    const int i0 = ic * 64;
    const int bh = b * Hh + h;

    const float hw = log1pf(expf(hwts[h]));
    const float wc = -0.5f * hw * 0.13608276348795434f;

    const float* QpB  = Qp  + ((size_t)(bh * Nn + i0)) * 16;
    const float* QPpB = QPp + ((size_t)(bh * Nn + i0)) * 12;
    const float* KpB  = Kp  + (size_t)(bh * Nn) * 16;
    const float* VpB  = Vp  + (size_t)(bh * Nn) * 16;
    const float* KPpB = KPp + (size_t)(bh * Nn) * 12;
    const float* VPpB = VPp + (size_t)(bh * Nn) * 24;
    const float* mb   = mask + b * Nn;

    // ---- A' staging ----
    {
        int i = t >> 2, cq = t & 3;
        float4 v = *(const float4*)(QpB + (size_t)i * 16 + 4 * cq);
        Ash[(4*cq+0) * 68 + i] = v.x;
        Ash[(4*cq+1) * 68 + i] = v.y;
        Ash[(4*cq+2) * 68 + i] = v.z;
        Ash[(4*cq+3) * 68 + i] = v.w;
    }
    if (t < 192) {
        int i = t / 3, cp = t % 3;
        float4 v = *(const float4*)(QPpB + (size_t)i * 12 + 4 * cp);
        Ash[(16+4*cp+0) * 68 + i] = v.x;
        Ash[(16+4*cp+1) * 68 + i] = v.y;
        Ash[(16+4*cp+2) * 68 + i] = v.z;
        Ash[(16+4*cp+3) * 68 + i] = v.w;
    }
    if (t < 64) {
        Ash[28 * 68 + t] = 1.0f;
        Ash[29 * 68 + t] = mask[b * Nn + i0 + t];
    }

    // ---- K'/V' staging ----
    if (t < 128) {
        const int jj2 = t >> 1, q = t & 1;
        const int j = jc * 64 + jj2;
        float4 kA  = *(const float4*)(KpB  + (size_t)j * 16 + 8 * q);
        float4 kB  = *(const float4*)(KpB  + (size_t)j * 16 + 8 * q + 4);
        float4 kpA = *(const float4*)(KPpB + (size_t)j * 12 + 8 * q);
        float4 kpB = *(const float4*)(KPpB + (size_t)j * 12 + 4);
        float mj   = mb[j];
        int c0 = 8 * q;
        Ksh[(c0+0)*68 + jj2] = kA.x; Ksh[(c0+1)*68 + jj2] = kA.y;
        Ksh[(c0+2)*68 + jj2] = kA.z; Ksh[(c0+3)*68 + jj2] = kA.w;
        Ksh[(c0+4)*68 + jj2] = kB.x; Ksh[(c0+5)*68 + jj2] = kB.y;
        Ksh[(c0+6)*68 + jj2] = kB.z; Ksh[(c0+7)*68 + jj2] = kB.w;
        float s_;
        if (q == 0) {
            Ksh[16*68 + jj2] = kpA.x; Ksh[17*68 + jj2] = kpA.y;
            Ksh[18*68 + jj2] = kpA.z; Ksh[19*68 + jj2] = kpA.w;
            Ksh[20*68 + jj2] = kpB.x; Ksh[21*68 + jj2] = kpB.y;
            Ksh[22*68 + jj2] = kpB.z; Ksh[23*68 + jj2] = kpB.w;
            s_ = kpA.x*kpA.x + kpA.y*kpA.y + kpA.z*kpA.z + kpA.w*kpA.w
               + kpB.x*kpB.x + kpB.y*kpB.y + kpB.z*kpB.z + kpB.w*kpB.w;
        } else {
            Ksh[24*68 + jj2] = kpA.x; Ksh[25*68 + jj2] = kpA.y;
            Ksh[26*68 + jj2] = kpA.z; Ksh[27*68 + jj2] = kpA.w;
            s_ = kpA.x*kpA.x + kpA.y*kpA.y + kpA.z*kpA.z + kpA.w*kpA.w;
        }
        float full_ = s_ + __shfl_xor(s_, 1);
        if (q == 1) {
            Ksh[28*68 + jj2] = wc * full_;
            Ksh[29*68 + jj2] = INFV * (mj - 1.0f);
        }
    } else {
        const int tt = t - 128;
        const int jj2 = tt >> 1, q = tt & 1;
        const int j = jc * 64 + jj2;
        float4 vA  = *(const float4*)(VpB  + (size_t)j * 16 + 8 * q);
        float4 vB  = *(const float4*)(VpB  + (size_t)j * 16 + 8 * q + 4);
        float4 vpA = *(const float4*)(VPpB + (size_t)j * 24 + 12 * q);
        float4 vpB = *(const float4*)(VPpB + (size_t)j * 24 + 12 * q + 4);
        float4 vpC = *(const float4*)(VPpB + (size_t)j * 24 + 12 * q + 8);
        *(float4*)&Vsh[jj2 * 44 + 8 * q]          = vA;
        *(float4*)&Vsh[jj2 * 44 + 8 * q + 4]      = vB;
        *(float4*)&Vsh[jj2 * 44 + 16 + 12*q]      = vpA;
        *(float4*)&Vsh[jj2 * 44 + 16 + 12*q + 4]  = vpB;
        *(float4*)&Vsh[jj2 * 44 + 16 + 12*q + 8]  = vpC;
    }
    __syncthreads();

    // ---- logits GEMM: L[64][64], 256 threads 4x4 each ----
    const int ig = t >> 4;
    const int jg = t & 15;
    float L[4][4];
#pragma unroll
    for (int ii = 0; ii < 4; ++ii)
#pragma unroll
        for (int jj = 0; jj < 4; ++jj) L[ii][jj] = 0.0f;

#pragma unroll
    for (int k = 0; k < 30; ++k) {
        float4 a = *(const float4*)&Ash[k * 68 + 4 * ig];
        float4 bb = *(const float4*)&Ksh[k * 68 + 4 * jg];
        L[0][0] += a.x*bb.x; L[0][1] += a.x*bb.y; L[0][2] += a.x*bb.z; L[0][3] += a.x*bb.w;
        L[1][0] += a.y*bb.x; L[1][1] += a.y*bb.y; L[1][2] += a.y*bb.z; L[1][3] += a.y*bb.w;
        L[2][0] += a.z*bb.x; L[2][1] += a.z*bb.y; L[2][2] += a.z*bb.z; L[2][3] += a.z*bb.w;
        L[3][0] += a.w*bb.x; L[3][1] += a.w*bb.y; L[3][2] += a.w*bb.z; L[3][3] += a.w*bb.w;
    }
    __syncthreads();   // NEW: all Ash/Ksh reads done before Psh aliases the region

    // ---- local softmax (16-lane row groups) ----
    const size_t pidx = ((size_t)(bh * 6 + ic)) * 6 + jc;
    float* po = part + pidx * PSTRIDE;
    float mrow[4], srow[4];
#pragma unroll
    for (int ii = 0; ii < 4; ++ii) {
        float tmax = fmaxf(fmaxf(L[ii][0], L[ii][1]), fmaxf(L[ii][2], L[ii][3]));
#pragma unroll
        for (int off = 8; off >= 1; off >>= 1) tmax = fmaxf(tmax, __shfl_xor(tmax, off));
        float p0 = __expf(L[ii][0] - tmax);
        float p1 = __expf(L[ii][1] - tmax);
        float p2 = __expf(L[ii][2] - tmax);
        float p3 = __expf(L[ii][3] - tmax);
        float cs = p0 + p1 + p2 + p3;
        L[ii][0] = p0; L[ii][1] = p1; L[ii][2] = p2; L[ii][3] = p3;
#pragma unroll
        for (int off = 8; off >= 1; off >>= 1) cs += __shfl_xor(cs, off);
        mrow[ii] = tmax; srow[ii] = cs;
    }
#pragma unroll
    for (int jj = 0; jj < 4; ++jj) {
        float4 pc; pc.x = L[0][jj]; pc.y = L[1][jj]; pc.z = L[2][jj]; pc.w = L[3][jj];
        *(float4*)&Psh[(4 * jg + jj) * 68 + 4 * ig] = pc;
    }
    if (jg == 0) {
#pragma unroll
        for (int ii = 0; ii < 4; ++ii) {
            po[2560 + 4 * ig + ii] = mrow[ii];
            po[2624 + 4 * ig + ii] = srow[ii];
        }
    }
    __syncthreads();

    // ---- PV GEMM: O[64][40] = P^T x V', 160 threads 4x4 each ----
    if (t < 160) {
        const int ig2 = t & 15;
        const int cg  = t >> 4;
        float acc[4][4];
#pragma unroll
        for (int ii = 0; ii < 4; ++ii)
#pragma unroll
            for (int cc = 0; cc < 4; ++cc) acc[ii][cc] = 0.0f;
#pragma unroll 4
        for (int j = 0; j < 64; ++j) {
            float4 pc = *(const float4*)&Psh[j * 68 + 4 * ig2];
            float4 vr = *(const float4*)&Vsh[j * 44 + 4 * cg];
            acc[0][0] += pc.x*vr.x; acc[0][1] += pc.x*vr.y; acc[0][2] += pc.x*vr.z; acc[0][3] += pc.x*vr.w;
            acc[1][0] += pc.y*vr.x; acc[1][1] += pc.y*vr.y; acc[1][2] += pc.y*vr.z; acc[1][3] += pc.y*vr.w;
            acc[2][0] += pc.z*vr.x; acc[2][1] += pc.z*vr.y; acc[2][2] += pc.z*vr.z; acc[2][3] += pc.z*vr.w;
            acc[3][0] += pc.w*vr.x; acc[3][1] += pc.w*vr.y; acc[3][2] += pc.w*vr.z; acc[3][3] += pc.w*vr.w;
        }
#pragma unroll
        for (int ii = 0; ii < 4; ++ii) {
            float4 o; o.x = acc[ii][0]; o.y = acc[ii][1]; o.z = acc[ii][2]; o.w = acc[ii][3];
            *(float4*)&po[(4 * ig2 + ii) * 40 + 4 * cg] = o;
        }
    }
}

// ---------------- Kernel 3b: merge partials + epilogue (r9, unchanged) ----------------
__global__ __launch_bounds__(256) void attn_merge_kernel(
    const float* __restrict__ part,
    const float* __restrict__ rot, const float* __restrict__ trans,
    float* __restrict__ cat)
{
    __shared__ float wsh[64 * 8];
    __shared__ float ob[64 * 44];

    const int bid = blockIdx.x;
    const int ic = bid % 6;
    const int h  = (bid / 6) % Hh;
    const int b  = bid / (6 * Hh);
    const int t  = threadIdx.x;
    const int i0 = ic * 64;
    const int bh = b * Hh + h;
    const size_t pbase = (((size_t)(bh * 6 + ic)) * 6) * PSTRIDE;

    if (t < 64) {
        float mk[6], sk[6];
        float M = -3.0e38f;
#pragma unroll
        for (int k = 0; k < 6; ++k) {
            mk[k] = part[pbase + (size_t)k * PSTRIDE + 2560 + t];
            sk[k] = part[pbase + (size_t)k * PSTRIDE + 2624 + t];
            M = fmaxf(M, mk[k]);
        }
        float wk[6]; float stot = 0.0f;
#pragma unroll
        for (int k = 0; k < 6; ++k) {
            wk[k] = __expf(mk[k] - M);
            stot += wk[k] * sk[k];
        }
        float inv = 1.0f / stot;
#pragma unroll
        for (int k = 0; k < 6; ++k) wsh[t * 8 + k] = wk[k] * inv;
    }
    __syncthreads();

#pragma unroll
    for (int it = 0; it < 10; ++it) {
        int idx = t + it * 256;
        int row = idx / 40, col = idx % 40;
        float v = 0.0f;
#pragma unroll
        for (int k = 0; k < 6; ++k)
            v += wsh[row * 8 + k] * part[pbase + (size_t)k * PSTRIDE + row * 40 + col];
        ob[row * 44 + col] = v;
    }
    __syncthreads();

    {
        const int i = t >> 2;
        const int qq = t & 3;
        const int bnI = b * Nn + i0 + i;
        float* crow = cat + (size_t)bnI * FCAT;

        float4 o = *(const float4*)&ob[i * 44 + 4 * qq];
        *(float4*)&crow[h * 16 + 4 * qq] = o;

        const float* R = rot + (size_t)bnI * 9;
        const float* T = trans + (size_t)bnI * 3;
#pragma unroll
        for (int e = 0; e < 2; ++e) {
            int pe = qq + 4 * e;
            float g0 = ob[i * 44 + 16 + 3 * pe + 0] - T[0];
            float g1 = ob[i * 44 + 16 + 3 * pe + 1] - T[1];
            float g2 = ob[i * 44 + 16 + 3 * pe + 2] - T[2];
            float lx = R[0]*g0 + R[3]*g1 + R[6]*g2;
            float ly = R[1]*g0 + R[4]*g1 + R[7]*g2;
            float lz = R[2]*g0 + R[5]*g1 + R[8]*g2;
            crow[192 + h * 8 + pe] = lx;
            crow[288 + h * 8 + pe] = ly;
            crow[384 + h * 8 + pe] = lz;
            crow[480 + h * 8 + pe] = sqrtf(lx*lx + ly*ly + lz*lz + EPSV);
        }
    }
}

// ---------------- Kernel 4: output GEMM, LDS-tiled (r9, unchanged) ----------------
__global__ __launch_bounds__(256) void out_kernel(
    const float* __restrict__ cat,
    const float* __restrict__ w_out, const float* __restrict__ b_out,
    float* __restrict__ out)
{
    __shared__ float cT[16 * 68];
    __shared__ float wT[16 * 64];

    const int bm = blockIdx.x % 24;
    const int bn = blockIdx.x / 24;
    const int m0 = bm * 64;
    const int n0 = bn * 64;
    const int t = threadIdx.x;

    const int smm = t >> 2;
    const int skq = t & 3;
    const int wkk = t >> 4;
    const int wfq = t & 15;

    const float* cptr = cat + (size_t)(m0 + smm) * FCAT + skq * 4;
    const float* wptr = w_out + (size_t)wkk * 384 + n0 + wfq * 4;

    const int tm = t >> 4;
    const int tn = t & 15;

    float acc[16];
#pragma unroll
    for (int e = 0; e < 16; ++e) acc[e] = 0.0f;

    float4 creg = *(const float4*)cptr;
    float4 wreg = *(const float4*)wptr;

    for (int ks = 0; ks < 36; ++ks) {
        cT[(skq * 4 + 0) * 68 + smm] = creg.x;
        cT[(skq * 4 + 1) * 68 + smm] = creg.y;
        cT[(skq * 4 + 2) * 68 + smm] = creg.z;
        cT[(skq * 4 + 3) * 68 + smm] = creg.w;
        *(float4*)&wT[wkk * 64 + wfq * 4] = wreg;
        __syncthreads();

        if (ks + 1 < 36) {
            creg = *(const float4*)(cptr + (ks + 1) * 16);
            wreg = *(const float4*)(wptr + (size_t)(ks + 1) * 16 * 384);
        }

#pragma unroll
        for (int kk = 0; kk < 16; ++kk) {
            float4 a = *(const float4*)&cT[kk * 68 + tm * 4];
            float4 b = *(const float4*)&wT[kk * 64 + tn * 4];
            acc[0]  += a.x * b.x; acc[1]  += a.x * b.y; acc[2]  += a.x * b.z; acc[3]  += a.x * b.w;
            acc[4]  += a.y * b.x; acc[5]  += a.y * b.y; acc[6]  += a.y * b.z; acc[7]  += a.y * b.w;
            acc[8]  += a.z * b.x; acc[9]  += a.z * b.y; acc[10] += a.z * b.z; acc[11] += a.z * b.w;
            acc[12] += a.w * b.x; acc[13] += a.w * b.y; acc[14] += a.w * b.z; acc[15] += a.w * b.w;
        }
        __syncthreads();
    }

    float4 bias = *(const float4*)&b_out[n0 + tn * 4];
#pragma unroll
    for (int rr = 0; rr < 4; ++rr) {
        float4 o;
        o.x = acc[rr * 4 + 0] + bias.x;
        o.y = acc[rr * 4 + 1] + bias.y;
        o.z = acc[rr * 4 + 2] + bias.z;
        o.w = acc[rr * 4 + 3] + bias.w;
        *(float4*)&out[(size_t)(m0 + tm * 4 + rr) * 384 + n0 + tn * 4] = o;
    }
}

extern "C" void kernel_launch(void* const* d_in, const int* in_sizes, int n_in,
                              void* d_out, int out_size, void* d_ws, size_t ws_size,
                              hipStream_t stream) {
    const float* s     = (const float*)d_in[0];
    const float* rot   = (const float*)d_in[2];
    const float* trans = (const float*)d_in[3];
    const float* mask  = (const float*)d_in[4];
    const float* w_q   = (const float*)d_in[5];
    const float* b_q   = (const float*)d_in[6];
    const float* w_kv  = (const float*)d_in[7];
    const float* b_kv  = (const float*)d_in[8];
    const float* w_qp  = (const float*)d_in[13];
    const float* b_qp  = (const float*)d_in[14];
    const float* w_kvp = (const float*)d_in[15];
    const float* b_kvp = (const float*)d_in[16];
    const float* hwts  = (const float*)d_in[17];
    const float* w_out = (const float*)d_in[18];
    const float* b_out = (const float*)d_in[19];

    float* ws    = (float*)d_ws;
    float* proj  = ws + WS_PROJ;
    float* Kp    = ws + WS_KP;
    float* Vp    = ws + WS_VP;
    float* KPp   = ws + WS_KPP;
    float* VPp   = ws + WS_VPP;
    float* catb  = ws + WS_CAT;
    float* Qp    = ws + WS_QP;
    float* QPp   = ws + WS_QPP;
    float* partb = ws + WS_PART;
    float* out   = (float*)d_out;

    hipLaunchKernelGGL(proj_kernel, dim3(432), dim3(256), 0, stream,
                       s, w_q, b_q, w_kv, b_kv, w_qp, b_qp, w_kvp, b_kvp, proj);
    hipLaunchKernelGGL(pack_kernel, dim3(1536), dim3(192), 0, stream,
                       proj, rot, trans, hwts, Kp, Vp, KPp, VPp, Qp, QPp);
    hipLaunchKernelGGL(attn_part_kernel, dim3(1728), dim3(256), 0, stream,
                       Qp, QPp, Kp, Vp, KPp, VPp, mask, hwts, partb);
    hipLaunchKernelGGL(attn_merge_kernel, dim3(288), dim3(256), 0, stream,
                       partb, rot, trans, catb);
    hipLaunchKernelGGL(out_kernel, dim3(144), dim3(256), 0, stream,
                       catb, w_out, b_out, out);
}

// Round 11
// 69.559 us; speedup vs baseline: 1.8765x; 1.3035x over previous
//
#include <hip/hip_runtime.h>
#include <math.h>

#define Bb 4
#define Nn 384
#define CSs 384
#define Hh 12
#define Cc 16
#define PQq 4
#define PVv 8
#define FPROJ 1152
#define FCAT 576
#define INFV 100000.0f
#define EPSV 1e-8f

// ws layout (floats)
#define WS_PROJ 0
#define WS_KP   1769472
#define WS_VP   2064384
#define WS_KPP  2359296
#define WS_VPP  2580480
#define WS_CAT  3022848
#define WS_QP   3907584
#define WS_QPP  4202496
#define WS_PART 4423680
#define PSTRIDE 2688
// bf16 weight regions (float-slot offsets; reinterpreted as short*)
#define WS_WT   9068544     // w proj transposed: [1152][384] bf16 = 221184 float slots
#define WS_WTO  9289728     // w_out transposed:  [384][576]  bf16 = 110592 float slots

typedef __attribute__((ext_vector_type(8))) short short8v;
typedef __attribute__((ext_vector_type(4))) float f32x4;

__device__ __forceinline__ short f2bf(float x) {
    unsigned u = __float_as_uint(x);
    unsigned r = (u + 0x7FFFu + ((u >> 16) & 1u)) >> 16;
    return (short)r;
}

__device__ __forceinline__ float get_bias(int f,
    const float* __restrict__ b_q, const float* __restrict__ b_kv,
    const float* __restrict__ b_qp, const float* __restrict__ b_kvp)
{
    if (f < 192) return b_q[f];
    if (f < 576) return b_kv[f - 192];
    if (f < 720) return b_qp[f - 576];
    return b_kvp[f - 720];
}

// ---------------- Kernel 0: weight prep (transpose + bf16) ----------------
// wt[f][k] = bf16(W[k][f]) for the fused 1152-col proj weight;
// wto[f][k] = bf16(w_out[k][f]).  663552 elems total.
__global__ __launch_bounds__(256) void prep_kernel(
    const float* __restrict__ w_q, const float* __restrict__ w_kv,
    const float* __restrict__ w_qp, const float* __restrict__ w_kvp,
    const float* __restrict__ w_out,
    short* __restrict__ wt, short* __restrict__ wto)
{
    int idx = blockIdx.x * 256 + threadIdx.x;
    if (idx < 1152 * 384) {
        int f = idx / 384, k = idx % 384;
        float v;
        if (f < 192)      v = w_q[(size_t)k * 192 + f];
        else if (f < 576) v = w_kv[(size_t)k * 384 + (f - 192)];
        else if (f < 720) v = w_qp[(size_t)k * 144 + (f - 576)];
        else              v = w_kvp[(size_t)k * 432 + (f - 720)];
        wt[idx] = f2bf(v);
    } else if (idx < 1152 * 384 + 384 * 576) {
        int j = idx - 1152 * 384;
        int f = j / 576, k = j % 576;
        wto[j] = f2bf(w_out[(size_t)k * 384 + f]);
    }
}

// ---------------- Kernel 1: projection GEMM via bf16 MFMA ----------------
// C[1536][1152] = s[1536][384] @ W + bias. Tile 64x64, 256 thr (4 waves),
// wave w owns rows 16w..16w+15 (1x4 mfma subtiles). K = 12 steps of 32.
// LDS: Al[row][k] / Bl[col][k] bf16, row stride 40 (80 B, 16-aligned, ~2-way banks).
__global__ __launch_bounds__(256) void proj_kernel(
    const float* __restrict__ s, const short* __restrict__ wt,
    const float* __restrict__ b_q, const float* __restrict__ b_kv,
    const float* __restrict__ b_qp, const float* __restrict__ b_kvp,
    float* __restrict__ proj)
{
    __shared__ short Al[64 * 40];
    __shared__ short Bl[64 * 40];

    const int bm = blockIdx.x % 24;
    const int bn = blockIdx.x / 24;
    const int m0 = bm * 64;
    const int f0 = bn * 64;
    const int t = threadIdx.x;
    const int w = t >> 6;
    const int lane = t & 63;
    const int lrow = lane & 15;
    const int lkg  = lane >> 4;        // k-group 0..3 (8 elems each)

    const int srow = t >> 2;           // staging: 0..63
    const int sseg = t & 3;            // k8 block

    f32x4 acc0 = {0,0,0,0}, acc1 = {0,0,0,0}, acc2 = {0,0,0,0}, acc3 = {0,0,0,0};

    for (int ks = 0; ks < 12; ++ks) {
        const int kbase = ks * 32;
        // stage A: s f32 -> bf16
        {
            const float* sp = s + (size_t)(m0 + srow) * CSs + kbase + sseg * 8;
            float4 v0 = *(const float4*)sp;
            float4 v1 = *(const float4*)(sp + 4);
            short8v a;
            a[0]=f2bf(v0.x); a[1]=f2bf(v0.y); a[2]=f2bf(v0.z); a[3]=f2bf(v0.w);
            a[4]=f2bf(v1.x); a[5]=f2bf(v1.y); a[6]=f2bf(v1.z); a[7]=f2bf(v1.w);
            *(short8v*)&Al[srow * 40 + sseg * 8] = a;
        }
        // stage B: wt bf16 copy
        {
            short8v bvv = *(const short8v*)&wt[(size_t)(f0 + srow) * 384 + kbase + sseg * 8];
            *(short8v*)&Bl[srow * 40 + sseg * 8] = bvv;
        }
        __syncthreads();

        short8v av = *(const short8v*)&Al[(16 * w + lrow) * 40 + lkg * 8];
        short8v b0 = *(const short8v*)&Bl[(lrow) * 40 + lkg * 8];
        short8v b1 = *(const short8v*)&Bl[(16 + lrow) * 40 + lkg * 8];
        short8v b2 = *(const short8v*)&Bl[(32 + lrow) * 40 + lkg * 8];
        short8v b3 = *(const short8v*)&Bl[(48 + lrow) * 40 + lkg * 8];
        acc0 = __builtin_amdgcn_mfma_f32_16x16x32_bf16(av, b0, acc0, 0, 0, 0);
        acc1 = __builtin_amdgcn_mfma_f32_16x16x32_bf16(av, b1, acc1, 0, 0, 0);
        acc2 = __builtin_amdgcn_mfma_f32_16x16x32_bf16(av, b2, acc2, 0, 0, 0);
        acc3 = __builtin_amdgcn_mfma_f32_16x16x32_bf16(av, b3, acc3, 0, 0, 0);
        __syncthreads();
    }

    // epilogue: C row = (lane>>4)*4+e, col = lane&15 (m89-verified)
    const int orow = m0 + 16 * w + lkg * 4;
#pragma unroll
    for (int e = 0; e < 4; ++e) {
        float* pr = proj + (size_t)(orow + e) * FPROJ + f0;
        int c0 = lrow;
        pr[c0]      = acc0[e] + get_bias(f0 + c0,      b_q, b_kv, b_qp, b_kvp);
        pr[16 + c0] = acc1[e] + get_bias(f0 + 16 + c0, b_q, b_kv, b_qp, b_kvp);
        pr[32 + c0] = acc2[e] + get_bias(f0 + 32 + c0, b_q, b_kv, b_qp, b_kvp);
        pr[48 + c0] = acc3[e] + get_bias(f0 + 48 + c0, b_q, b_kv, b_qp, b_kvp);
    }
}

// ---------------- Kernel 2: rigid-apply + pack (r10, unchanged) ----------------
__global__ __launch_bounds__(192) void pack_kernel(
    const float* __restrict__ proj,
    const float* __restrict__ rot, const float* __restrict__ trans,
    const float* __restrict__ hwts,
    float* __restrict__ Kp, float* __restrict__ Vp,
    float* __restrict__ KPp, float* __restrict__ VPp,
    float* __restrict__ Qp, float* __restrict__ QPp)
{
    const int bn = blockIdx.x;
    const int b = bn / Nn;
    const int n = bn % Nn;
    const int t = threadIdx.x;
    const float* R = rot + (size_t)bn * 9;
    const float* T = trans + (size_t)bn * 3;
    const float* pr = proj + (size_t)bn * FPROJ;

    if (t < 144) {
        float x = pr[720 + t];
        float y = pr[720 + 144 + t];
        float z = pr[720 + 288 + t];
        float ox = R[0]*x + R[1]*y + R[2]*z + T[0];
        float oy = R[3]*x + R[4]*y + R[5]*z + T[1];
        float oz = R[6]*x + R[7]*y + R[8]*z + T[2];
        int h = t / 12, pp = t % 12;
        int bh = b * Hh + h;
        if (pp < PQq) {
            float* o = KPp + ((size_t)(bh * Nn + n)) * 12 + pp * 3;
            o[0] = ox; o[1] = oy; o[2] = oz;
        } else {
            float* o = VPp + ((size_t)(bh * Nn + n)) * 24 + (pp - PQq) * 3;
            o[0] = ox; o[1] = oy; o[2] = oz;
        }
    }
    if (t < 48) {
        float x = pr[576 + t];
        float y = pr[576 + 48 + t];
        float z = pr[576 + 96 + t];
        float ox = R[0]*x + R[1]*y + R[2]*z + T[0];
        float oy = R[3]*x + R[4]*y + R[5]*z + T[1];
        float oz = R[6]*x + R[7]*y + R[8]*z + T[2];
        int h = t / 4, p = t % 4;
        float hw2 = log1pf(expf(hwts[h]));
        float n2wc = hw2 * 0.13608276348795434f;
        float* o = QPp + ((size_t)((b * Hh + h) * Nn + n)) * 12 + p * 3;
        o[0] = n2wc * ox; o[1] = n2wc * oy; o[2] = n2wc * oz;
    }
#pragma unroll
    for (int rep = 0; rep < 2; ++rep) {
        int idx = t + rep * 192;
        {
            int h = idx / 32, c2 = idx % 32;
            int bh = b * Hh + h;
            float v = pr[192 + h * 32 + c2];
            if (c2 < 16) Kp[((size_t)(bh * Nn + n)) * 16 + c2] = v;
            else         Vp[((size_t)(bh * Nn + n)) * 16 + (c2 - 16)] = v;
        }
        if (idx < 192) {
            int h = idx >> 4, c = idx & 15;
            int bh = b * Hh + h;
            Qp[((size_t)(bh * Nn + n)) * 16 + c] = 0.28867513459481287f * pr[idx];
        }
    }
}

// ---------------- Kernel 3a: attention partial (r10, unchanged) ----------------
__global__ __launch_bounds__(256) void attn_part_kernel(
    const float* __restrict__ Qp, const float* __restrict__ QPp,
    const float* __restrict__ Kp, const float* __restrict__ Vp,
    const float* __restrict__ KPp, const float* __restrict__ VPp,
    const float* __restrict__ mask, const float* __restrict__ hwts,
    float* __restrict__ part)
{
    __shared__ float smem[7168];
    float* Ash = smem;
    float* Ksh = smem + 2176;
    float* Psh = smem;
    float* Vsh = smem + 4352;

    const int bid = blockIdx.x;
    const int jc = bid % 6;
    const int ic = (bid / 6) % 6;
    const int h  = (bid / 36) % Hh;
    const int b  = bid / (36 * Hh);
    const int t  = threadIdx.x;
    const int i0 = ic * 64;
    const int bh = b * Hh + h;

    const float hw = log1pf(expf(hwts[h]));
    const float wc = -0.5f * hw * 0.13608276348795434f;

    const float* QpB  = Qp  + ((size_t)(bh * Nn + i0)) * 16;
    const float* QPpB = QPp + ((size_t)(bh * Nn + i0)) * 12;
    const float* KpB  = Kp  + (size_t)(bh * Nn) * 16;
    const float* VpB  = Vp  + (size_t)(bh * Nn) * 16;
    const float* KPpB = KPp + (size_t)(bh * Nn) * 12;
    const float* VPpB = VPp + (size_t)(bh * Nn) * 24;
    const float* mb   = mask + b * Nn;

    {
        int i = t >> 2, cq = t & 3;
        float4 v = *(const float4*)(QpB + (size_t)i * 16 + 4 * cq);
        Ash[(4*cq+0) * 68 + i] = v.x;
        Ash[(4*cq+1) * 68 + i] = v.y;
        Ash[(4*cq+2) * 68 + i] = v.z;
        Ash[(4*cq+3) * 68 + i] = v.w;
    }
    if (t < 192) {
        int i = t / 3, cp = t % 3;
        float4 v = *(const float4*)(QPpB + (size_t)i * 12 + 4 * cp);
        Ash[(16+4*cp+0) * 68 + i] = v.x;
        Ash[(16+4*cp+1) * 68 + i] = v.y;
        Ash[(16+4*cp+2) * 68 + i] = v.z;
        Ash[(16+4*cp+3) * 68 + i] = v.w;
    }
    if (t < 64) {
        Ash[28 * 68 + t] = 1.0f;
        Ash[29 * 68 + t] = mask[b * Nn + i0 + t];
    }

    if (t < 128) {
        const int jj2 = t >> 1, q = t & 1;
        const int j = jc * 64 + jj2;
        float4 kA  = *(const float4*)(KpB  + (size_t)j * 16 + 8 * q);
        float4 kB  = *(const float4*)(KpB  + (size_t)j * 16 + 8 * q + 4);
        float4 kpA = *(const float4*)(KPpB + (size_t)j * 12 + 8 * q);
        float4 kpB = *(const float4*)(KPpB + (size_t)j * 12 + 4);
        float mj   = mb[j];
        int c0 = 8 * q;
        Ksh[(c0+0)*68 + jj2] = kA.x; Ksh[(c0+1)*68 + jj2] = kA.y;
        Ksh[(c0+2)*68 + jj2] = kA.z; Ksh[(c0+3)*68 + jj2] = kA.w;
        Ksh[(c0+4)*68 + jj2] = kB.x; Ksh[(c0+5)*68 + jj2] = kB.y;
        Ksh[(c0+6)*68 + jj2] = kB.z; Ksh[(c0+7)*68 + jj2] = kB.w;
        float s_;
        if (q == 0) {
            Ksh[16*68 + jj2] = kpA.x; Ksh[17*68 + jj2] = kpA.y;
            Ksh[18*68 + jj2] = kpA.z; Ksh[19*68 + jj2] = kpA.w;
            Ksh[20*68 + jj2] = kpB.x; Ksh[21*68 + jj2] = kpB.y;
            Ksh[22*68 + jj2] = kpB.z; Ksh[23*68 + jj2] = kpB.w;
            s_ = kpA.x*kpA.x + kpA.y*kpA.y + kpA.z*kpA.z + kpA.w*kpA.w
               + kpB.x*kpB.x + kpB.y*kpB.y + kpB.z*kpB.z + kpB.w*kpB.w;
        } else {
            Ksh[24*68 + jj2] = kpA.x; Ksh[25*68 + jj2] = kpA.y;
            Ksh[26*68 + jj2] = kpA.z; Ksh[27*68 + jj2] = kpA.w;
            s_ = kpA.x*kpA.x + kpA.y*kpA.y + kpA.z*kpA.z + kpA.w*kpA.w;
        }
        float full_ = s_ + __shfl_xor(s_, 1);
        if (q == 1) {
            Ksh[28*68 + jj2] = wc * full_;
            Ksh[29*68 + jj2] = INFV * (mj - 1.0f);
        }
    } else {
        const int tt = t - 128;
        const int jj2 = tt >> 1, q = tt & 1;
        const int j = jc * 64 + jj2;
        float4 vA  = *(const float4*)(VpB  + (size_t)j * 16 + 8 * q);
        float4 vB  = *(const float4*)(VpB  + (size_t)j * 16 + 8 * q + 4);
        float4 vpA = *(const float4*)(VPpB + (size_t)j * 24 + 12 * q);
        float4 vpB = *(const float4*)(VPpB + (size_t)j * 24 + 12 * q + 4);
        float4 vpC = *(const float4*)(VPpB + (size_t)j * 24 + 12 * q + 8);
        *(float4*)&Vsh[jj2 * 44 + 8 * q]          = vA;
        *(float4*)&Vsh[jj2 * 44 + 8 * q + 4]      = vB;
        *(float4*)&Vsh[jj2 * 44 + 16 + 12*q]      = vpA;
        *(float4*)&Vsh[jj2 * 44 + 16 + 12*q + 4]  = vpB;
        *(float4*)&Vsh[jj2 * 44 + 16 + 12*q + 8]  = vpC;
    }
    __syncthreads();

    const int ig = t >> 4;
    const int jg = t & 15;
    float L[4][4];
#pragma unroll
    for (int ii = 0; ii < 4; ++ii)
#pragma unroll
        for (int jj = 0; jj < 4; ++jj) L[ii][jj] = 0.0f;

#pragma unroll
    for (int k = 0; k < 30; ++k) {
        float4 a = *(const float4*)&Ash[k * 68 + 4 * ig];
        float4 bb = *(const float4*)&Ksh[k * 68 + 4 * jg];
        L[0][0] += a.x*bb.x; L[0][1] += a.x*bb.y; L[0][2] += a.x*bb.z; L[0][3] += a.x*bb.w;
        L[1][0] += a.y*bb.x; L[1][1] += a.y*bb.y; L[1][2] += a.y*bb.z; L[1][3] += a.y*bb.w;
        L[2][0] += a.z*bb.x; L[2][1] += a.z*bb.y; L[2][2] += a.z*bb.z; L[2][3] += a.z*bb.w;
        L[3][0] += a.w*bb.x; L[3][1] += a.w*bb.y; L[3][2] += a.w*bb.z; L[3][3] += a.w*bb.w;
    }
    __syncthreads();

    const size_t pidx = ((size_t)(bh * 6 + ic)) * 6 + jc;
    float* po = part + pidx * PSTRIDE;
    float mrow[4], srow[4];
#pragma unroll
    for (int ii = 0; ii < 4; ++ii) {
        float tmax = fmaxf(fmaxf(L[ii][0], L[ii][1]), fmaxf(L[ii][2], L[ii][3]));
#pragma unroll
        for (int off = 8; off >= 1; off >>= 1) tmax = fmaxf(tmax, __shfl_xor(tmax, off));
        float p0 = __expf(L[ii][0] - tmax);
        float p1 = __expf(L[ii][1] - tmax);
        float p2 = __expf(L[ii][2] - tmax);
        float p3 = __expf(L[ii][3] - tmax);
        float cs = p0 + p1 + p2 + p3;
        L[ii][0] = p0; L[ii][1] = p1; L[ii][2] = p2; L[ii][3] = p3;
#pragma unroll
        for (int off = 8; off >= 1; off >>= 1) cs += __shfl_xor(cs, off);
        mrow[ii] = tmax; srow[ii] = cs;
    }
#pragma unroll
    for (int jj = 0; jj < 4; ++jj) {
        float4 pc; pc.x = L[0][jj]; pc.y = L[1][jj]; pc.z = L[2][jj]; pc.w = L[3][jj];
        *(float4*)&Psh[(4 * jg + jj) * 68 + 4 * ig] = pc;
    }
    if (jg == 0) {
#pragma unroll
        for (int ii = 0; ii < 4; ++ii) {
            po[2560 + 4 * ig + ii] = mrow[ii];
            po[2624 + 4 * ig + ii] = srow[ii];
        }
    }
    __syncthreads();

    if (t < 160) {
        const int ig2 = t & 15;
        const int cg  = t >> 4;
        float acc[4][4];
#pragma unroll
        for (int ii = 0; ii < 4; ++ii)
#pragma unroll
            for (int cc = 0; cc < 4; ++cc) acc[ii][cc] = 0.0f;
#pragma unroll 4
        for (int j = 0; j < 64; ++j) {
            float4 pc = *(const float4*)&Psh[j * 68 + 4 * ig2];
            float4 vr = *(const float4*)&Vsh[j * 44 + 4 * cg];
            acc[0][0] += pc.x*vr.x; acc[0][1] += pc.x*vr.y; acc[0][2] += pc.x*vr.z; acc[0][3] += pc.x*vr.w;
            acc[1][0] += pc.y*vr.x; acc[1][1] += pc.y*vr.y; acc[1][2] += pc.y*vr.z; acc[1][3] += pc.y*vr.w;
            acc[2][0] += pc.z*vr.x; acc[2][1] += pc.z*vr.y; acc[2][2] += pc.z*vr.z; acc[2][3] += pc.z*vr.w;
            acc[3][0] += pc.w*vr.x; acc[3][1] += pc.w*vr.y; acc[3][2] += pc.w*vr.z; acc[3][3] += pc.w*vr.w;
        }
#pragma unroll
        for (int ii = 0; ii < 4; ++ii) {
            float4 o; o.x = acc[ii][0]; o.y = acc[ii][1]; o.z = acc[ii][2]; o.w = acc[ii][3];
            *(float4*)&po[(4 * ig2 + ii) * 40 + 4 * cg] = o;
        }
    }
}

// ---------------- Kernel 3b: merge partials + epilogue (r10, unchanged) ----------------
__global__ __launch_bounds__(256) void attn_merge_kernel(
    const float* __restrict__ part,
    const float* __restrict__ rot, const float* __restrict__ trans,
    float* __restrict__ cat)
{
    __shared__ float wsh[64 * 8];
    __shared__ float ob[64 * 44];

    const int bid = blockIdx.x;
    const int ic = bid % 6;
    const int h  = (bid / 6) % Hh;
    const int b  = bid / (6 * Hh);
    const int t  = threadIdx.x;
    const int i0 = ic * 64;
    const int bh = b * Hh + h;
    const size_t pbase = (((size_t)(bh * 6 + ic)) * 6) * PSTRIDE;

    if (t < 64) {
        float mk[6], sk[6];
        float M = -3.0e38f;
#pragma unroll
        for (int k = 0; k < 6; ++k) {
            mk[k] = part[pbase + (size_t)k * PSTRIDE + 2560 + t];
            sk[k] = part[pbase + (size_t)k * PSTRIDE + 2624 + t];
            M = fmaxf(M, mk[k]);
        }
        float wk[6]; float stot = 0.0f;
#pragma unroll
        for (int k = 0; k < 6; ++k) {
            wk[k] = __expf(mk[k] - M);
            stot += wk[k] * sk[k];
        }
        float inv = 1.0f / stot;
#pragma unroll
        for (int k = 0; k < 6; ++k) wsh[t * 8 + k] = wk[k] * inv;
    }
    __syncthreads();

#pragma unroll
    for (int it = 0; it < 10; ++it) {
        int idx = t + it * 256;
        int row = idx / 40, col = idx % 40;
        float v = 0.0f;
#pragma unroll
        for (int k = 0; k < 6; ++k)
            v += wsh[row * 8 + k] * part[pbase + (size_t)k * PSTRIDE + row * 40 + col];
        ob[row * 44 + col] = v;
    }
    __syncthreads();

    {
        const int i = t >> 2;
        const int qq = t & 3;
        const int bnI = b * Nn + i0 + i;
        float* crow = cat + (size_t)bnI * FCAT;

        float4 o = *(const float4*)&ob[i * 44 + 4 * qq];
        *(float4*)&crow[h * 16 + 4 * qq] = o;

        const float* R = rot + (size_t)bnI * 9;
        const float* T = trans + (size_t)bnI * 3;
#pragma unroll
        for (int e = 0; e < 2; ++e) {
            int pe = qq + 4 * e;
            float g0 = ob[i * 44 + 16 + 3 * pe + 0] - T[0];
            float g1 = ob[i * 44 + 16 + 3 * pe + 1] - T[1];
            float g2 = ob[i * 44 + 16 + 3 * pe + 2] - T[2];
            float lx = R[0]*g0 + R[3]*g1 + R[6]*g2;
            float ly = R[1]*g0 + R[4]*g1 + R[7]*g2;
            float lz = R[2]*g0 + R[5]*g1 + R[8]*g2;
            crow[192 + h * 8 + pe] = lx;
            crow[288 + h * 8 + pe] = ly;
            crow[384 + h * 8 + pe] = lz;
            crow[480 + h * 8 + pe] = sqrtf(lx*lx + ly*ly + lz*lz + EPSV);
        }
    }
}

// ---------------- Kernel 4: output GEMM via bf16 MFMA ----------------
// out[1536][384] = cat[1536][576] @ w_out + b_out. Tile 64x64, 256 thr,
// K = 18 steps of 32; cat converted to bf16 in staging; wto prepped.
__global__ __launch_bounds__(256) void out_kernel(
    const float* __restrict__ cat, const short* __restrict__ wto,
    const float* __restrict__ b_out, float* __restrict__ out)
{
    __shared__ short Al[64 * 40];
    __shared__ short Bl[64 * 40];

    const int bm = blockIdx.x % 24;
    const int bn = blockIdx.x / 24;
    const int m0 = bm * 64;
    const int n0 = bn * 64;
    const int t = threadIdx.x;
    const int w = t >> 6;
    const int lane = t & 63;
    const int lrow = lane & 15;
    const int lkg  = lane >> 4;

    const int srow = t >> 2;
    const int sseg = t & 3;

    f32x4 acc0 = {0,0,0,0}, acc1 = {0,0,0,0}, acc2 = {0,0,0,0}, acc3 = {0,0,0,0};

    for (int ks = 0; ks < 18; ++ks) {
        const int kbase = ks * 32;
        {
            const float* cp = cat + (size_t)(m0 + srow) * FCAT + kbase + sseg * 8;
            float4 v0 = *(const float4*)cp;
            float4 v1 = *(const float4*)(cp + 4);
            short8v a;
            a[0]=f2bf(v0.x); a[1]=f2bf(v0.y); a[2]=f2bf(v0.z); a[3]=f2bf(v0.w);
            a[4]=f2bf(v1.x); a[5]=f2bf(v1.y); a[6]=f2bf(v1.z); a[7]=f2bf(v1.w);
            *(short8v*)&Al[srow * 40 + sseg * 8] = a;
        }
        {
            short8v bvv = *(const short8v*)&wto[(size_t)(n0 + srow) * FCAT + kbase + sseg * 8];
            *(short8v*)&Bl[srow * 40 + sseg * 8] = bvv;
        }
        __syncthreads();

        short8v av = *(const short8v*)&Al[(16 * w + lrow) * 40 + lkg * 8];
        short8v b0 = *(const short8v*)&Bl[(lrow) * 40 + lkg * 8];
        short8v b1 = *(const short8v*)&Bl[(16 + lrow) * 40 + lkg * 8];
        short8v b2 = *(const short8v*)&Bl[(32 + lrow) * 40 + lkg * 8];
        short8v b3 = *(const short8v*)&Bl[(48 + lrow) * 40 + lkg * 8];
        acc0 = __builtin_amdgcn_mfma_f32_16x16x32_bf16(av, b0, acc0, 0, 0, 0);
        acc1 = __builtin_amdgcn_mfma_f32_16x16x32_bf16(av, b1, acc1, 0, 0, 0);
        acc2 = __builtin_amdgcn_mfma_f32_16x16x32_bf16(av, b2, acc2, 0, 0, 0);
        acc3 = __builtin_amdgcn_mfma_f32_16x16x32_bf16(av, b3, acc3, 0, 0, 0);
        __syncthreads();
    }

    const int orow = m0 + 16 * w + lkg * 4;
#pragma unroll
    for (int e = 0; e < 4; ++e) {
        float* pr = out + (size_t)(orow + e) * 384 + n0;
        int c0 = lrow;
        pr[c0]      = acc0[e] + b_out[n0 + c0];
        pr[16 + c0] = acc1[e] + b_out[n0 + 16 + c0];
        pr[32 + c0] = acc2[e] + b_out[n0 + 32 + c0];
        pr[48 + c0] = acc3[e] + b_out[n0 + 48 + c0];
    }
}

extern "C" void kernel_launch(void* const* d_in, const int* in_sizes, int n_in,
                              void* d_out, int out_size, void* d_ws, size_t ws_size,
                              hipStream_t stream) {
    const float* s     = (const float*)d_in[0];
    const float* rot   = (const float*)d_in[2];
    const float* trans = (const float*)d_in[3];
    const float* mask  = (const float*)d_in[4];
    const float* w_q   = (const float*)d_in[5];
    const float* b_q   = (const float*)d_in[6];
    const float* w_kv  = (const float*)d_in[7];
    const float* b_kv  = (const float*)d_in[8];
    const float* w_qp  = (const float*)d_in[13];
    const float* b_qp  = (const float*)d_in[14];
    const float* w_kvp = (const float*)d_in[15];
    const float* b_kvp = (const float*)d_in[16];
    const float* hwts  = (const float*)d_in[17];
    const float* w_out = (const float*)d_in[18];
    const float* b_out = (const float*)d_in[19];

    float* ws    = (float*)d_ws;
    float* proj  = ws + WS_PROJ;
    float* Kp    = ws + WS_KP;
    float* Vp    = ws + WS_VP;
    float* KPp   = ws + WS_KPP;
    float* VPp   = ws + WS_VPP;
    float* catb  = ws + WS_CAT;
    float* Qp    = ws + WS_QP;
    float* QPp   = ws + WS_QPP;
    float* partb = ws + WS_PART;
    short* wt    = (short*)(ws + WS_WT);
    short* wto   = (short*)(ws + WS_WTO);
    float* out   = (float*)d_out;

    hipLaunchKernelGGL(prep_kernel, dim3(2592), dim3(256), 0, stream,
                       w_q, w_kv, w_qp, w_kvp, w_out, wt, wto);
    hipLaunchKernelGGL(proj_kernel, dim3(432), dim3(256), 0, stream,
                       s, wt, b_q, b_kv, b_qp, b_kvp, proj);
    hipLaunchKernelGGL(pack_kernel, dim3(1536), dim3(192), 0, stream,
                       proj, rot, trans, hwts, Kp, Vp, KPp, VPp, Qp, QPp);
    hipLaunchKernelGGL(attn_part_kernel, dim3(1728), dim3(256), 0, stream,
                       Qp, QPp, Kp, Vp, KPp, VPp, mask, hwts, partb);
    hipLaunchKernelGGL(attn_merge_kernel, dim3(288), dim3(256), 0, stream,
                       partb, rot, trans, catb);
    hipLaunchKernelGGL(out_kernel, dim3(144), dim3(256), 0, stream,
                       catb, wto, b_out, out);
}

// Round 12
// 60.196 us; speedup vs baseline: 2.1684x; 1.1555x over previous
//
#include <hip/hip_runtime.h>
#include <math.h>

#define Bb 4
#define Nn 384
#define CSs 384
#define Hh 12
#define Cc 16
#define PQq 4
#define PVv 8
#define FPROJ 1152
#define FCAT 576
#define INFV 100000.0f
#define EPSV 1e-8f

// ws layout (floats)
#define WS_PROJ 0
#define WS_KP   1769472
#define WS_VP   2064384
#define WS_KPP  2359296
#define WS_VPP  2580480
#define WS_CAT  3022848
#define WS_QP   3907584
#define WS_QPP  4202496
#define WS_PART 4423680
#define PSTRIDE 2688
#define WS_WT   9068544
#define WS_WTO  9289728

typedef __attribute__((ext_vector_type(8))) short short8v;
typedef __attribute__((ext_vector_type(4))) float f32x4;

__device__ __forceinline__ short f2bf(float x) {
    unsigned u = __float_as_uint(x);
    unsigned r = (u + 0x7FFFu + ((u >> 16) & 1u)) >> 16;
    return (short)r;
}

__device__ __forceinline__ float get_bias(int f,
    const float* __restrict__ b_q, const float* __restrict__ b_kv,
    const float* __restrict__ b_qp, const float* __restrict__ b_kvp)
{
    if (f < 192) return b_q[f];
    if (f < 576) return b_kv[f - 192];
    if (f < 720) return b_qp[f - 576];
    return b_kvp[f - 720];
}

// ---------------- Kernel 0: weight prep (r11, unchanged) ----------------
__global__ __launch_bounds__(256) void prep_kernel(
    const float* __restrict__ w_q, const float* __restrict__ w_kv,
    const float* __restrict__ w_qp, const float* __restrict__ w_kvp,
    const float* __restrict__ w_out,
    short* __restrict__ wt, short* __restrict__ wto)
{
    int idx = blockIdx.x * 256 + threadIdx.x;
    if (idx < 1152 * 384) {
        int f = idx / 384, k = idx % 384;
        float v;
        if (f < 192)      v = w_q[(size_t)k * 192 + f];
        else if (f < 576) v = w_kv[(size_t)k * 384 + (f - 192)];
        else if (f < 720) v = w_qp[(size_t)k * 144 + (f - 576)];
        else              v = w_kvp[(size_t)k * 432 + (f - 720)];
        wt[idx] = f2bf(v);
    } else if (idx < 1152 * 384 + 384 * 576) {
        int j = idx - 1152 * 384;
        int f = j / 576, k = j % 576;
        wto[j] = f2bf(w_out[(size_t)k * 384 + f]);
    }
}

// ---------------- Kernel 1: projection GEMM via bf16 MFMA (r11, unchanged) ----------------
__global__ __launch_bounds__(256) void proj_kernel(
    const float* __restrict__ s, const short* __restrict__ wt,
    const float* __restrict__ b_q, const float* __restrict__ b_kv,
    const float* __restrict__ b_qp, const float* __restrict__ b_kvp,
    float* __restrict__ proj)
{
    __shared__ short Al[64 * 40];
    __shared__ short Bl[64 * 40];

    const int bm = blockIdx.x % 24;
    const int bn = blockIdx.x / 24;
    const int m0 = bm * 64;
    const int f0 = bn * 64;
    const int t = threadIdx.x;
    const int w = t >> 6;
    const int lane = t & 63;
    const int lrow = lane & 15;
    const int lkg  = lane >> 4;

    const int srow = t >> 2;
    const int sseg = t & 3;

    f32x4 acc0 = {0,0,0,0}, acc1 = {0,0,0,0}, acc2 = {0,0,0,0}, acc3 = {0,0,0,0};

    for (int ks = 0; ks < 12; ++ks) {
        const int kbase = ks * 32;
        {
            const float* sp = s + (size_t)(m0 + srow) * CSs + kbase + sseg * 8;
            float4 v0 = *(const float4*)sp;
            float4 v1 = *(const float4*)(sp + 4);
            short8v a;
            a[0]=f2bf(v0.x); a[1]=f2bf(v0.y); a[2]=f2bf(v0.z); a[3]=f2bf(v0.w);
            a[4]=f2bf(v1.x); a[5]=f2bf(v1.y); a[6]=f2bf(v1.z); a[7]=f2bf(v1.w);
            *(short8v*)&Al[srow * 40 + sseg * 8] = a;
        }
        {
            short8v bvv = *(const short8v*)&wt[(size_t)(f0 + srow) * 384 + kbase + sseg * 8];
            *(short8v*)&Bl[srow * 40 + sseg * 8] = bvv;
        }
        __syncthreads();

        short8v av = *(const short8v*)&Al[(16 * w + lrow) * 40 + lkg * 8];
        short8v b0 = *(const short8v*)&Bl[(lrow) * 40 + lkg * 8];
        short8v b1 = *(const short8v*)&Bl[(16 + lrow) * 40 + lkg * 8];
        short8v b2 = *(const short8v*)&Bl[(32 + lrow) * 40 + lkg * 8];
        short8v b3 = *(const short8v*)&Bl[(48 + lrow) * 40 + lkg * 8];
        acc0 = __builtin_amdgcn_mfma_f32_16x16x32_bf16(av, b0, acc0, 0, 0, 0);
        acc1 = __builtin_amdgcn_mfma_f32_16x16x32_bf16(av, b1, acc1, 0, 0, 0);
        acc2 = __builtin_amdgcn_mfma_f32_16x16x32_bf16(av, b2, acc2, 0, 0, 0);
        acc3 = __builtin_amdgcn_mfma_f32_16x16x32_bf16(av, b3, acc3, 0, 0, 0);
        __syncthreads();
    }

    const int orow = m0 + 16 * w + lkg * 4;
#pragma unroll
    for (int e = 0; e < 4; ++e) {
        float* pr = proj + (size_t)(orow + e) * FPROJ + f0;
        int c0 = lrow;
        pr[c0]      = acc0[e] + get_bias(f0 + c0,      b_q, b_kv, b_qp, b_kvp);
        pr[16 + c0] = acc1[e] + get_bias(f0 + 16 + c0, b_q, b_kv, b_qp, b_kvp);
        pr[32 + c0] = acc2[e] + get_bias(f0 + 32 + c0, b_q, b_kv, b_qp, b_kvp);
        pr[48 + c0] = acc3[e] + get_bias(f0 + 48 + c0, b_q, b_kv, b_qp, b_kvp);
    }
}

// ---------------- Kernel 2: rigid-apply + pack (r11, unchanged) ----------------
__global__ __launch_bounds__(192) void pack_kernel(
    const float* __restrict__ proj,
    const float* __restrict__ rot, const float* __restrict__ trans,
    const float* __restrict__ hwts,
    float* __restrict__ Kp, float* __restrict__ Vp,
    float* __restrict__ KPp, float* __restrict__ VPp,
    float* __restrict__ Qp, float* __restrict__ QPp)
{
    const int bn = blockIdx.x;
    const int b = bn / Nn;
    const int n = bn % Nn;
    const int t = threadIdx.x;
    const float* R = rot + (size_t)bn * 9;
    const float* T = trans + (size_t)bn * 3;
    const float* pr = proj + (size_t)bn * FPROJ;

    if (t < 144) {
        float x = pr[720 + t];
        float y = pr[720 + 144 + t];
        float z = pr[720 + 288 + t];
        float ox = R[0]*x + R[1]*y + R[2]*z + T[0];
        float oy = R[3]*x + R[4]*y + R[5]*z + T[1];
        float oz = R[6]*x + R[7]*y + R[8]*z + T[2];
        int h = t / 12, pp = t % 12;
        int bh = b * Hh + h;
        if (pp < PQq) {
            float* o = KPp + ((size_t)(bh * Nn + n)) * 12 + pp * 3;
            o[0] = ox; o[1] = oy; o[2] = oz;
        } else {
            float* o = VPp + ((size_t)(bh * Nn + n)) * 24 + (pp - PQq) * 3;
            o[0] = ox; o[1] = oy; o[2] = oz;
        }
    }
    if (t < 48) {
        float x = pr[576 + t];
        float y = pr[576 + 48 + t];
        float z = pr[576 + 96 + t];
        float ox = R[0]*x + R[1]*y + R[2]*z + T[0];
        float oy = R[3]*x + R[4]*y + R[5]*z + T[1];
        float oz = R[6]*x + R[7]*y + R[8]*z + T[2];
        int h = t / 4, p = t % 4;
        float hw2 = log1pf(expf(hwts[h]));
        float n2wc = hw2 * 0.13608276348795434f;
        float* o = QPp + ((size_t)((b * Hh + h) * Nn + n)) * 12 + p * 3;
        o[0] = n2wc * ox; o[1] = n2wc * oy; o[2] = n2wc * oz;
    }
#pragma unroll
    for (int rep = 0; rep < 2; ++rep) {
        int idx = t + rep * 192;
        {
            int h = idx / 32, c2 = idx % 32;
            int bh = b * Hh + h;
            float v = pr[192 + h * 32 + c2];
            if (c2 < 16) Kp[((size_t)(bh * Nn + n)) * 16 + c2] = v;
            else         Vp[((size_t)(bh * Nn + n)) * 16 + (c2 - 16)] = v;
        }
        if (idx < 192) {
            int h = idx >> 4, c = idx & 15;
            int bh = b * Hh + h;
            Qp[((size_t)(bh * Nn + n)) * 16 + c] = 0.28867513459481287f * pr[idx];
        }
    }
}

// ---------------- Kernel 3a: attention partial via MFMA ----------------
// grid 1728, 256 threads (4 waves). Logits: split-bf16 (hi/lo) 3-MFMA; PV: bf16.
// LDS 27.4 KB: A/K hi+lo [64][40] bf16; V^T [48][72] bf16; P [64][72] bf16
// aliases the dead A/K region after logits.
__device__ __forceinline__ void store_hilo(short* H, short* L, int off, const float* vals) {
    short8v h0, h1, l0, l1;
#pragma unroll
    for (int k = 0; k < 8; ++k) {
        short hh = f2bf(vals[k]);
        float hf = __uint_as_float(((unsigned)(unsigned short)hh) << 16);
        h0[k] = hh; l0[k] = f2bf(vals[k] - hf);
    }
#pragma unroll
    for (int k = 0; k < 8; ++k) {
        short hh = f2bf(vals[k + 8]);
        float hf = __uint_as_float(((unsigned)(unsigned short)hh) << 16);
        h1[k] = hh; l1[k] = f2bf(vals[k + 8] - hf);
    }
    *(short8v*)&H[off]     = h0; *(short8v*)&H[off + 8] = h1;
    *(short8v*)&L[off]     = l0; *(short8v*)&L[off + 8] = l1;
}

__global__ __launch_bounds__(256) void attn_part_kernel(
    const float* __restrict__ Qp, const float* __restrict__ QPp,
    const float* __restrict__ Kp, const float* __restrict__ Vp,
    const float* __restrict__ KPp, const float* __restrict__ VPp,
    const float* __restrict__ mask, const float* __restrict__ hwts,
    float* __restrict__ part)
{
    __shared__ short smem_s[13696];      // 27392 B
    short* Ahi = smem_s;                 // [64][40]
    short* Alo = smem_s + 2560;
    short* Khi = smem_s + 5120;
    short* Klo = smem_s + 7680;
    short* Vb  = smem_s + 10240;         // [48][72]
    short* Pb  = smem_s;                 // [64][72], aliases A/K after logits

    const int bid = blockIdx.x;
    const int jc = bid % 6;
    const int ic = (bid / 6) % 6;
    const int h  = (bid / 36) % Hh;
    const int b  = bid / (36 * Hh);
    const int t  = threadIdx.x;
    const int i0 = ic * 64;
    const int j0 = jc * 64;
    const int bh = b * Hh + h;

    const float hw = log1pf(expf(hwts[h]));
    const float wc = -0.5f * hw * 0.13608276348795434f;

    const float* QpB  = Qp  + ((size_t)(bh * Nn + i0)) * 16;
    const float* QPpB = QPp + ((size_t)(bh * Nn + i0)) * 12;
    const float* KpB  = Kp  + ((size_t)(bh * Nn + j0)) * 16;
    const float* VpB  = Vp  + ((size_t)(bh * Nn + j0)) * 16;
    const float* KPpB = KPp + ((size_t)(bh * Nn + j0)) * 12;
    const float* VPpB = VPp + ((size_t)(bh * Nn + j0)) * 24;
    const float* mb   = mask + b * Nn;

    // ---- staging phase 1: A' (t<128) and K' (t>=128), hi/lo bf16 ----
    if (t < 128) {
        const int i = t >> 1, half = t & 1;
        float vals[16];
        if (half == 0) {
            float4 a0 = *(const float4*)(QpB + i * 16);
            float4 a1 = *(const float4*)(QpB + i * 16 + 4);
            float4 a2 = *(const float4*)(QpB + i * 16 + 8);
            float4 a3 = *(const float4*)(QpB + i * 16 + 12);
            vals[0]=a0.x; vals[1]=a0.y; vals[2]=a0.z; vals[3]=a0.w;
            vals[4]=a1.x; vals[5]=a1.y; vals[6]=a1.z; vals[7]=a1.w;
            vals[8]=a2.x; vals[9]=a2.y; vals[10]=a2.z; vals[11]=a2.w;
            vals[12]=a3.x; vals[13]=a3.y; vals[14]=a3.z; vals[15]=a3.w;
        } else {
            float4 a0 = *(const float4*)(QPpB + i * 12);
            float4 a1 = *(const float4*)(QPpB + i * 12 + 4);
            float4 a2 = *(const float4*)(QPpB + i * 12 + 8);
            vals[0]=a0.x; vals[1]=a0.y; vals[2]=a0.z; vals[3]=a0.w;
            vals[4]=a1.x; vals[5]=a1.y; vals[6]=a1.z; vals[7]=a1.w;
            vals[8]=a2.x; vals[9]=a2.y; vals[10]=a2.z; vals[11]=a2.w;
            vals[12] = 1.0f;
            vals[13] = mb[i0 + i];
            vals[14] = 0.0f; vals[15] = 0.0f;
        }
        store_hilo(Ahi, Alo, i * 40 + half * 16, vals);
    } else {
        const int tt = t - 128, j = tt >> 1, half = tt & 1;
        float vals[16];
        if (half == 0) {
            float4 a0 = *(const float4*)(KpB + j * 16);
            float4 a1 = *(const float4*)(KpB + j * 16 + 4);
            float4 a2 = *(const float4*)(KpB + j * 16 + 8);
            float4 a3 = *(const float4*)(KpB + j * 16 + 12);
            vals[0]=a0.x; vals[1]=a0.y; vals[2]=a0.z; vals[3]=a0.w;
            vals[4]=a1.x; vals[5]=a1.y; vals[6]=a1.z; vals[7]=a1.w;
            vals[8]=a2.x; vals[9]=a2.y; vals[10]=a2.z; vals[11]=a2.w;
            vals[12]=a3.x; vals[13]=a3.y; vals[14]=a3.z; vals[15]=a3.w;
        } else {
            float4 a0 = *(const float4*)(KPpB + j * 12);
            float4 a1 = *(const float4*)(KPpB + j * 12 + 4);
            float4 a2 = *(const float4*)(KPpB + j * 12 + 8);
            vals[0]=a0.x; vals[1]=a0.y; vals[2]=a0.z; vals[3]=a0.w;
            vals[4]=a1.x; vals[5]=a1.y; vals[6]=a1.z; vals[7]=a1.w;
            vals[8]=a2.x; vals[9]=a2.y; vals[10]=a2.z; vals[11]=a2.w;
            float sq = a0.x*a0.x + a0.y*a0.y + a0.z*a0.z + a0.w*a0.w
                     + a1.x*a1.x + a1.y*a1.y + a1.z*a1.z + a1.w*a1.w
                     + a2.x*a2.x + a2.y*a2.y + a2.z*a2.z + a2.w*a2.w;
            vals[12] = wc * sq;
            vals[13] = INFV * (mb[j0 + j] - 1.0f);
            vals[14] = 0.0f; vals[15] = 0.0f;
        }
        store_hilo(Khi, Klo, j * 40 + half * 16, vals);
    }
    // ---- staging phase 2: V^T bf16 (t<128), zero pad rows (t>=128) ----
    if (t < 128) {
        const int j = t >> 1, q = t & 1;
        float vv[20];
        if (q == 0) {
            float4 a0 = *(const float4*)(VpB + j * 16);
            float4 a1 = *(const float4*)(VpB + j * 16 + 4);
            float4 a2 = *(const float4*)(VpB + j * 16 + 8);
            float4 a3 = *(const float4*)(VpB + j * 16 + 12);
            float4 a4 = *(const float4*)(VPpB + j * 24);
            vv[0]=a0.x; vv[1]=a0.y; vv[2]=a0.z; vv[3]=a0.w;
            vv[4]=a1.x; vv[5]=a1.y; vv[6]=a1.z; vv[7]=a1.w;
            vv[8]=a2.x; vv[9]=a2.y; vv[10]=a2.z; vv[11]=a2.w;
            vv[12]=a3.x; vv[13]=a3.y; vv[14]=a3.z; vv[15]=a3.w;
            vv[16]=a4.x; vv[17]=a4.y; vv[18]=a4.z; vv[19]=a4.w;
        } else {
            float4 a0 = *(const float4*)(VPpB + j * 24 + 4);
            float4 a1 = *(const float4*)(VPpB + j * 24 + 8);
            float4 a2 = *(const float4*)(VPpB + j * 24 + 12);
            float4 a3 = *(const float4*)(VPpB + j * 24 + 16);
            float4 a4 = *(const float4*)(VPpB + j * 24 + 20);
            vv[0]=a0.x; vv[1]=a0.y; vv[2]=a0.z; vv[3]=a0.w;
            vv[4]=a1.x; vv[5]=a1.y; vv[6]=a1.z; vv[7]=a1.w;
            vv[8]=a2.x; vv[9]=a2.y; vv[10]=a2.z; vv[11]=a2.w;
            vv[12]=a3.x; vv[13]=a3.y; vv[14]=a3.z; vv[15]=a3.w;
            vv[16]=a4.x; vv[17]=a4.y; vv[18]=a4.z; vv[19]=a4.w;
        }
        const int c0 = q * 20;
#pragma unroll
        for (int k = 0; k < 20; ++k)
            Vb[(c0 + k) * 72 + j] = f2bf(vv[k]);
    } else {
        const int tt = t - 128;
        const int r = 40 + (tt >> 4);
        const int c0 = (tt & 15) * 4;
        Vb[r * 72 + c0 + 0] = 0; Vb[r * 72 + c0 + 1] = 0;
        Vb[r * 72 + c0 + 2] = 0; Vb[r * 72 + c0 + 3] = 0;
    }
    __syncthreads();

    // ---- logits: 12 MFMAs (4 j-subtiles x {hi*hi, lo*hi, hi*lo}) ----
    const int w = t >> 6;
    const int lane = t & 63;
    const int lrow = lane & 15;
    const int lkg  = lane >> 4;

    f32x4 La0 = {0,0,0,0}, La1 = {0,0,0,0}, La2 = {0,0,0,0}, La3 = {0,0,0,0};
    {
        short8v ahi = *(const short8v*)&Ahi[(16 * w + lrow) * 40 + lkg * 8];
        short8v alo = *(const short8v*)&Alo[(16 * w + lrow) * 40 + lkg * 8];
        short8v k0h = *(const short8v*)&Khi[(lrow) * 40 + lkg * 8];
        short8v k1h = *(const short8v*)&Khi[(16 + lrow) * 40 + lkg * 8];
        short8v k2h = *(const short8v*)&Khi[(32 + lrow) * 40 + lkg * 8];
        short8v k3h = *(const short8v*)&Khi[(48 + lrow) * 40 + lkg * 8];
        short8v k0l = *(const short8v*)&Klo[(lrow) * 40 + lkg * 8];
        short8v k1l = *(const short8v*)&Klo[(16 + lrow) * 40 + lkg * 8];
        short8v k2l = *(const short8v*)&Klo[(32 + lrow) * 40 + lkg * 8];
        short8v k3l = *(const short8v*)&Klo[(48 + lrow) * 40 + lkg * 8];
        La0 = __builtin_amdgcn_mfma_f32_16x16x32_bf16(ahi, k0h, La0, 0, 0, 0);
        La1 = __builtin_amdgcn_mfma_f32_16x16x32_bf16(ahi, k1h, La1, 0, 0, 0);
        La2 = __builtin_amdgcn_mfma_f32_16x16x32_bf16(ahi, k2h, La2, 0, 0, 0);
        La3 = __builtin_amdgcn_mfma_f32_16x16x32_bf16(ahi, k3h, La3, 0, 0, 0);
        La0 = __builtin_amdgcn_mfma_f32_16x16x32_bf16(alo, k0h, La0, 0, 0, 0);
        La1 = __builtin_amdgcn_mfma_f32_16x16x32_bf16(alo, k1h, La1, 0, 0, 0);
        La2 = __builtin_amdgcn_mfma_f32_16x16x32_bf16(alo, k2h, La2, 0, 0, 0);
        La3 = __builtin_amdgcn_mfma_f32_16x16x32_bf16(alo, k3h, La3, 0, 0, 0);
        La0 = __builtin_amdgcn_mfma_f32_16x16x32_bf16(ahi, k0l, La0, 0, 0, 0);
        La1 = __builtin_amdgcn_mfma_f32_16x16x32_bf16(ahi, k1l, La1, 0, 0, 0);
        La2 = __builtin_amdgcn_mfma_f32_16x16x32_bf16(ahi, k2l, La2, 0, 0, 0);
        La3 = __builtin_amdgcn_mfma_f32_16x16x32_bf16(ahi, k3l, La3, 0, 0, 0);
    }

    // ---- softmax in C-layout: row = 16w + 4*lkg + e, col = 16*jsub + lrow ----
    const size_t pidx = ((size_t)(bh * 6 + ic)) * 6 + jc;
    float* po = part + pidx * PSTRIDE;

    float m0_, m1_, m2_, m3_, s0_, s1_, s2_, s3_;
    float p00,p10,p20,p30, p01,p11,p21,p31, p02,p12,p22,p32, p03,p13,p23,p33;

#define SMAX_E(E, TM, SM, P0, P1, P2, P3) { \
    float tmax_ = fmaxf(fmaxf(La0[E], La1[E]), fmaxf(La2[E], La3[E])); \
    tmax_ = fmaxf(tmax_, __shfl_xor(tmax_, 1)); \
    tmax_ = fmaxf(tmax_, __shfl_xor(tmax_, 2)); \
    tmax_ = fmaxf(tmax_, __shfl_xor(tmax_, 4)); \
    tmax_ = fmaxf(tmax_, __shfl_xor(tmax_, 8)); \
    P0 = __expf(La0[E] - tmax_); P1 = __expf(La1[E] - tmax_); \
    P2 = __expf(La2[E] - tmax_); P3 = __expf(La3[E] - tmax_); \
    float cs_ = P0 + P1 + P2 + P3; \
    cs_ += __shfl_xor(cs_, 1); cs_ += __shfl_xor(cs_, 2); \
    cs_ += __shfl_xor(cs_, 4); cs_ += __shfl_xor(cs_, 8); \
    TM = tmax_; SM = cs_; }

    SMAX_E(0, m0_, s0_, p00, p10, p20, p30);
    SMAX_E(1, m1_, s1_, p01, p11, p21, p31);
    SMAX_E(2, m2_, s2_, p02, p12, p22, p32);
    SMAX_E(3, m3_, s3_, p03, p13, p23, p33);
#undef SMAX_E

    if (lrow == 0) {
        int rb = 16 * w + 4 * lkg;
        po[2560 + rb + 0] = m0_; po[2624 + rb + 0] = s0_;
        po[2560 + rb + 1] = m1_; po[2624 + rb + 1] = s1_;
        po[2560 + rb + 2] = m2_; po[2624 + rb + 2] = s2_;
        po[2560 + rb + 3] = m3_; po[2624 + rb + 3] = s3_;
    }
    __syncthreads();    // A/K reads complete before Pb aliases the region

    // ---- write P to LDS [i][j] bf16 ----
#define PW(E, PJ0, PJ1, PJ2, PJ3) { \
    int r_ = (16 * w + 4 * lkg + E) * 72; \
    Pb[r_ + lrow]      = f2bf(PJ0); \
    Pb[r_ + 16 + lrow] = f2bf(PJ1); \
    Pb[r_ + 32 + lrow] = f2bf(PJ2); \
    Pb[r_ + 48 + lrow] = f2bf(PJ3); }
    PW(0, p00, p10, p20, p30);
    PW(1, p01, p11, p21, p31);
    PW(2, p02, p12, p22, p32);
    PW(3, p03, p13, p23, p33);
#undef PW
    __syncthreads();

    // ---- PV: 6 MFMAs (3 c-subtiles x 2 k-chunks) ----
    f32x4 O0 = {0,0,0,0}, O1 = {0,0,0,0}, O2 = {0,0,0,0};
#pragma unroll
    for (int ch = 0; ch < 2; ++ch) {
        short8v pf = *(const short8v*)&Pb[(16 * w + lrow) * 72 + ch * 32 + lkg * 8];
        short8v v0 = *(const short8v*)&Vb[(lrow) * 72 + ch * 32 + lkg * 8];
        short8v v1 = *(const short8v*)&Vb[(16 + lrow) * 72 + ch * 32 + lkg * 8];
        short8v v2 = *(const short8v*)&Vb[(32 + lrow) * 72 + ch * 32 + lkg * 8];
        O0 = __builtin_amdgcn_mfma_f32_16x16x32_bf16(pf, v0, O0, 0, 0, 0);
        O1 = __builtin_amdgcn_mfma_f32_16x16x32_bf16(pf, v1, O1, 0, 0, 0);
        O2 = __builtin_amdgcn_mfma_f32_16x16x32_bf16(pf, v2, O2, 0, 0, 0);
    }
#pragma unroll
    for (int e = 0; e < 4; ++e) {
        int r = 16 * w + 4 * lkg + e;
        po[r * 40 + lrow]      = O0[e];
        po[r * 40 + 16 + lrow] = O1[e];
        if (lrow < 8) po[r * 40 + 32 + lrow] = O2[e];
    }
}

// ---------------- Kernel 3b: merge partials + epilogue (r11, unchanged) ----------------
__global__ __launch_bounds__(256) void attn_merge_kernel(
    const float* __restrict__ part,
    const float* __restrict__ rot, const float* __restrict__ trans,
    float* __restrict__ cat)
{
    __shared__ float wsh[64 * 8];
    __shared__ float ob[64 * 44];

    const int bid = blockIdx.x;
    const int ic = bid % 6;
    const int h  = (bid / 6) % Hh;
    const int b  = bid / (6 * Hh);
    const int t  = threadIdx.x;
    const int i0 = ic * 64;
    const int bh = b * Hh + h;
    const size_t pbase = (((size_t)(bh * 6 + ic)) * 6) * PSTRIDE;

    if (t < 64) {
        float mk[6], sk[6];
        float M = -3.0e38f;
#pragma unroll
        for (int k = 0; k < 6; ++k) {
            mk[k] = part[pbase + (size_t)k * PSTRIDE + 2560 + t];
            sk[k] = part[pbase + (size_t)k * PSTRIDE + 2624 + t];
            M = fmaxf(M, mk[k]);
        }
        float wk[6]; float stot = 0.0f;
#pragma unroll
        for (int k = 0; k < 6; ++k) {
            wk[k] = __expf(mk[k] - M);
            stot += wk[k] * sk[k];
        }
        float inv = 1.0f / stot;
#pragma unroll
        for (int k = 0; k < 6; ++k) wsh[t * 8 + k] = wk[k] * inv;
    }
    __syncthreads();

#pragma unroll
    for (int it = 0; it < 10; ++it) {
        int idx = t + it * 256;
        int row = idx / 40, col = idx % 40;
        float v = 0.0f;
#pragma unroll
        for (int k = 0; k < 6; ++k)
            v += wsh[row * 8 + k] * part[pbase + (size_t)k * PSTRIDE + row * 40 + col];
        ob[row * 44 + col] = v;
    }
    __syncthreads();

    {
        const int i = t >> 2;
        const int qq = t & 3;
        const int bnI = b * Nn + i0 + i;
        float* crow = cat + (size_t)bnI * FCAT;

        float4 o = *(const float4*)&ob[i * 44 + 4 * qq];
        *(float4*)&crow[h * 16 + 4 * qq] = o;

        const float* R = rot + (size_t)bnI * 9;
        const float* T = trans + (size_t)bnI * 3;
#pragma unroll
        for (int e = 0; e < 2; ++e) {
            int pe = qq + 4 * e;
            float g0 = ob[i * 44 + 16 + 3 * pe + 0] - T[0];
            float g1 = ob[i * 44 + 16 + 3 * pe + 1] - T[1];
            float g2 = ob[i * 44 + 16 + 3 * pe + 2] - T[2];
            float lx = R[0]*g0 + R[3]*g1 + R[6]*g2;
            float ly = R[1]*g0 + R[4]*g1 + R[7]*g2;
            float lz = R[2]*g0 + R[5]*g1 + R[8]*g2;
            crow[192 + h * 8 + pe] = lx;
            crow[288 + h * 8 + pe] = ly;
            crow[384 + h * 8 + pe] = lz;
            crow[480 + h * 8 + pe] = sqrtf(lx*lx + ly*ly + lz*lz + EPSV);
        }
    }
}

// ---------------- Kernel 4: output GEMM via bf16 MFMA (r11, unchanged) ----------------
__global__ __launch_bounds__(256) void out_kernel(
    const float* __restrict__ cat, const short* __restrict__ wto,
    const float* __restrict__ b_out, float* __restrict__ out)
{
    __shared__ short Al[64 * 40];
    __shared__ short Bl[64 * 40];

    const int bm = blockIdx.x % 24;
    const int bn = blockIdx.x / 24;
    const int m0 = bm * 64;
    const int n0 = bn * 64;
    const int t = threadIdx.x;
    const int w = t >> 6;
    const int lane = t & 63;
    const int lrow = lane & 15;
    const int lkg  = lane >> 4;

    const int srow = t >> 2;
    const int sseg = t & 3;

    f32x4 acc0 = {0,0,0,0}, acc1 = {0,0,0,0}, acc2 = {0,0,0,0}, acc3 = {0,0,0,0};

    for (int ks = 0; ks < 18; ++ks) {
        const int kbase = ks * 32;
        {
            const float* cp = cat + (size_t)(m0 + srow) * FCAT + kbase + sseg * 8;
            float4 v0 = *(const float4*)cp;
            float4 v1 = *(const float4*)(cp + 4);
            short8v a;
            a[0]=f2bf(v0.x); a[1]=f2bf(v0.y); a[2]=f2bf(v0.z); a[3]=f2bf(v0.w);
            a[4]=f2bf(v1.x); a[5]=f2bf(v1.y); a[6]=f2bf(v1.z); a[7]=f2bf(v1.w);
            *(short8v*)&Al[srow * 40 + sseg * 8] = a;
        }
        {
            short8v bvv = *(const short8v*)&wto[(size_t)(n0 + srow) * FCAT + kbase + sseg * 8];
            *(short8v*)&Bl[srow * 40 + sseg * 8] = bvv;
        }
        __syncthreads();

        short8v av = *(const short8v*)&Al[(16 * w + lrow) * 40 + lkg * 8];
        short8v b0 = *(const short8v*)&Bl[(lrow) * 40 + lkg * 8];
        short8v b1 = *(const short8v*)&Bl[(16 + lrow) * 40 + lkg * 8];
        short8v b2 = *(const short8v*)&Bl[(32 + lrow) * 40 + lkg * 8];
        short8v b3 = *(const short8v*)&Bl[(48 + lrow) * 40 + lkg * 8];
        acc0 = __builtin_amdgcn_mfma_f32_16x16x32_bf16(av, b0, acc0, 0, 0, 0);
        acc1 = __builtin_amdgcn_mfma_f32_16x16x32_bf16(av, b1, acc1, 0, 0, 0);
        acc2 = __builtin_amdgcn_mfma_f32_16x16x32_bf16(av, b2, acc2, 0, 0, 0);
        acc3 = __builtin_amdgcn_mfma_f32_16x16x32_bf16(av, b3, acc3, 0, 0, 0);
        __syncthreads();
    }

    const int orow = m0 + 16 * w + lkg * 4;
#pragma unroll
    for (int e = 0; e < 4; ++e) {
        float* pr = out + (size_t)(orow + e) * 384 + n0;
        int c0 = lrow;
        pr[c0]      = acc0[e] + b_out[n0 + c0];
        pr[16 + c0] = acc1[e] + b_out[n0 + 16 + c0];
        pr[32 + c0] = acc2[e] + b_out[n0 + 32 + c0];
        pr[48 + c0] = acc3[e] + b_out[n0 + 48 + c0];
    }
}

extern "C" void kernel_launch(void* const* d_in, const int* in_sizes, int n_in,
                              void* d_out, int out_size, void* d_ws, size_t ws_size,
                              hipStream_t stream) {
    const float* s     = (const float*)d_in[0];
    const float* rot   = (const float*)d_in[2];
    const float* trans = (const float*)d_in[3];
    const float* mask  = (const float*)d_in[4];
    const float* w_q   = (const float*)d_in[5];
    const float* b_q   = (const float*)d_in[6];
    const float* w_kv  = (const float*)d_in[7];
    const float* b_kv  = (const float*)d_in[8];
    const float* w_qp  = (const float*)d_in[13];
    const float* b_qp  = (const float*)d_in[14];
    const float* w_kvp = (const float*)d_in[15];
    const float* b_kvp = (const float*)d_in[16];
    const float* hwts  = (const float*)d_in[17];
    const float* w_out = (const float*)d_in[18];
    const float* b_out = (const float*)d_in[19];

    float* ws    = (float*)d_ws;
    float* proj  = ws + WS_PROJ;
    float* Kp    = ws + WS_KP;
    float* Vp    = ws + WS_VP;
    float* KPp   = ws + WS_KPP;
    float* VPp   = ws + WS_VPP;
    float* catb  = ws + WS_CAT;
    float* Qp    = ws + WS_QP;
    float* QPp   = ws + WS_QPP;
    float* partb = ws + WS_PART;
    short* wt    = (short*)(ws + WS_WT);
    short* wto   = (short*)(ws + WS_WTO);
    float* out   = (float*)d_out;

    hipLaunchKernelGGL(prep_kernel, dim3(2592), dim3(256), 0, stream,
                       w_q, w_kv, w_qp, w_kvp, w_out, wt, wto);
    hipLaunchKernelGGL(proj_kernel, dim3(432), dim3(256), 0, stream,
                       s, wt, b_q, b_kv, b_qp, b_kvp, proj);
    hipLaunchKernelGGL(pack_kernel, dim3(1536), dim3(192), 0, stream,
                       proj, rot, trans, hwts, Kp, Vp, KPp, VPp, Qp, QPp);
    hipLaunchKernelGGL(attn_part_kernel, dim3(1728), dim3(256), 0, stream,
                       Qp, QPp, Kp, Vp, KPp, VPp, mask, hwts, partb);
    hipLaunchKernelGGL(attn_merge_kernel, dim3(288), dim3(256), 0, stream,
                       partb, rot, trans, catb);
    hipLaunchKernelGGL(out_kernel, dim3(144), dim3(256), 0, stream,
                       catb, wto, b_out, out);
}

// Round 13
// 55.461 us; speedup vs baseline: 2.3535x; 1.0854x over previous
//
#include <hip/hip_runtime.h>
#include <math.h>

#define Bb 4
#define Nn 384
#define CSs 384
#define Hh 12
#define Cc 16
#define PQq 4
#define PVv 8
#define FPROJ 1152
#define FCAT 576
#define INFV 100000.0f
#define EPSV 1e-8f

// ws layout (float slots)
#define WS_PROJ 0
#define WS_CAT  3022848      // reused as bf16 cat: 1536*576 shorts
#define WS_PART 4423680      // 48*36 blocks, stride 2688
#define PSTRIDE 2688
#define WS_WT   9068544
#define WS_WTO  9289728
#define WS_AH   9400320      // 48*384*32 shorts = 294912 float slots
#define WS_AL   9695232
#define WS_KH   9990144
#define WS_KL   10285056
#define WS_VBP  10579968     // 48*384*40 shorts = 368640 float slots

typedef __attribute__((ext_vector_type(8))) short short8v;
typedef __attribute__((ext_vector_type(4))) float f32x4;

__device__ __forceinline__ short f2bf(float x) {
    unsigned u = __float_as_uint(x);
    unsigned r = (u + 0x7FFFu + ((u >> 16) & 1u)) >> 16;
    return (short)r;
}
__device__ __forceinline__ float bf2f(short h) {
    return __uint_as_float(((unsigned)(unsigned short)h) << 16);
}

__device__ __forceinline__ float get_bias(int f,
    const float* __restrict__ b_q, const float* __restrict__ b_kv,
    const float* __restrict__ b_qp, const float* __restrict__ b_kvp)
{
    if (f < 192) return b_q[f];
    if (f < 576) return b_kv[f - 192];
    if (f < 720) return b_qp[f - 576];
    return b_kvp[f - 720];
}

// ---------------- Kernel 0: weight prep (r12, unchanged) ----------------
__global__ __launch_bounds__(256) void prep_kernel(
    const float* __restrict__ w_q, const float* __restrict__ w_kv,
    const float* __restrict__ w_qp, const float* __restrict__ w_kvp,
    const float* __restrict__ w_out,
    short* __restrict__ wt, short* __restrict__ wto)
{
    int idx = blockIdx.x * 256 + threadIdx.x;
    if (idx < 1152 * 384) {
        int f = idx / 384, k = idx % 384;
        float v;
        if (f < 192)      v = w_q[(size_t)k * 192 + f];
        else if (f < 576) v = w_kv[(size_t)k * 384 + (f - 192)];
        else if (f < 720) v = w_qp[(size_t)k * 144 + (f - 576)];
        else              v = w_kvp[(size_t)k * 432 + (f - 720)];
        wt[idx] = f2bf(v);
    } else if (idx < 1152 * 384 + 384 * 576) {
        int j = idx - 1152 * 384;
        int f = j / 576, k = j % 576;
        wto[j] = f2bf(w_out[(size_t)k * 384 + f]);
    }
}

// ---------------- Kernel 1: projection GEMM via bf16 MFMA (r12, unchanged) ----------------
__global__ __launch_bounds__(256) void proj_kernel(
    const float* __restrict__ s, const short* __restrict__ wt,
    const float* __restrict__ b_q, const float* __restrict__ b_kv,
    const float* __restrict__ b_qp, const float* __restrict__ b_kvp,
    float* __restrict__ proj)
{
    __shared__ short Al[64 * 40];
    __shared__ short Bl[64 * 40];

    const int bm = blockIdx.x % 24;
    const int bn = blockIdx.x / 24;
    const int m0 = bm * 64;
    const int f0 = bn * 64;
    const int t = threadIdx.x;
    const int w = t >> 6;
    const int lane = t & 63;
    const int lrow = lane & 15;
    const int lkg  = lane >> 4;

    const int srow = t >> 2;
    const int sseg = t & 3;

    f32x4 acc0 = {0,0,0,0}, acc1 = {0,0,0,0}, acc2 = {0,0,0,0}, acc3 = {0,0,0,0};

    for (int ks = 0; ks < 12; ++ks) {
        const int kbase = ks * 32;
        {
            const float* sp = s + (size_t)(m0 + srow) * CSs + kbase + sseg * 8;
            float4 v0 = *(const float4*)sp;
            float4 v1 = *(const float4*)(sp + 4);
            short8v a;
            a[0]=f2bf(v0.x); a[1]=f2bf(v0.y); a[2]=f2bf(v0.z); a[3]=f2bf(v0.w);
            a[4]=f2bf(v1.x); a[5]=f2bf(v1.y); a[6]=f2bf(v1.z); a[7]=f2bf(v1.w);
            *(short8v*)&Al[srow * 40 + sseg * 8] = a;
        }
        {
            short8v bvv = *(const short8v*)&wt[(size_t)(f0 + srow) * 384 + kbase + sseg * 8];
            *(short8v*)&Bl[srow * 40 + sseg * 8] = bvv;
        }
        __syncthreads();

        short8v av = *(const short8v*)&Al[(16 * w + lrow) * 40 + lkg * 8];
        short8v b0 = *(const short8v*)&Bl[(lrow) * 40 + lkg * 8];
        short8v b1 = *(const short8v*)&Bl[(16 + lrow) * 40 + lkg * 8];
        short8v b2 = *(const short8v*)&Bl[(32 + lrow) * 40 + lkg * 8];
        short8v b3 = *(const short8v*)&Bl[(48 + lrow) * 40 + lkg * 8];
        acc0 = __builtin_amdgcn_mfma_f32_16x16x32_bf16(av, b0, acc0, 0, 0, 0);
        acc1 = __builtin_amdgcn_mfma_f32_16x16x32_bf16(av, b1, acc1, 0, 0, 0);
        acc2 = __builtin_amdgcn_mfma_f32_16x16x32_bf16(av, b2, acc2, 0, 0, 0);
        acc3 = __builtin_amdgcn_mfma_f32_16x16x32_bf16(av, b3, acc3, 0, 0, 0);
        __syncthreads();
    }

    const int orow = m0 + 16 * w + lkg * 4;
#pragma unroll
    for (int e = 0; e < 4; ++e) {
        float* pr = proj + (size_t)(orow + e) * FPROJ + f0;
        int c0 = lrow;
        pr[c0]      = acc0[e] + get_bias(f0 + c0,      b_q, b_kv, b_qp, b_kvp);
        pr[16 + c0] = acc1[e] + get_bias(f0 + 16 + c0, b_q, b_kv, b_qp, b_kvp);
        pr[32 + c0] = acc2[e] + get_bias(f0 + 32 + c0, b_q, b_kv, b_qp, b_kvp);
        pr[48 + c0] = acc3[e] + get_bias(f0 + 48 + c0, b_q, b_kv, b_qp, b_kvp);
    }
}

// ---------------- Kernel 2: pack v2 — rigid-apply + hi/lo bf16 operand build ----------------
// grid 1536 (one bn each), 192 threads. Emits pre-split bf16 A'/K' (32-dim padded)
// and bf16 V' (40-dim) so attn_part staging is pure copies.
__global__ __launch_bounds__(192) void pack_kernel(
    const float* __restrict__ proj,
    const float* __restrict__ rot, const float* __restrict__ trans,
    const float* __restrict__ hwts, const float* __restrict__ mask,
    short* __restrict__ Ah, short* __restrict__ Al,
    short* __restrict__ Kh, short* __restrict__ Kl,
    short* __restrict__ Vbp)
{
    __shared__ float abuf[12 * 32];
    __shared__ float kbuf[12 * 32];
    __shared__ float vbuf[12 * 40];
    __shared__ float kpsq[12 * 4];

    const int bn = blockIdx.x;
    const int b = bn / Nn;
    const int n = bn % Nn;
    const int t = threadIdx.x;
    const float* R = rot + (size_t)bn * 9;
    const float* T = trans + (size_t)bn * 3;
    const float* pr = proj + (size_t)bn * FPROJ;
    const float mi = mask[bn];

    if (t < 144) {
        float x = pr[720 + t];
        float y = pr[720 + 144 + t];
        float z = pr[720 + 288 + t];
        float ox = R[0]*x + R[1]*y + R[2]*z + T[0];
        float oy = R[3]*x + R[4]*y + R[5]*z + T[1];
        float oz = R[6]*x + R[7]*y + R[8]*z + T[2];
        int h = t / 12, pp = t % 12;
        if (pp < PQq) {
            kbuf[h*32 + 16 + pp*3 + 0] = ox;
            kbuf[h*32 + 16 + pp*3 + 1] = oy;
            kbuf[h*32 + 16 + pp*3 + 2] = oz;
            kpsq[h*4 + pp] = ox*ox + oy*oy + oz*oz;
        } else {
            vbuf[h*40 + 16 + (pp - PQq)*3 + 0] = ox;
            vbuf[h*40 + 16 + (pp - PQq)*3 + 1] = oy;
            vbuf[h*40 + 16 + (pp - PQq)*3 + 2] = oz;
        }
    }
    if (t < 48) {
        float x = pr[576 + t];
        float y = pr[576 + 48 + t];
        float z = pr[576 + 96 + t];
        float ox = R[0]*x + R[1]*y + R[2]*z + T[0];
        float oy = R[3]*x + R[4]*y + R[5]*z + T[1];
        float oz = R[6]*x + R[7]*y + R[8]*z + T[2];
        int h = t / 4, p = t % 4;
        float n2wc = log1pf(expf(hwts[h])) * 0.13608276348795434f;   // -2*wc
        abuf[h*32 + 16 + p*3 + 0] = n2wc * ox;
        abuf[h*32 + 16 + p*3 + 1] = n2wc * oy;
        abuf[h*32 + 16 + p*3 + 2] = n2wc * oz;
    }
    {
        int h = t >> 4, c = t & 15;
        abuf[h*32 + c] = 0.28867513459481287f * pr[h * 16 + c];      // scale2*q
        kbuf[h*32 + c] = pr[192 + h * 32 + c];
        vbuf[h*40 + c] = pr[192 + h * 32 + 16 + c];
    }
    if (t < 12) {
        abuf[t*32 + 28] = 1.0f;  abuf[t*32 + 29] = mi;
        abuf[t*32 + 30] = 0.0f;  abuf[t*32 + 31] = 0.0f;
        kbuf[t*32 + 29] = INFV * (mi - 1.0f);
        kbuf[t*32 + 30] = 0.0f;  kbuf[t*32 + 31] = 0.0f;
    }
    __syncthreads();
    if (t < 12) {
        float hw2 = log1pf(expf(hwts[t]));
        float wc = -0.5f * hw2 * 0.13608276348795434f;
        kbuf[t*32 + 28] = wc * (kpsq[t*4] + kpsq[t*4+1] + kpsq[t*4+2] + kpsq[t*4+3]);
    }
    __syncthreads();

    if (t < 48) {
        int h = t >> 2, pc = t & 3;
        const float* src = &abuf[h*32 + pc*8];
        short8v hi, lo;
#pragma unroll
        for (int k = 0; k < 8; ++k) {
            short hh = f2bf(src[k]);
            hi[k] = hh; lo[k] = f2bf(src[k] - bf2f(hh));
        }
        size_t off = ((size_t)((b * Hh + h) * Nn + n)) * 32 + pc * 8;
        *(short8v*)&Ah[off] = hi;
        *(short8v*)&Al[off] = lo;
    } else if (t < 96) {
        int tt = t - 48, h = tt >> 2, pc = tt & 3;
        const float* src = &kbuf[h*32 + pc*8];
        short8v hi, lo;
#pragma unroll
        for (int k = 0; k < 8; ++k) {
            short hh = f2bf(src[k]);
            hi[k] = hh; lo[k] = f2bf(src[k] - bf2f(hh));
        }
        size_t off = ((size_t)((b * Hh + h) * Nn + n)) * 32 + pc * 8;
        *(short8v*)&Kh[off] = hi;
        *(short8v*)&Kl[off] = lo;
    } else if (t < 156) {
        int tt = t - 96, h = tt / 5, pc = tt % 5;
        const float* src = &vbuf[h*40 + pc*8];
        short8v v;
#pragma unroll
        for (int k = 0; k < 8; ++k) v[k] = f2bf(src[k]);
        *(short8v*)&Vbp[((size_t)((b * Hh + h) * Nn + n)) * 40 + pc * 8] = v;
    }
}

// ---------------- Kernel 3a: attention partial via MFMA (prepacked staging) ----------------
__global__ __launch_bounds__(256) void attn_part_kernel(
    const short* __restrict__ Ah, const short* __restrict__ Al,
    const short* __restrict__ Kh, const short* __restrict__ Kl,
    const short* __restrict__ Vbp,
    float* __restrict__ part)
{
    __shared__ short smem_s[13696];      // 27392 B
    short* Ahi = smem_s;                 // [64][40]
    short* Alo = smem_s + 2560;
    short* Khi = smem_s + 5120;
    short* Klo = smem_s + 7680;
    short* Vb  = smem_s + 10240;         // [48][72]
    short* Pb  = smem_s;                 // [64][72], aliases A/K after logits

    const int bid = blockIdx.x;
    const int jc = bid % 6;
    const int ic = (bid / 6) % 6;
    const int h  = (bid / 36) % Hh;
    const int b  = bid / (36 * Hh);
    const int t  = threadIdx.x;
    const int i0 = ic * 64;
    const int j0 = jc * 64;
    const int bh = b * Hh + h;

    const short* AhB = Ah + ((size_t)(bh * Nn + i0)) * 32;
    const short* AlB = Al + ((size_t)(bh * Nn + i0)) * 32;
    const short* KhB = Kh + ((size_t)(bh * Nn + j0)) * 32;
    const short* KlB = Kl + ((size_t)(bh * Nn + j0)) * 32;
    const short* VbB = Vbp + ((size_t)(bh * Nn + j0)) * 40;

    // ---- staging: pure short8 copies + V transpose scatter ----
    {
        const int i = t >> 2, pc = t & 3;
        *(short8v*)&Ahi[i * 40 + pc * 8] = *(const short8v*)&AhB[i * 32 + pc * 8];
        *(short8v*)&Alo[i * 40 + pc * 8] = *(const short8v*)&AlB[i * 32 + pc * 8];
        *(short8v*)&Khi[i * 40 + pc * 8] = *(const short8v*)&KhB[i * 32 + pc * 8];
        *(short8v*)&Klo[i * 40 + pc * 8] = *(const short8v*)&KlB[i * 32 + pc * 8];
    }
#pragma unroll
    for (int e = t; e < 320; e += 256) {
        int j = e / 5, pc = e % 5;
        short8v v = *(const short8v*)&VbB[j * 40 + pc * 8];
#pragma unroll
        for (int k = 0; k < 8; ++k) Vb[(pc * 8 + k) * 72 + j] = v[k];
    }
    if (t < 144) {
        int o = 40 * 72 + t * 4;
        Vb[o] = 0; Vb[o+1] = 0; Vb[o+2] = 0; Vb[o+3] = 0;
    }
    __syncthreads();

    // ---- logits: 12 MFMAs ----
    const int w = t >> 6;
    const int lane = t & 63;
    const int lrow = lane & 15;
    const int lkg  = lane >> 4;

    f32x4 La0 = {0,0,0,0}, La1 = {0,0,0,0}, La2 = {0,0,0,0}, La3 = {0,0,0,0};
    {
        short8v ahi = *(const short8v*)&Ahi[(16 * w + lrow) * 40 + lkg * 8];
        short8v alo = *(const short8v*)&Alo[(16 * w + lrow) * 40 + lkg * 8];
        short8v k0h = *(const short8v*)&Khi[(lrow) * 40 + lkg * 8];
        short8v k1h = *(const short8v*)&Khi[(16 + lrow) * 40 + lkg * 8];
        short8v k2h = *(const short8v*)&Khi[(32 + lrow) * 40 + lkg * 8];
        short8v k3h = *(const short8v*)&Khi[(48 + lrow) * 40 + lkg * 8];
        short8v k0l = *(const short8v*)&Klo[(lrow) * 40 + lkg * 8];
        short8v k1l = *(const short8v*)&Klo[(16 + lrow) * 40 + lkg * 8];
        short8v k2l = *(const short8v*)&Klo[(32 + lrow) * 40 + lkg * 8];
        short8v k3l = *(const short8v*)&Klo[(48 + lrow) * 40 + lkg * 8];
        La0 = __builtin_amdgcn_mfma_f32_16x16x32_bf16(ahi, k0h, La0, 0, 0, 0);
        La1 = __builtin_amdgcn_mfma_f32_16x16x32_bf16(ahi, k1h, La1, 0, 0, 0);
        La2 = __builtin_amdgcn_mfma_f32_16x16x32_bf16(ahi, k2h, La2, 0, 0, 0);
        La3 = __builtin_amdgcn_mfma_f32_16x16x32_bf16(ahi, k3h, La3, 0, 0, 0);
        La0 = __builtin_amdgcn_mfma_f32_16x16x32_bf16(alo, k0h, La0, 0, 0, 0);
        La1 = __builtin_amdgcn_mfma_f32_16x16x32_bf16(alo, k1h, La1, 0, 0, 0);
        La2 = __builtin_amdgcn_mfma_f32_16x16x32_bf16(alo, k2h, La2, 0, 0, 0);
        La3 = __builtin_amdgcn_mfma_f32_16x16x32_bf16(alo, k3h, La3, 0, 0, 0);
        La0 = __builtin_amdgcn_mfma_f32_16x16x32_bf16(ahi, k0l, La0, 0, 0, 0);
        La1 = __builtin_amdgcn_mfma_f32_16x16x32_bf16(ahi, k1l, La1, 0, 0, 0);
        La2 = __builtin_amdgcn_mfma_f32_16x16x32_bf16(ahi, k2l, La2, 0, 0, 0);
        La3 = __builtin_amdgcn_mfma_f32_16x16x32_bf16(ahi, k3l, La3, 0, 0, 0);
    }

    const size_t pidx = ((size_t)(bh * 6 + ic)) * 6 + jc;
    float* po = part + pidx * PSTRIDE;

    float m0_, m1_, m2_, m3_, s0_, s1_, s2_, s3_;
    float p00,p10,p20,p30, p01,p11,p21,p31, p02,p12,p22,p32, p03,p13,p23,p33;

#define SMAX_E(E, TM, SM, P0, P1, P2, P3) { \
    float tmax_ = fmaxf(fmaxf(La0[E], La1[E]), fmaxf(La2[E], La3[E])); \
    tmax_ = fmaxf(tmax_, __shfl_xor(tmax_, 1)); \
    tmax_ = fmaxf(tmax_, __shfl_xor(tmax_, 2)); \
    tmax_ = fmaxf(tmax_, __shfl_xor(tmax_, 4)); \
    tmax_ = fmaxf(tmax_, __shfl_xor(tmax_, 8)); \
    P0 = __expf(La0[E] - tmax_); P1 = __expf(La1[E] - tmax_); \
    P2 = __expf(La2[E] - tmax_); P3 = __expf(La3[E] - tmax_); \
    float cs_ = P0 + P1 + P2 + P3; \
    cs_ += __shfl_xor(cs_, 1); cs_ += __shfl_xor(cs_, 2); \
    cs_ += __shfl_xor(cs_, 4); cs_ += __shfl_xor(cs_, 8); \
    TM = tmax_; SM = cs_; }

    SMAX_E(0, m0_, s0_, p00, p10, p20, p30);
    SMAX_E(1, m1_, s1_, p01, p11, p21, p31);
    SMAX_E(2, m2_, s2_, p02, p12, p22, p32);
    SMAX_E(3, m3_, s3_, p03, p13, p23, p33);
#undef SMAX_E

    if (lrow == 0) {
        int rb = 16 * w + 4 * lkg;
        po[2560 + rb + 0] = m0_; po[2624 + rb + 0] = s0_;
        po[2560 + rb + 1] = m1_; po[2624 + rb + 1] = s1_;
        po[2560 + rb + 2] = m2_; po[2624 + rb + 2] = s2_;
        po[2560 + rb + 3] = m3_; po[2624 + rb + 3] = s3_;
    }
    __syncthreads();    // A/K reads complete before Pb aliases the region

#define PW(E, PJ0, PJ1, PJ2, PJ3) { \
    int r_ = (16 * w + 4 * lkg + E) * 72; \
    Pb[r_ + lrow]      = f2bf(PJ0); \
    Pb[r_ + 16 + lrow] = f2bf(PJ1); \
    Pb[r_ + 32 + lrow] = f2bf(PJ2); \
    Pb[r_ + 48 + lrow] = f2bf(PJ3); }
    PW(0, p00, p10, p20, p30);
    PW(1, p01, p11, p21, p31);
    PW(2, p02, p12, p22, p32);
    PW(3, p03, p13, p23, p33);
#undef PW
    __syncthreads();

    // ---- PV: 6 MFMAs ----
    f32x4 O0 = {0,0,0,0}, O1 = {0,0,0,0}, O2 = {0,0,0,0};
#pragma unroll
    for (int ch = 0; ch < 2; ++ch) {
        short8v pf = *(const short8v*)&Pb[(16 * w + lrow) * 72 + ch * 32 + lkg * 8];
        short8v v0 = *(const short8v*)&Vb[(lrow) * 72 + ch * 32 + lkg * 8];
        short8v v1 = *(const short8v*)&Vb[(16 + lrow) * 72 + ch * 32 + lkg * 8];
        short8v v2 = *(const short8v*)&Vb[(32 + lrow) * 72 + ch * 32 + lkg * 8];
        O0 = __builtin_amdgcn_mfma_f32_16x16x32_bf16(pf, v0, O0, 0, 0, 0);
        O1 = __builtin_amdgcn_mfma_f32_16x16x32_bf16(pf, v1, O1, 0, 0, 0);
        O2 = __builtin_amdgcn_mfma_f32_16x16x32_bf16(pf, v2, O2, 0, 0, 0);
    }
#pragma unroll
    for (int e = 0; e < 4; ++e) {
        int r = 16 * w + 4 * lkg + e;
        po[r * 40 + lrow]      = O0[e];
        po[r * 40 + 16 + lrow] = O1[e];
        if (lrow < 8) po[r * 40 + 32 + lrow] = O2[e];
    }
}

// ---------------- Kernel 3b: merge partials + epilogue (writes bf16 cat) ----------------
__global__ __launch_bounds__(256) void attn_merge_kernel(
    const float* __restrict__ part,
    const float* __restrict__ rot, const float* __restrict__ trans,
    short* __restrict__ cat_bf)
{
    __shared__ float wsh[64 * 8];
    __shared__ float ob[64 * 44];

    const int bid = blockIdx.x;
    const int ic = bid % 6;
    const int h  = (bid / 6) % Hh;
    const int b  = bid / (6 * Hh);
    const int t  = threadIdx.x;
    const int i0 = ic * 64;
    const int bh = b * Hh + h;
    const size_t pbase = (((size_t)(bh * 6 + ic)) * 6) * PSTRIDE;

    if (t < 64) {
        float mk[6], sk[6];
        float M = -3.0e38f;
#pragma unroll
        for (int k = 0; k < 6; ++k) {
            mk[k] = part[pbase + (size_t)k * PSTRIDE + 2560 + t];
            sk[k] = part[pbase + (size_t)k * PSTRIDE + 2624 + t];
            M = fmaxf(M, mk[k]);
        }
        float wk[6]; float stot = 0.0f;
#pragma unroll
        for (int k = 0; k < 6; ++k) {
            wk[k] = __expf(mk[k] - M);
            stot += wk[k] * sk[k];
        }
        float inv = 1.0f / stot;
#pragma unroll
        for (int k = 0; k < 6; ++k) wsh[t * 8 + k] = wk[k] * inv;
    }
    __syncthreads();

#pragma unroll
    for (int it = 0; it < 10; ++it) {
        int idx = t + it * 256;
        int row = idx / 40, col = idx % 40;
        float v = 0.0f;
#pragma unroll
        for (int k = 0; k < 6; ++k)
            v += wsh[row * 8 + k] * part[pbase + (size_t)k * PSTRIDE + row * 40 + col];
        ob[row * 44 + col] = v;
    }
    __syncthreads();

    {
        const int i = t >> 2;
        const int qq = t & 3;
        const int bnI = b * Nn + i0 + i;
        short* crow = cat_bf + (size_t)bnI * FCAT;

        float4 o = *(const float4*)&ob[i * 44 + 4 * qq];
        crow[h * 16 + 4 * qq + 0] = f2bf(o.x);
        crow[h * 16 + 4 * qq + 1] = f2bf(o.y);
        crow[h * 16 + 4 * qq + 2] = f2bf(o.z);
        crow[h * 16 + 4 * qq + 3] = f2bf(o.w);

        const float* R = rot + (size_t)bnI * 9;
        const float* T = trans + (size_t)bnI * 3;
#pragma unroll
        for (int e = 0; e < 2; ++e) {
            int pe = qq + 4 * e;
            float g0 = ob[i * 44 + 16 + 3 * pe + 0] - T[0];
            float g1 = ob[i * 44 + 16 + 3 * pe + 1] - T[1];
            float g2 = ob[i * 44 + 16 + 3 * pe + 2] - T[2];
            float lx = R[0]*g0 + R[3]*g1 + R[6]*g2;
            float ly = R[1]*g0 + R[4]*g1 + R[7]*g2;
            float lz = R[2]*g0 + R[5]*g1 + R[8]*g2;
            crow[192 + h * 8 + pe] = f2bf(lx);
            crow[288 + h * 8 + pe] = f2bf(ly);
            crow[384 + h * 8 + pe] = f2bf(lz);
            crow[480 + h * 8 + pe] = f2bf(sqrtf(lx*lx + ly*ly + lz*lz + EPSV));
        }
    }
}

// ---------------- Kernel 4: output GEMM via bf16 MFMA (bf16 cat staging) ----------------
__global__ __launch_bounds__(256) void out_kernel(
    const short* __restrict__ cat_bf, const short* __restrict__ wto,
    const float* __restrict__ b_out, float* __restrict__ out)
{
    __shared__ short Al[64 * 40];
    __shared__ short Bl[64 * 40];

    const int bm = blockIdx.x % 24;
    const int bn = blockIdx.x / 24;
    const int m0 = bm * 64;
    const int n0 = bn * 64;
    const int t = threadIdx.x;
    const int w = t >> 6;
    const int lane = t & 63;
    const int lrow = lane & 15;
    const int lkg  = lane >> 4;

    const int srow = t >> 2;
    const int sseg = t & 3;

    f32x4 acc0 = {0,0,0,0}, acc1 = {0,0,0,0}, acc2 = {0,0,0,0}, acc3 = {0,0,0,0};

    for (int ks = 0; ks < 18; ++ks) {
        const int kbase = ks * 32;
        {
            short8v a = *(const short8v*)&cat_bf[(size_t)(m0 + srow) * FCAT + kbase + sseg * 8];
            *(short8v*)&Al[srow * 40 + sseg * 8] = a;
        }
        {
            short8v bvv = *(const short8v*)&wto[(size_t)(n0 + srow) * FCAT + kbase + sseg * 8];
            *(short8v*)&Bl[srow * 40 + sseg * 8] = bvv;
        }
        __syncthreads();

        short8v av = *(const short8v*)&Al[(16 * w + lrow) * 40 + lkg * 8];
        short8v b0 = *(const short8v*)&Bl[(lrow) * 40 + lkg * 8];
        short8v b1 = *(const short8v*)&Bl[(16 + lrow) * 40 + lkg * 8];
        short8v b2 = *(const short8v*)&Bl[(32 + lrow) * 40 + lkg * 8];
        short8v b3 = *(const short8v*)&Bl[(48 + lrow) * 40 + lkg * 8];
        acc0 = __builtin_amdgcn_mfma_f32_16x16x32_bf16(av, b0, acc0, 0, 0, 0);
        acc1 = __builtin_amdgcn_mfma_f32_16x16x32_bf16(av, b1, acc1, 0, 0, 0);
        acc2 = __builtin_amdgcn_mfma_f32_16x16x32_bf16(av, b2, acc2, 0, 0, 0);
        acc3 = __builtin_amdgcn_mfma_f32_16x16x32_bf16(av, b3, acc3, 0, 0, 0);
        __syncthreads();
    }

    const int orow = m0 + 16 * w + lkg * 4;
#pragma unroll
    for (int e = 0; e < 4; ++e) {
        float* pr = out + (size_t)(orow + e) * 384 + n0;
        int c0 = lrow;
        pr[c0]      = acc0[e] + b_out[n0 + c0];
        pr[16 + c0] = acc1[e] + b_out[n0 + 16 + c0];
        pr[32 + c0] = acc2[e] + b_out[n0 + 32 + c0];
        pr[48 + c0] = acc3[e] + b_out[n0 + 48 + c0];
    }
}

extern "C" void kernel_launch(void* const* d_in, const int* in_sizes, int n_in,
                              void* d_out, int out_size, void* d_ws, size_t ws_size,
                              hipStream_t stream) {
    const float* s     = (const float*)d_in[0];
    const float* rot   = (const float*)d_in[2];
    const float* trans = (const float*)d_in[3];
    const float* mask  = (const float*)d_in[4];
    const float* w_q   = (const float*)d_in[5];
    const float* b_q   = (const float*)d_in[6];
    const float* w_kv  = (const float*)d_in[7];
    const float* b_kv  = (const float*)d_in[8];
    const float* w_qp  = (const float*)d_in[13];
    const float* b_qp  = (const float*)d_in[14];
    const float* w_kvp = (const float*)d_in[15];
    const float* b_kvp = (const float*)d_in[16];
    const float* hwts  = (const float*)d_in[17];
    const float* w_out = (const float*)d_in[18];
    const float* b_out = (const float*)d_in[19];

    float* ws    = (float*)d_ws;
    float* proj  = ws + WS_PROJ;
    short* cat_bf = (short*)(ws + WS_CAT);
    float* partb = ws + WS_PART;
    short* wt    = (short*)(ws + WS_WT);
    short* wto   = (short*)(ws + WS_WTO);
    short* Ah    = (short*)(ws + WS_AH);
    short* Alp   = (short*)(ws + WS_AL);
    short* Kh    = (short*)(ws + WS_KH);
    short* Kl    = (short*)(ws + WS_KL);
    short* Vbp   = (short*)(ws + WS_VBP);
    float* out   = (float*)d_out;

    hipLaunchKernelGGL(prep_kernel, dim3(2592), dim3(256), 0, stream,
                       w_q, w_kv, w_qp, w_kvp, w_out, wt, wto);
    hipLaunchKernelGGL(proj_kernel, dim3(432), dim3(256), 0, stream,
                       s, wt, b_q, b_kv, b_qp, b_kvp, proj);
    hipLaunchKernelGGL(pack_kernel, dim3(1536), dim3(192), 0, stream,
                       proj, rot, trans, hwts, mask, Ah, Alp, Kh, Kl, Vbp);
    hipLaunchKernelGGL(attn_part_kernel, dim3(1728), dim3(256), 0, stream,
                       Ah, Alp, Kh, Kl, Vbp, partb);
    hipLaunchKernelGGL(attn_merge_kernel, dim3(288), dim3(256), 0, stream,
                       partb, rot, trans, cat_bf);
    hipLaunchKernelGGL(out_kernel, dim3(144), dim3(256), 0, stream,
                       cat_bf, wto, b_out, out);
}

// Round 14
// 54.210 us; speedup vs baseline: 2.4078x; 1.0231x over previous
//
#include <hip/hip_runtime.h>
#include <math.h>

#define Bb 4
#define Nn 384
#define CSs 384
#define Hh 12
#define Cc 16
#define PQq 4
#define PVv 8
#define FPROJ 1152
#define FCAT 576
#define INFV 100000.0f
#define EPSV 1e-8f

// ws layout (float slots)
#define WS_PROJ 0
#define WS_CAT  3022848      // bf16 cat: 1536*576 shorts
#define WS_PART 4423680      // 48*36 partials, stride 1408 (O bf16 [64][40] | m[64]@1280 | s[64]@1344)
#define PSTRIDE 1408
#define WS_WT   9068544
#define WS_WTO  9289728
#define WS_AH   9400320
#define WS_AL   9695232
#define WS_KH   9990144
#define WS_KL   10285056
#define WS_VBP  10579968     // 48*384*40 shorts
#define WS_SB   10948608     // s bf16: 1536*384 shorts = 294912 float slots

typedef __attribute__((ext_vector_type(8))) short short8v;
typedef __attribute__((ext_vector_type(4))) float f32x4;

__device__ __forceinline__ short f2bf(float x) {
    unsigned u = __float_as_uint(x);
    unsigned r = (u + 0x7FFFu + ((u >> 16) & 1u)) >> 16;
    return (short)r;
}
__device__ __forceinline__ float bf2f(short h) {
    return __uint_as_float(((unsigned)(unsigned short)h) << 16);
}

__device__ __forceinline__ float get_bias(int f,
    const float* __restrict__ b_q, const float* __restrict__ b_kv,
    const float* __restrict__ b_qp, const float* __restrict__ b_kvp)
{
    if (f < 192) return b_q[f];
    if (f < 576) return b_kv[f - 192];
    if (f < 720) return b_qp[f - 576];
    return b_kvp[f - 720];
}

// ---------------- Kernel 0: prep — weights + s to bf16 ----------------
// grid 4896 = (442368 + 221184 + 589824)/256
__global__ __launch_bounds__(256) void prep_kernel(
    const float* __restrict__ w_q, const float* __restrict__ w_kv,
    const float* __restrict__ w_qp, const float* __restrict__ w_kvp,
    const float* __restrict__ w_out, const float* __restrict__ s,
    short* __restrict__ wt, short* __restrict__ wto, short* __restrict__ sb)
{
    int idx = blockIdx.x * 256 + threadIdx.x;
    if (idx < 1152 * 384) {
        int f = idx / 384, k = idx % 384;
        float v;
        if (f < 192)      v = w_q[(size_t)k * 192 + f];
        else if (f < 576) v = w_kv[(size_t)k * 384 + (f - 192)];
        else if (f < 720) v = w_qp[(size_t)k * 144 + (f - 576)];
        else              v = w_kvp[(size_t)k * 432 + (f - 720)];
        wt[idx] = f2bf(v);
    } else if (idx < 1152 * 384 + 384 * 576) {
        int j = idx - 1152 * 384;
        int f = j / 576, k = j % 576;
        wto[j] = f2bf(w_out[(size_t)k * 384 + f]);
    } else if (idx < 1152 * 384 + 384 * 576 + 1536 * 384) {
        int j = idx - (1152 * 384 + 384 * 576);
        sb[j] = f2bf(s[j]);
    }
}

// ---------------- Kernel 1: projection GEMM via bf16 MFMA (A from prepacked sb) ----------------
__global__ __launch_bounds__(256) void proj_kernel(
    const short* __restrict__ sb, const short* __restrict__ wt,
    const float* __restrict__ b_q, const float* __restrict__ b_kv,
    const float* __restrict__ b_qp, const float* __restrict__ b_kvp,
    float* __restrict__ proj)
{
    __shared__ short Al[64 * 40];
    __shared__ short Bl[64 * 40];

    const int bm = blockIdx.x % 24;
    const int bn = blockIdx.x / 24;
    const int m0 = bm * 64;
    const int f0 = bn * 64;
    const int t = threadIdx.x;
    const int w = t >> 6;
    const int lane = t & 63;
    const int lrow = lane & 15;
    const int lkg  = lane >> 4;

    const int srow = t >> 2;
    const int sseg = t & 3;

    f32x4 acc0 = {0,0,0,0}, acc1 = {0,0,0,0}, acc2 = {0,0,0,0}, acc3 = {0,0,0,0};

    for (int ks = 0; ks < 12; ++ks) {
        const int kbase = ks * 32;
        *(short8v*)&Al[srow * 40 + sseg * 8] =
            *(const short8v*)&sb[(size_t)(m0 + srow) * CSs + kbase + sseg * 8];
        *(short8v*)&Bl[srow * 40 + sseg * 8] =
            *(const short8v*)&wt[(size_t)(f0 + srow) * 384 + kbase + sseg * 8];
        __syncthreads();

        short8v av = *(const short8v*)&Al[(16 * w + lrow) * 40 + lkg * 8];
        short8v b0 = *(const short8v*)&Bl[(lrow) * 40 + lkg * 8];
        short8v b1 = *(const short8v*)&Bl[(16 + lrow) * 40 + lkg * 8];
        short8v b2 = *(const short8v*)&Bl[(32 + lrow) * 40 + lkg * 8];
        short8v b3 = *(const short8v*)&Bl[(48 + lrow) * 40 + lkg * 8];
        acc0 = __builtin_amdgcn_mfma_f32_16x16x32_bf16(av, b0, acc0, 0, 0, 0);
        acc1 = __builtin_amdgcn_mfma_f32_16x16x32_bf16(av, b1, acc1, 0, 0, 0);
        acc2 = __builtin_amdgcn_mfma_f32_16x16x32_bf16(av, b2, acc2, 0, 0, 0);
        acc3 = __builtin_amdgcn_mfma_f32_16x16x32_bf16(av, b3, acc3, 0, 0, 0);
        __syncthreads();
    }

    const int orow = m0 + 16 * w + lkg * 4;
#pragma unroll
    for (int e = 0; e < 4; ++e) {
        float* pr = proj + (size_t)(orow + e) * FPROJ + f0;
        int c0 = lrow;
        pr[c0]      = acc0[e] + get_bias(f0 + c0,      b_q, b_kv, b_qp, b_kvp);
        pr[16 + c0] = acc1[e] + get_bias(f0 + 16 + c0, b_q, b_kv, b_qp, b_kvp);
        pr[32 + c0] = acc2[e] + get_bias(f0 + 32 + c0, b_q, b_kv, b_qp, b_kvp);
        pr[48 + c0] = acc3[e] + get_bias(f0 + 48 + c0, b_q, b_kv, b_qp, b_kvp);
    }
}

// ---------------- Kernel 2: pack v2 (r13, unchanged) ----------------
__global__ __launch_bounds__(192) void pack_kernel(
    const float* __restrict__ proj,
    const float* __restrict__ rot, const float* __restrict__ trans,
    const float* __restrict__ hwts, const float* __restrict__ mask,
    short* __restrict__ Ah, short* __restrict__ Al,
    short* __restrict__ Kh, short* __restrict__ Kl,
    short* __restrict__ Vbp)
{
    __shared__ float abuf[12 * 32];
    __shared__ float kbuf[12 * 32];
    __shared__ float vbuf[12 * 40];
    __shared__ float kpsq[12 * 4];

    const int bn = blockIdx.x;
    const int b = bn / Nn;
    const int n = bn % Nn;
    const int t = threadIdx.x;
    const float* R = rot + (size_t)bn * 9;
    const float* T = trans + (size_t)bn * 3;
    const float* pr = proj + (size_t)bn * FPROJ;
    const float mi = mask[bn];

    if (t < 144) {
        float x = pr[720 + t];
        float y = pr[720 + 144 + t];
        float z = pr[720 + 288 + t];
        float ox = R[0]*x + R[1]*y + R[2]*z + T[0];
        float oy = R[3]*x + R[4]*y + R[5]*z + T[1];
        float oz = R[6]*x + R[7]*y + R[8]*z + T[2];
        int h = t / 12, pp = t % 12;
        if (pp < PQq) {
            kbuf[h*32 + 16 + pp*3 + 0] = ox;
            kbuf[h*32 + 16 + pp*3 + 1] = oy;
            kbuf[h*32 + 16 + pp*3 + 2] = oz;
            kpsq[h*4 + pp] = ox*ox + oy*oy + oz*oz;
        } else {
            vbuf[h*40 + 16 + (pp - PQq)*3 + 0] = ox;
            vbuf[h*40 + 16 + (pp - PQq)*3 + 1] = oy;
            vbuf[h*40 + 16 + (pp - PQq)*3 + 2] = oz;
        }
    }
    if (t < 48) {
        float x = pr[576 + t];
        float y = pr[576 + 48 + t];
        float z = pr[576 + 96 + t];
        float ox = R[0]*x + R[1]*y + R[2]*z + T[0];
        float oy = R[3]*x + R[4]*y + R[5]*z + T[1];
        float oz = R[6]*x + R[7]*y + R[8]*z + T[2];
        int h = t / 4, p = t % 4;
        float n2wc = log1pf(expf(hwts[h])) * 0.13608276348795434f;
        abuf[h*32 + 16 + p*3 + 0] = n2wc * ox;
        abuf[h*32 + 16 + p*3 + 1] = n2wc * oy;
        abuf[h*32 + 16 + p*3 + 2] = n2wc * oz;
    }
    {
        int h = t >> 4, c = t & 15;
        abuf[h*32 + c] = 0.28867513459481287f * pr[h * 16 + c];
        kbuf[h*32 + c] = pr[192 + h * 32 + c];
        vbuf[h*40 + c] = pr[192 + h * 32 + 16 + c];
    }
    if (t < 12) {
        abuf[t*32 + 28] = 1.0f;  abuf[t*32 + 29] = mi;
        abuf[t*32 + 30] = 0.0f;  abuf[t*32 + 31] = 0.0f;
        kbuf[t*32 + 29] = INFV * (mi - 1.0f);
        kbuf[t*32 + 30] = 0.0f;  kbuf[t*32 + 31] = 0.0f;
    }
    __syncthreads();
    if (t < 12) {
        float hw2 = log1pf(expf(hwts[t]));
        float wc = -0.5f * hw2 * 0.13608276348795434f;
        kbuf[t*32 + 28] = wc * (kpsq[t*4] + kpsq[t*4+1] + kpsq[t*4+2] + kpsq[t*4+3]);
    }
    __syncthreads();

    if (t < 48) {
        int h = t >> 2, pc = t & 3;
        const float* src = &abuf[h*32 + pc*8];
        short8v hi, lo;
#pragma unroll
        for (int k = 0; k < 8; ++k) {
            short hh = f2bf(src[k]);
            hi[k] = hh; lo[k] = f2bf(src[k] - bf2f(hh));
        }
        size_t off = ((size_t)((b * Hh + h) * Nn + n)) * 32 + pc * 8;
        *(short8v*)&Ah[off] = hi;
        *(short8v*)&Al[off] = lo;
    } else if (t < 96) {
        int tt = t - 48, h = tt >> 2, pc = tt & 3;
        const float* src = &kbuf[h*32 + pc*8];
        short8v hi, lo;
#pragma unroll
        for (int k = 0; k < 8; ++k) {
            short hh = f2bf(src[k]);
            hi[k] = hh; lo[k] = f2bf(src[k] - bf2f(hh));
        }
        size_t off = ((size_t)((b * Hh + h) * Nn + n)) * 32 + pc * 8;
        *(short8v*)&Kh[off] = hi;
        *(short8v*)&Kl[off] = lo;
    } else if (t < 156) {
        int tt = t - 96, h = tt / 5, pc = tt % 5;
        const float* src = &vbuf[h*40 + pc*8];
        short8v v;
#pragma unroll
        for (int k = 0; k < 8; ++k) v[k] = f2bf(src[k]);
        *(short8v*)&Vbp[((size_t)((b * Hh + h) * Nn + n)) * 40 + pc * 8] = v;
    }
}

// ---------------- Kernel 3a: attention partial via MFMA (bf16 partials) ----------------
__global__ __launch_bounds__(256) void attn_part_kernel(
    const short* __restrict__ Ah, const short* __restrict__ Al,
    const short* __restrict__ Kh, const short* __restrict__ Kl,
    const short* __restrict__ Vbp,
    float* __restrict__ part)
{
    __shared__ short smem_s[13696];
    short* Ahi = smem_s;
    short* Alo = smem_s + 2560;
    short* Khi = smem_s + 5120;
    short* Klo = smem_s + 7680;
    short* Vb  = smem_s + 10240;
    short* Pb  = smem_s;

    const int bid = blockIdx.x;
    const int jc = bid % 6;
    const int ic = (bid / 6) % 6;
    const int h  = (bid / 36) % Hh;
    const int b  = bid / (36 * Hh);
    const int t  = threadIdx.x;
    const int i0 = ic * 64;
    const int j0 = jc * 64;
    const int bh = b * Hh + h;

    const short* AhB = Ah + ((size_t)(bh * Nn + i0)) * 32;
    const short* AlB = Al + ((size_t)(bh * Nn + i0)) * 32;
    const short* KhB = Kh + ((size_t)(bh * Nn + j0)) * 32;
    const short* KlB = Kl + ((size_t)(bh * Nn + j0)) * 32;
    const short* VbB = Vbp + ((size_t)(bh * Nn + j0)) * 40;

    {
        const int i = t >> 2, pc = t & 3;
        *(short8v*)&Ahi[i * 40 + pc * 8] = *(const short8v*)&AhB[i * 32 + pc * 8];
        *(short8v*)&Alo[i * 40 + pc * 8] = *(const short8v*)&AlB[i * 32 + pc * 8];
        *(short8v*)&Khi[i * 40 + pc * 8] = *(const short8v*)&KhB[i * 32 + pc * 8];
        *(short8v*)&Klo[i * 40 + pc * 8] = *(const short8v*)&KlB[i * 32 + pc * 8];
    }
#pragma unroll
    for (int e = t; e < 320; e += 256) {
        int j = e / 5, pc = e % 5;
        short8v v = *(const short8v*)&VbB[j * 40 + pc * 8];
#pragma unroll
        for (int k = 0; k < 8; ++k) Vb[(pc * 8 + k) * 72 + j] = v[k];
    }
    if (t < 144) {
        int o = 40 * 72 + t * 4;
        Vb[o] = 0; Vb[o+1] = 0; Vb[o+2] = 0; Vb[o+3] = 0;
    }
    __syncthreads();

    const int w = t >> 6;
    const int lane = t & 63;
    const int lrow = lane & 15;
    const int lkg  = lane >> 4;

    f32x4 La0 = {0,0,0,0}, La1 = {0,0,0,0}, La2 = {0,0,0,0}, La3 = {0,0,0,0};
    {
        short8v ahi = *(const short8v*)&Ahi[(16 * w + lrow) * 40 + lkg * 8];
        short8v alo = *(const short8v*)&Alo[(16 * w + lrow) * 40 + lkg * 8];
        short8v k0h = *(const short8v*)&Khi[(lrow) * 40 + lkg * 8];
        short8v k1h = *(const short8v*)&Khi[(16 + lrow) * 40 + lkg * 8];
        short8v k2h = *(const short8v*)&Khi[(32 + lrow) * 40 + lkg * 8];
        short8v k3h = *(const short8v*)&Khi[(48 + lrow) * 40 + lkg * 8];
        short8v k0l = *(const short8v*)&Klo[(lrow) * 40 + lkg * 8];
        short8v k1l = *(const short8v*)&Klo[(16 + lrow) * 40 + lkg * 8];
        short8v k2l = *(const short8v*)&Klo[(32 + lrow) * 40 + lkg * 8];
        short8v k3l = *(const short8v*)&Klo[(48 + lrow) * 40 + lkg * 8];
        La0 = __builtin_amdgcn_mfma_f32_16x16x32_bf16(ahi, k0h, La0, 0, 0, 0);
        La1 = __builtin_amdgcn_mfma_f32_16x16x32_bf16(ahi, k1h, La1, 0, 0, 0);
        La2 = __builtin_amdgcn_mfma_f32_16x16x32_bf16(ahi, k2h, La2, 0, 0, 0);
        La3 = __builtin_amdgcn_mfma_f32_16x16x32_bf16(ahi, k3h, La3, 0, 0, 0);
        La0 = __builtin_amdgcn_mfma_f32_16x16x32_bf16(alo, k0h, La0, 0, 0, 0);
        La1 = __builtin_amdgcn_mfma_f32_16x16x32_bf16(alo, k1h, La1, 0, 0, 0);
        La2 = __builtin_amdgcn_mfma_f32_16x16x32_bf16(alo, k2h, La2, 0, 0, 0);
        La3 = __builtin_amdgcn_mfma_f32_16x16x32_bf16(alo, k3h, La3, 0, 0, 0);
        La0 = __builtin_amdgcn_mfma_f32_16x16x32_bf16(ahi, k0l, La0, 0, 0, 0);
        La1 = __builtin_amdgcn_mfma_f32_16x16x32_bf16(ahi, k1l, La1, 0, 0, 0);
        La2 = __builtin_amdgcn_mfma_f32_16x16x32_bf16(ahi, k2l, La2, 0, 0, 0);
        La3 = __builtin_amdgcn_mfma_f32_16x16x32_bf16(ahi, k3l, La3, 0, 0, 0);
    }

    const size_t pidx = ((size_t)(bh * 6 + ic)) * 6 + jc;
    float* po = part + pidx * PSTRIDE;
    short* poO = (short*)po;     // O bf16 occupies float slots [0,1280)

    float m0_, m1_, m2_, m3_, s0_, s1_, s2_, s3_;
    float p00,p10,p20,p30, p01,p11,p21,p31, p02,p12,p22,p32, p03,p13,p23,p33;

#define SMAX_E(E, TM, SM, P0, P1, P2, P3) { \
    float tmax_ = fmaxf(fmaxf(La0[E], La1[E]), fmaxf(La2[E], La3[E])); \
    tmax_ = fmaxf(tmax_, __shfl_xor(tmax_, 1)); \
    tmax_ = fmaxf(tmax_, __shfl_xor(tmax_, 2)); \
    tmax_ = fmaxf(tmax_, __shfl_xor(tmax_, 4)); \
    tmax_ = fmaxf(tmax_, __shfl_xor(tmax_, 8)); \
    P0 = __expf(La0[E] - tmax_); P1 = __expf(La1[E] - tmax_); \
    P2 = __expf(La2[E] - tmax_); P3 = __expf(La3[E] - tmax_); \
    float cs_ = P0 + P1 + P2 + P3; \
    cs_ += __shfl_xor(cs_, 1); cs_ += __shfl_xor(cs_, 2); \
    cs_ += __shfl_xor(cs_, 4); cs_ += __shfl_xor(cs_, 8); \
    TM = tmax_; SM = cs_; }

    SMAX_E(0, m0_, s0_, p00, p10, p20, p30);
    SMAX_E(1, m1_, s1_, p01, p11, p21, p31);
    SMAX_E(2, m2_, s2_, p02, p12, p22, p32);
    SMAX_E(3, m3_, s3_, p03, p13, p23, p33);
#undef SMAX_E

    if (lrow == 0) {
        int rb = 16 * w + 4 * lkg;
        po[1280 + rb + 0] = m0_; po[1344 + rb + 0] = s0_;
        po[1280 + rb + 1] = m1_; po[1344 + rb + 1] = s1_;
        po[1280 + rb + 2] = m2_; po[1344 + rb + 2] = s2_;
        po[1280 + rb + 3] = m3_; po[1344 + rb + 3] = s3_;
    }
    __syncthreads();

#define PW(E, PJ0, PJ1, PJ2, PJ3) { \
    int r_ = (16 * w + 4 * lkg + E) * 72; \
    Pb[r_ + lrow]      = f2bf(PJ0); \
    Pb[r_ + 16 + lrow] = f2bf(PJ1); \
    Pb[r_ + 32 + lrow] = f2bf(PJ2); \
    Pb[r_ + 48 + lrow] = f2bf(PJ3); }
    PW(0, p00, p10, p20, p30);
    PW(1, p01, p11, p21, p31);
    PW(2, p02, p12, p22, p32);
    PW(3, p03, p13, p23, p33);
#undef PW
    __syncthreads();

    f32x4 O0 = {0,0,0,0}, O1 = {0,0,0,0}, O2 = {0,0,0,0};
#pragma unroll
    for (int ch = 0; ch < 2; ++ch) {
        short8v pf = *(const short8v*)&Pb[(16 * w + lrow) * 72 + ch * 32 + lkg * 8];
        short8v v0 = *(const short8v*)&Vb[(lrow) * 72 + ch * 32 + lkg * 8];
        short8v v1 = *(const short8v*)&Vb[(16 + lrow) * 72 + ch * 32 + lkg * 8];
        short8v v2 = *(const short8v*)&Vb[(32 + lrow) * 72 + ch * 32 + lkg * 8];
        O0 = __builtin_amdgcn_mfma_f32_16x16x32_bf16(pf, v0, O0, 0, 0, 0);
        O1 = __builtin_amdgcn_mfma_f32_16x16x32_bf16(pf, v1, O1, 0, 0, 0);
        O2 = __builtin_amdgcn_mfma_f32_16x16x32_bf16(pf, v2, O2, 0, 0, 0);
    }
#pragma unroll
    for (int e = 0; e < 4; ++e) {
        int r = 16 * w + 4 * lkg + e;
        poO[r * 40 + lrow]      = f2bf(O0[e]);
        poO[r * 40 + 16 + lrow] = f2bf(O1[e]);
        if (lrow < 8) poO[r * 40 + 32 + lrow] = f2bf(O2[e]);
    }
}

// ---------------- Kernel 3b: merge partials (bf16 O) + epilogue ----------------
__global__ __launch_bounds__(256) void attn_merge_kernel(
    const float* __restrict__ part,
    const float* __restrict__ rot, const float* __restrict__ trans,
    short* __restrict__ cat_bf)
{
    __shared__ float wsh[64 * 8];
    __shared__ float ob[64 * 44];

    const int bid = blockIdx.x;
    const int ic = bid % 6;
    const int h  = (bid / 6) % Hh;
    const int b  = bid / (6 * Hh);
    const int t  = threadIdx.x;
    const int i0 = ic * 64;
    const int bh = b * Hh + h;
    const size_t pbase = (((size_t)(bh * 6 + ic)) * 6) * PSTRIDE;

    if (t < 64) {
        float mk[6], sk[6];
        float M = -3.0e38f;
#pragma unroll
        for (int k = 0; k < 6; ++k) {
            mk[k] = part[pbase + (size_t)k * PSTRIDE + 1280 + t];
            sk[k] = part[pbase + (size_t)k * PSTRIDE + 1344 + t];
            M = fmaxf(M, mk[k]);
        }
        float wk[6]; float stot = 0.0f;
#pragma unroll
        for (int k = 0; k < 6; ++k) {
            wk[k] = __expf(mk[k] - M);
            stot += wk[k] * sk[k];
        }
        float inv = 1.0f / stot;
#pragma unroll
        for (int k = 0; k < 6; ++k) wsh[t * 8 + k] = wk[k] * inv;
    }
    __syncthreads();

#pragma unroll
    for (int it = 0; it < 10; ++it) {
        int idx = t + it * 256;
        int row = idx / 40, col = idx % 40;
        float v = 0.0f;
#pragma unroll
        for (int k = 0; k < 6; ++k) {
            const short* pO = (const short*)&part[pbase + (size_t)k * PSTRIDE];
            v += wsh[row * 8 + k] * bf2f(pO[row * 40 + col]);
        }
        ob[row * 44 + col] = v;
    }
    __syncthreads();

    {
        const int i = t >> 2;
        const int qq = t & 3;
        const int bnI = b * Nn + i0 + i;
        short* crow = cat_bf + (size_t)bnI * FCAT;

        float4 o = *(const float4*)&ob[i * 44 + 4 * qq];
        crow[h * 16 + 4 * qq + 0] = f2bf(o.x);
        crow[h * 16 + 4 * qq + 1] = f2bf(o.y);
        crow[h * 16 + 4 * qq + 2] = f2bf(o.z);
        crow[h * 16 + 4 * qq + 3] = f2bf(o.w);

        const float* R = rot + (size_t)bnI * 9;
        const float* T = trans + (size_t)bnI * 3;
#pragma unroll
        for (int e = 0; e < 2; ++e) {
            int pe = qq + 4 * e;
            float g0 = ob[i * 44 + 16 + 3 * pe + 0] - T[0];
            float g1 = ob[i * 44 + 16 + 3 * pe + 1] - T[1];
            float g2 = ob[i * 44 + 16 + 3 * pe + 2] - T[2];
            float lx = R[0]*g0 + R[3]*g1 + R[6]*g2;
            float ly = R[1]*g0 + R[4]*g1 + R[7]*g2;
            float lz = R[2]*g0 + R[5]*g1 + R[8]*g2;
            crow[192 + h * 8 + pe] = f2bf(lx);
            crow[288 + h * 8 + pe] = f2bf(ly);
            crow[384 + h * 8 + pe] = f2bf(lz);
            crow[480 + h * 8 + pe] = f2bf(sqrtf(lx*lx + ly*ly + lz*lz + EPSV));
        }
    }
}

// ---------------- Kernel 4: output GEMM via bf16 MFMA, 32x64 tiles ----------------
// grid 288 = 48 bm x 6 bn; 256 thr (4 waves): wave w -> rows 16(w&1), cols 32(w>>1)
__global__ __launch_bounds__(256) void out_kernel(
    const short* __restrict__ cat_bf, const short* __restrict__ wto,
    const float* __restrict__ b_out, float* __restrict__ out)
{
    __shared__ short Al[32 * 40];
    __shared__ short Bl[64 * 40];

    const int bm = blockIdx.x % 48;
    const int bn = blockIdx.x / 48;
    const int m0 = bm * 32;
    const int n0 = bn * 64;
    const int t = threadIdx.x;
    const int w = t >> 6;
    const int lane = t & 63;
    const int lrow = lane & 15;
    const int lkg  = lane >> 4;
    const int r0 = 16 * (w & 1);
    const int c0 = 32 * (w >> 1);

    f32x4 acc0 = {0,0,0,0}, acc1 = {0,0,0,0};

    for (int ks = 0; ks < 18; ++ks) {
        const int kbase = ks * 32;
        if (t < 128) {
            int arow = t >> 2, aseg = t & 3;
            *(short8v*)&Al[arow * 40 + aseg * 8] =
                *(const short8v*)&cat_bf[(size_t)(m0 + arow) * FCAT + kbase + aseg * 8];
        }
        {
            int brow = t >> 2, bseg = t & 3;
            *(short8v*)&Bl[brow * 40 + bseg * 8] =
                *(const short8v*)&wto[(size_t)(n0 + brow) * FCAT + kbase + bseg * 8];
        }
        __syncthreads();

        short8v av = *(const short8v*)&Al[(r0 + lrow) * 40 + lkg * 8];
        short8v b0 = *(const short8v*)&Bl[(c0 + lrow) * 40 + lkg * 8];
        short8v b1 = *(const short8v*)&Bl[(c0 + 16 + lrow) * 40 + lkg * 8];
        acc0 = __builtin_amdgcn_mfma_f32_16x16x32_bf16(av, b0, acc0, 0, 0, 0);
        acc1 = __builtin_amdgcn_mfma_f32_16x16x32_bf16(av, b1, acc1, 0, 0, 0);
        __syncthreads();
    }

    const int orow = m0 + r0 + lkg * 4;
#pragma unroll
    for (int e = 0; e < 4; ++e) {
        float* pr = out + (size_t)(orow + e) * 384 + n0 + c0;
        pr[lrow]      = acc0[e] + b_out[n0 + c0 + lrow];
        pr[16 + lrow] = acc1[e] + b_out[n0 + c0 + 16 + lrow];
    }
}

extern "C" void kernel_launch(void* const* d_in, const int* in_sizes, int n_in,
                              void* d_out, int out_size, void* d_ws, size_t ws_size,
                              hipStream_t stream) {
    const float* s     = (const float*)d_in[0];
    const float* rot   = (const float*)d_in[2];
    const float* trans = (const float*)d_in[3];
    const float* mask  = (const float*)d_in[4];
    const float* w_q   = (const float*)d_in[5];
    const float* b_q   = (const float*)d_in[6];
    const float* w_kv  = (const float*)d_in[7];
    const float* b_kv  = (const float*)d_in[8];
    const float* w_qp  = (const float*)d_in[13];
    const float* b_qp  = (const float*)d_in[14];
    const float* w_kvp = (const float*)d_in[15];
    const float* b_kvp = (const float*)d_in[16];
    const float* hwts  = (const float*)d_in[17];
    const float* w_out = (const float*)d_in[18];
    const float* b_out = (const float*)d_in[19];

    float* ws     = (float*)d_ws;
    float* proj   = ws + WS_PROJ;
    short* cat_bf = (short*)(ws + WS_CAT);
    float* partb  = ws + WS_PART;
    short* wt     = (short*)(ws + WS_WT);
    short* wto    = (short*)(ws + WS_WTO);
    short* Ah     = (short*)(ws + WS_AH);
    short* Alp    = (short*)(ws + WS_AL);
    short* Kh     = (short*)(ws + WS_KH);
    short* Kl     = (short*)(ws + WS_KL);
    short* Vbp    = (short*)(ws + WS_VBP);
    short* sb     = (short*)(ws + WS_SB);
    float* out    = (float*)d_out;

    hipLaunchKernelGGL(prep_kernel, dim3(4896), dim3(256), 0, stream,
                       w_q, w_kv, w_qp, w_kvp, w_out, s, wt, wto, sb);
    hipLaunchKernelGGL(proj_kernel, dim3(432), dim3(256), 0, stream,
                       sb, wt, b_q, b_kv, b_qp, b_kvp, proj);
    hipLaunchKernelGGL(pack_kernel, dim3(1536), dim3(192), 0, stream,
                       proj, rot, trans, hwts, mask, Ah, Alp, Kh, Kl, Vbp);
    hipLaunchKernelGGL(attn_part_kernel, dim3(1728), dim3(256), 0, stream,
                       Ah, Alp, Kh, Kl, Vbp, partb);
    hipLaunchKernelGGL(attn_merge_kernel, dim3(288), dim3(256), 0, stream,
                       partb, rot, trans, cat_bf);
    hipLaunchKernelGGL(out_kernel, dim3(288), dim3(256), 0, stream,
                       cat_bf, wto, b_out, out);
}